// Round 13
// baseline (1895.388 us; speedup 1.0000x reference)
//
#include <hip/hip_runtime.h>
#include <stdint.h>

#define DEV static __device__ __forceinline__

typedef float f32x4 __attribute__((ext_vector_type(4)));
typedef int   i32x4 __attribute__((ext_vector_type(4)));
typedef unsigned short u16x8 __attribute__((ext_vector_type(8)));

DEV float bf2f(unsigned short u){ return __uint_as_float(((unsigned int)u)<<16); }
DEV unsigned short f2bfr(float f){ // round-to-nearest-even bf16
  unsigned int u = __float_as_uint(f);
  return (unsigned short)((u + 0x7FFF + ((u>>16)&1)) >> 16);
}
DEV signed char f2i8(float f){ return (signed char)(int)f; } // f already rint+clamped

// ---------------- block reductions (256-thread blocks, 4 waves) ----------------
DEV float wredsum(float v){
#pragma unroll
  for (int o=32;o;o>>=1) v += __shfl_xor(v,o);
  return v;
}
DEV float wredmax(float v){
#pragma unroll
  for (int o=32;o;o>>=1) v = fmaxf(v,__shfl_xor(v,o));
  return v;
}
DEV float bredsum(float v, float* red){
  v = wredsum(v);
  if ((threadIdx.x&63)==0) red[threadIdx.x>>6] = v;
  __syncthreads();
  float r = red[0]+red[1]+red[2]+red[3];
  __syncthreads();
  return r;
}
DEV float bredmax(float v, float* red){
  v = wredmax(v);
  if ((threadIdx.x&63)==0) red[threadIdx.x>>6] = v;
  __syncthreads();
  float r = fmaxf(fmaxf(red[0],red[1]),fmaxf(red[2],red[3]));
  __syncthreads();
  return r;
}

// ---------------- misc ----------------
__global__ void fill_k(float* p, int n, float v){
  int i = blockIdx.x*256 + threadIdx.x;
  if (i < n) p[i] = v;
}

// merged setup: copy_init (1024 blocks) + delta (128) + ropetab (64)
__global__ __launch_bounds__(256) void setup_misc_k(const float* __restrict__ x,
                                                    float* __restrict__ h, float* __restrict__ ho,
                                                    const float* __restrict__ temb,
                                                    const float* __restrict__ lpw,
                                                    const float* __restrict__ lp2w,
                                                    const float* __restrict__ lp2b,
                                                    float* __restrict__ delta,
                                                    float* __restrict__ tab){
  __shared__ float red[4];
  int bid = blockIdx.x, t = threadIdx.x;
  if (bid < 1024){
    int i = bid*256 + t;
    float4 v = *(const float4*)(x + (size_t)i*4);
    *(float4*)(h  + (size_t)i*4) = v;
    *(float4*)(ho + (size_t)i*4) = v;
    if (i==0) ho[1048576] = 0.f;
  } else if (bid < 1152){
    int blk = bid - 1024;
    int b = blk >> 6, j = blk & 63;
    float te = temb[b*256 + t];
    float p1 = bredsum(te * lpw[j*256 + t], red);
    float p2 = bredsum(te * lp2w[j*256 + t], red);
    if (t < 8){
      int i = t;
      float frac = (float)i / 7.f;
      int jj = j & 31;
      float fr = expf(-logf(10000.f) * (float)jj * (1.f/32.f));
      float ang = frac * fr;
      float sig = (j < 32) ? sinf(ang) : cosf(ang);
      delta[i*128 + b*64 + j] = sig*p1 + p2 + lp2b[j];
    }
  } else {
    int i = (bid-1152)*256 + t;   // 16384
    int tpos = i >> 5, d = i & 31;
    float inv = powf(10000.f, -(float)d * (1.f/32.f));
    float sv, cv; sincosf((float)tpos * inv, &sv, &cv);
    tab[i*2]   = cv;
    tab[i*2+1] = sv;
  }
}

// ---------------- fused setup: 18 weight matrices ----------------
struct WSetup {
  const float* src[18];
  signed char* dst[18];
  int mode[18];     // 0 normal; 1 row-interleave even; 2 row-interleave odd
};
DEV long n4of(int mat){ return mat<9 ? 262144 : (mat<15 ? 1048576 : (mat<17 ? 8192 : 256)); }

// grid 9216: mats 0-8 x256 segs, mats 9-14 x1024 segs, mats 15-17 x256 segs.
__global__ __launch_bounds__(256) void absmean_all_k(WSetup wsu, float* __restrict__ part){
  __shared__ float red[4];
  int bid = blockIdx.x, mat, seg;
  if (bid < 2304){ mat = bid >> 8; seg = bid & 255; }
  else if (bid < 8448){ mat = 9 + ((bid-2304) >> 10); seg = (bid-2304) & 1023; }
  else { mat = 15 + ((bid-8448) >> 8); seg = (bid-8448) & 255; }
  long n4 = n4of(mat);
  int segs = (mat >= 9 && mat < 15) ? 1024 : 256;
  long cnt = n4 / segs;
  const float4* p = (const float4*)wsu.src[mat] + (long)seg*cnt;
  float s0=0.f, s1=0.f, s2=0.f, s3=0.f;
  if (cnt >= 2048){            // 8 independent streams
    long oct = cnt >> 3;
    float s[8] = {0.f,0.f,0.f,0.f,0.f,0.f,0.f,0.f};
    for (long j = threadIdx.x; j < oct; j += 256){
#pragma unroll
      for (int k=0;k<8;k++){
        float4 a = p[j + (long)k*oct];
        s[k] += fabsf(a.x)+fabsf(a.y)+fabsf(a.z)+fabsf(a.w);
      }
    }
    s0 = s[0]+s[4]; s1 = s[1]+s[5]; s2 = s[2]+s[6]; s3 = s[3]+s[7];
  } else if (cnt >= 1024){
    long quar = cnt >> 2;
    const float4* p1 = p + quar;
    const float4* p2 = p + 2*quar;
    const float4* p3 = p + 3*quar;
    for (long j = threadIdx.x; j < quar; j += 256){
      float4 a = p[j], b = p1[j], c = p2[j], d = p3[j];
      s0 += fabsf(a.x)+fabsf(a.y)+fabsf(a.z)+fabsf(a.w);
      s1 += fabsf(b.x)+fabsf(b.y)+fabsf(b.z)+fabsf(b.w);
      s2 += fabsf(c.x)+fabsf(c.y)+fabsf(c.z)+fabsf(c.w);
      s3 += fabsf(d.x)+fabsf(d.y)+fabsf(d.z)+fabsf(d.w);
    }
  } else {
    for (long j = threadIdx.x; j < cnt; j += 256){
      float4 a = p[j];
      s0 += fabsf(a.x)+fabsf(a.y)+fabsf(a.z)+fabsf(a.w);
    }
  }
  float s = bredsum(s0+s1+s2+s3, red);
  if (threadIdx.x==0) part[(long)mat*1024 + seg] = s;
}

__global__ __launch_bounds__(256) void finalize_scales_k(const float* __restrict__ part,
                                                         float* __restrict__ scales){
  __shared__ float red[4];
  const long numel[18] = {1048576, 1048576,1048576, 1048576,1048576, 1048576,1048576,
                          1048576,1048576, 4194304,4194304, 4194304,4194304, 4194304,4194304,
                          32768, 32768, 1024};
  int t = threadIdx.x;
  for (int m=0;m<18;m++){
    int segs = (m >= 9 && m < 15) ? 1024 : 256;
    float v = 0.f;
    for (int j=t; j<segs; j+=256) v += part[(long)m*1024 + j];
    v = bredsum(v, red);
    if (t==0) scales[m] = v/(float)numel[m] + 1e-8f;
  }
  if (t==0){
    for (int l=0;l<2;l++){
      scales[18+l*3+0] = scales[1+l];   // wq
      scales[18+l*3+1] = scales[3+l];   // wk
      scales[18+l*3+2] = scales[5+l];   // wv
      scales[24+l*2+0] = scales[9+l];   // wg
      scales[24+l*2+1] = scales[11+l];  // wu
    }
  }
}

__global__ __launch_bounds__(256) void quantw_all_k(WSetup wsu, const float* __restrict__ scales){
  int bid = blockIdx.x;
  int mat = 0, c = 0;
  for (;;){
    int nb = mat<9 ? 256 : (mat<15 ? 1024 : (mat<17 ? 8 : 1));
    if (bid < c + nb) break;
    c += nb; mat++;
  }
  long seg = bid - c;
  long n4 = n4of(mat);
  float s = scales[mat];
  int md = wsu.mode[mat];
  const float4* src = (const float4*)wsu.src[mat];
  char4* dst = (char4*)wsu.dst[mat];
  long base = seg*1024;
#pragma unroll
  for (int k=0;k<4;k++){
    long i = base + k*256 + threadIdx.x;
    if (i < n4){
      float4 v = src[i];
      char4 q;
      q.x = f2i8(fminf(fmaxf(rintf(v.x/s), -1.f), 1.f));
      q.y = f2i8(fminf(fmaxf(rintf(v.y/s), -1.f), 1.f));
      q.z = f2i8(fminf(fmaxf(rintf(v.z/s), -1.f), 1.f));
      q.w = f2i8(fminf(fmaxf(rintf(v.w/s), -1.f), 1.f));
      if (md == 0) dst[i] = q;
      else {
        long r = i >> 8, cc = i & 255;    // K=1024 -> 256 char4/row
        dst[(((r<<1) | (md-1))<<8) | cc] = q;
      }
    }
  }
}

// ---------------- row quant (1024 wide) -> i8; input f32 or bf16 ----------------
template<bool BF>
__global__ __launch_bounds__(256) void rowquant1k_k(const void* __restrict__ xin,
                                                    signed char* __restrict__ xq,
                                                    float* __restrict__ rs){
  __shared__ float red[4];
  int m = blockIdx.x, t = threadIdx.x;
  float v[4];
  if (BF){
    ushort4 u = *(const ushort4*)((const unsigned short*)xin + (size_t)m*1024 + t*4);
    v[0]=bf2f(u.x); v[1]=bf2f(u.y); v[2]=bf2f(u.z); v[3]=bf2f(u.w);
  } else {
    float4 f = *(const float4*)((const float*)xin + (size_t)m*1024 + t*4);
    v[0]=f.x; v[1]=f.y; v[2]=f.z; v[3]=f.w;
  }
  float am = fmaxf(fmaxf(fabsf(v[0]),fabsf(v[1])),fmaxf(fabsf(v[2]),fabsf(v[3])));
  am = bredmax(am, red);
  float a = fmaxf(am, 1e-8f), inv = 127.f/a;
  char4 q;
  q.x = f2i8(fminf(fmaxf(rintf(v[0]*inv),-128.f),127.f));
  q.y = f2i8(fminf(fmaxf(rintf(v[1]*inv),-128.f),127.f));
  q.z = f2i8(fminf(fmaxf(rintf(v[2]*inv),-128.f),127.f));
  q.w = f2i8(fminf(fmaxf(rintf(v[3]*inv),-128.f),127.f));
  *(char4*)(xq + (size_t)m*1024 + t*4) = q;
  if (t==0) rs[m] = a/127.f;
}

// ---------------- row quant (4096 wide, bf16 input) -> i8 ----------------
__global__ __launch_bounds__(256) void rowquant4k_k(const unsigned short* __restrict__ x,
                                                    signed char* __restrict__ xq,
                                                    float* __restrict__ rs){
  __shared__ float red[4];
  int m = blockIdx.x, t = threadIdx.x;
  const unsigned short* p = x + (size_t)m*4096 + t*16;
  u16x8 u0 = *(const u16x8*)p;
  u16x8 u1 = *(const u16x8*)(p + 8);
  float v[16];
#pragma unroll
  for (int j=0;j<8;j++){ v[j] = bf2f(u0[j]); v[j+8] = bf2f(u1[j]); }
  float am = 0.f;
#pragma unroll
  for (int j=0;j<16;j++) am = fmaxf(am, fabsf(v[j]));
  am = bredmax(am, red);
  float a = fmaxf(am, 1e-8f), inv = 127.f/a;
#pragma unroll
  for (int j=0;j<16;j+=4){
    char4 q;
    q.x = f2i8(fminf(fmaxf(rintf(v[j+0]*inv),-128.f),127.f));
    q.y = f2i8(fminf(fmaxf(rintf(v[j+1]*inv),-128.f),127.f));
    q.z = f2i8(fminf(fmaxf(rintf(v[j+2]*inv),-128.f),127.f));
    q.w = f2i8(fminf(fmaxf(rintf(v[j+3]*inv),-128.f),127.f));
    *(char4*)(xq + (size_t)m*4096 + t*16 + j) = q;
  }
  if (t==0) rs[m] = a/127.f;
}

// ---------------- fused: h_in = rmsnorm(h+delta, lnw); a_in quant with n1 ----------------
__global__ __launch_bounds__(256) void loopnorm_quant_k(const float* __restrict__ h,
                                                        const float* __restrict__ delta,
                                                        const float* __restrict__ lnw,
                                                        const float* __restrict__ n1,
                                                        float* __restrict__ hin,
                                                        signed char* __restrict__ xq,
                                                        float* __restrict__ rs){
  __shared__ float red[4];
  int m = blockIdx.x, t = threadIdx.x;
  int b = m >> 9;
  float v[4];
  float4 f = *(const float4*)(h + (size_t)m*1024 + t*4);
  v[0]=f.x; v[1]=f.y; v[2]=f.z; v[3]=f.w;
  if (t < 16){
#pragma unroll
    for (int j=0;j<4;j++) v[j] += delta[b*64 + t*4 + j];
  }
  float ss = v[0]*v[0]+v[1]*v[1]+v[2]*v[2]+v[3]*v[3];
  ss = bredsum(ss, red);
  float r1 = rsqrtf(ss*(1.f/1024.f) + 1e-6f);
  float w4[4];
#pragma unroll
  for (int j=0;j<4;j++) w4[j] = v[j]*r1*lnw[t*4+j];
  float4 of; of.x=w4[0]; of.y=w4[1]; of.z=w4[2]; of.w=w4[3];
  *(float4*)(hin + (size_t)m*1024 + t*4) = of;
  float s2 = w4[0]*w4[0]+w4[1]*w4[1]+w4[2]*w4[2]+w4[3]*w4[3];
  s2 = bredsum(s2, red);
  float r2 = rsqrtf(s2*(1.f/1024.f) + 1e-6f);
  float y[4];
#pragma unroll
  for (int j=0;j<4;j++) y[j] = w4[j]*r2*n1[t*4+j];
  float am = fmaxf(fmaxf(fabsf(y[0]),fabsf(y[1])),fmaxf(fabsf(y[2]),fabsf(y[3])));
  am = bredmax(am, red);
  float a = fmaxf(am, 1e-8f), inv = 127.f/a;
  char4 q;
  q.x = f2i8(fminf(fmaxf(rintf(y[0]*inv),-128.f),127.f));
  q.y = f2i8(fminf(fmaxf(rintf(y[1]*inv),-128.f),127.f));
  q.z = f2i8(fminf(fmaxf(rintf(y[2]*inv),-128.f),127.f));
  q.w = f2i8(fminf(fmaxf(rintf(y[3]*inv),-128.f),127.f));
  *(char4*)(xq + (size_t)m*1024 + t*4) = q;
  if (t==0) rs[m] = a/127.f;
}

// ---------------- i8 MFMA GEMM (triple-buffered, 2-deep prefetch, swizzled) ----------------
DEV f32x4 accfence(f32x4 c){ asm volatile("s_nop 7\n\ts_nop 7" : "+v"(c)); return c; }
DEV i32x4 accfencei(i32x4 c){ asm volatile("s_nop 7\n\ts_nop 7" : "+v"(c)); return c; }

template<bool SPLITK, bool GUSILU>
__global__ __launch_bounds__(256)
void gemm_i8(const signed char* __restrict__ A, const signed char* __restrict__ W,
             const float* __restrict__ rowsc, const float* __restrict__ wscv,
             const float* __restrict__ res, float* __restrict__ C, int N, int Kf, int Kc)
{
  __shared__ __align__(16) signed char As[3][8192];
  __shared__ __align__(16) signed char Bs[3][8192];
  const int tid = threadIdx.x;
  const int lane = tid & 63, wvid = tid >> 6;
  const int wr = wvid >> 1, wc = wvid & 1;
  const int bm = blockIdx.y, bn = blockIdx.x;

  const int r0 = (wvid<<4) + (lane>>2);
  const int sw = (((lane&3) ^ ((r0>>1)&3)) << 4);        // byte offset of 16B chunk
  const long kstart = SPLITK ? (long)blockIdx.z * Kc : 0;
  const signed char* gA = A + (size_t)(bm*128 + r0)*Kf + kstart + sw;
  const signed char* gB = W + (size_t)(bn*128 + r0)*Kf + kstart + sw;
  const size_t row64 = (size_t)64*Kf;

#define STAGE(buf, koff) do { \
    __builtin_amdgcn_global_load_lds(gA + (koff),         &As[buf][(wvid<<10)],      16, 0, 0); \
    __builtin_amdgcn_global_load_lds(gA + (koff) + row64, &As[buf][(wvid<<10)+4096], 16, 0, 0); \
    __builtin_amdgcn_global_load_lds(gB + (koff),         &Bs[buf][(wvid<<10)],      16, 0, 0); \
    __builtin_amdgcn_global_load_lds(gB + (koff) + row64, &Bs[buf][(wvid<<10)+4096], 16, 0, 0); \
  } while(0)

  i32x4 acc[4][4] = {};
  const int rA = (wr<<6) + (lane&15);
  const int rB = (wc<<6) + (lane&15);
  const int psA = (((lane>>4) ^ (((lane&15)>>1)&3)) << 4);  // byte offset

  const int NT = Kc >> 6;   // >= 4 for all our shapes
  STAGE(0, 0);
  STAGE(1, 64);
  int cur = 0, nxt = 1, nx2 = 2;
  for (int kt = 0; kt < NT; ++kt){
    const int k2 = kt + 2;
    const int kn = (k2 < NT) ? (k2<<6) : 0;     // wrap: dead-buffer reload, keeps vmcnt count exact
    STAGE(nx2, kn);
    asm volatile("s_waitcnt vmcnt(8)" ::: "memory");   // tile kt's 4 DMAs done; 8 stay in flight
    __builtin_amdgcn_s_barrier();
    asm volatile("" ::: "memory");
    i32x4 a[4], b[4];
    const signed char* Ab = As[cur];
    const signed char* Bb = Bs[cur];
#pragma unroll
    for (int mi=0;mi<4;mi++) a[mi] = *(const i32x4*)(Ab + (rA + mi*16)*64 + psA);
#pragma unroll
    for (int ni=0;ni<4;ni++) b[ni] = *(const i32x4*)(Bb + (rB + ni*16)*64 + psA);
#pragma unroll
    for (int mi=0;mi<4;mi++)
#pragma unroll
      for (int ni=0;ni<4;ni++)
        asm("v_mfma_i32_16x16x64_i8 %0, %1, %2, %0" : "+v"(acc[mi][ni]) : "v"(a[mi]), "v"(b[ni]));
    asm volatile("s_waitcnt lgkmcnt(0)" ::: "memory");
    __builtin_amdgcn_s_barrier();
    int tmp = cur; cur = nxt; nxt = nx2; nx2 = tmp;
  }
#undef STAGE

#pragma unroll
  for (int mi=0;mi<4;mi++)
#pragma unroll
    for (int ni=0;ni<4;ni++)
      acc[mi][ni] = accfencei(acc[mi][ni]);

  const int rif = (lane>>4)<<2;
  const int cif = lane&15;
  const int gcol0 = bn*128 + (wc<<6);

  if constexpr (SPLITK){
    float* P = C + (size_t)blockIdx.z * ((size_t)N << 10);
#pragma unroll
    for (int mi=0;mi<4;mi++)
#pragma unroll
      for (int r=0;r<4;r++){
        const int grow = bm*128 + (wr<<6) + mi*16 + rif + r;
#pragma unroll
        for (int ni=0;ni<4;ni++)
          P[(size_t)grow*N + gcol0 + ni*16 + cif] = (float)acc[mi][ni][r];
      }
    return;
  }

  if constexpr (GUSILU){
    const float sg = wscv[0], su = wscv[1];
    unsigned short* Cb = (unsigned short*)C;   // bf16 [M][4096]
#pragma unroll
    for (int mi=0;mi<4;mi++){
#pragma unroll
      for (int r=0;r<4;r++){
        const int grow = bm*128 + (wr<<6) + mi*16 + rif + r;
        const float rsc = rowsc[grow];
#pragma unroll
        for (int ni=0;ni<4;ni++){
          const int gcol = gcol0 + ni*16 + cif;
          float val = (float)acc[mi][ni][r] * rsc * ((gcol & 1) ? su : sg);
          float other = __shfl_xor(val, 1);
          if (!(lane & 1)){
            float g = val, u = other;
            float outv = g/(1.f+expf(-g))*u;
            Cb[(size_t)grow*4096 + (gcol>>1)] = f2bfr(outv);
          }
        }
      }
    }
    return;
  }

#pragma unroll
  for (int mi=0;mi<4;mi++){
#pragma unroll
    for (int r=0;r<4;r++){
      const int grow = bm*128 + (wr<<6) + mi*16 + rif + r;
      const float rsc = rowsc[grow];
#pragma unroll
      for (int ni=0;ni<4;ni++){
        const int gcol = gcol0 + ni*16 + cif;
        float vvv = (float)acc[mi][ni][r] * rsc * wscv[0];
        const size_t off = (size_t)grow*N + gcol;
        if (res) vvv += res[off];
        C[off] = vvv;
      }
    }
  }
}

// ---------------- qkv GEMM: same triple-buffered loop + rope epilogue -> bf16 ----------------
// grid (24, 8). N=3072, K=1024. Each 64-col half-tile (wc) is one head-section.
__global__ __launch_bounds__(256)
void gemm_qkv128(const signed char* __restrict__ A, const signed char* __restrict__ W,
                 const float* __restrict__ rowsc, const float* __restrict__ wscv,
                 const float* __restrict__ tab, unsigned short* __restrict__ C)
{
  __shared__ __align__(16) signed char As[3][8192];
  __shared__ __align__(16) signed char Bs[3][8192];
  const int tid = threadIdx.x;
  const int lane = tid & 63, wvid = tid >> 6;
  const int wr = wvid >> 1, wc = wvid & 1;
  const int bm = blockIdx.y, bn = blockIdx.x;
  const int Kf = 1024;

  const int r0 = (wvid<<4) + (lane>>2);
  const int sw = (((lane&3) ^ ((r0>>1)&3)) << 4);
  const signed char* gA = A + (size_t)(bm*128 + r0)*Kf + sw;
  const signed char* gB = W + (size_t)(bn*128 + r0)*Kf + sw;
  const size_t row64 = (size_t)64*Kf;

#define STAGE(buf, koff) do { \
    __builtin_amdgcn_global_load_lds(gA + (koff),         &As[buf][(wvid<<10)],      16, 0, 0); \
    __builtin_amdgcn_global_load_lds(gA + (koff) + row64, &As[buf][(wvid<<10)+4096], 16, 0, 0); \
    __builtin_amdgcn_global_load_lds(gB + (koff),         &Bs[buf][(wvid<<10)],      16, 0, 0); \
    __builtin_amdgcn_global_load_lds(gB + (koff) + row64, &Bs[buf][(wvid<<10)+4096], 16, 0, 0); \
  } while(0)

  i32x4 acc[4][4] = {};
  const int rA = (wr<<6) + (lane&15);
  const int rB = (wc<<6) + (lane&15);
  const int psA = (((lane>>4) ^ (((lane&15)>>1)&3)) << 4);

  const int NT = 16;
  STAGE(0, 0);
  STAGE(1, 64);
  int cur = 0, nxt = 1, nx2 = 2;
  for (int kt = 0; kt < NT; ++kt){
    const int k2 = kt + 2;
    const int kn = (k2 < NT) ? (k2<<6) : 0;
    STAGE(nx2, kn);
    asm volatile("s_waitcnt vmcnt(8)" ::: "memory");
    __builtin_amdgcn_s_barrier();
    asm volatile("" ::: "memory");
    i32x4 a[4], b[4];
    const signed char* Ab = As[cur];
    const signed char* Bb = Bs[cur];
#pragma unroll
    for (int mi=0;mi<4;mi++) a[mi] = *(const i32x4*)(Ab + (rA + mi*16)*64 + psA);
#pragma unroll
    for (int ni=0;ni<4;ni++) b[ni] = *(const i32x4*)(Bb + (rB + ni*16)*64 + psA);
#pragma unroll
    for (int mi=0;mi<4;mi++)
#pragma unroll
      for (int ni=0;ni<4;ni++)
        asm("v_mfma_i32_16x16x64_i8 %0, %1, %2, %0" : "+v"(acc[mi][ni]) : "v"(a[mi]), "v"(b[ni]));
    asm volatile("s_waitcnt lgkmcnt(0)" ::: "memory");
    __builtin_amdgcn_s_barrier();
    int tmp = cur; cur = nxt; nxt = nx2; nx2 = tmp;
  }
#undef STAGE

#pragma unroll
  for (int mi=0;mi<4;mi++)
#pragma unroll
    for (int ni=0;ni<4;ni++)
      acc[mi][ni] = accfencei(acc[mi][ni]);

  const int rif = (lane>>4)<<2;
  const int cif = lane&15;
  const int gcol0 = bn*128 + (wc<<6);     // head-aligned 64-col span
  const int sec = gcol0 >> 10;            // 0=q, 1=k, 2=v
  const float wsc = wscv[sec] * ((sec==0) ? 0.125f : 1.f);

  if (sec < 2){
    // rope: col d pairs with d+32 -> acc[mi][np] with acc[mi][np+2], np in {0,1}
#pragma unroll
    for (int mi=0;mi<4;mi++){
#pragma unroll
      for (int r=0;r<4;r++){
        const int grow = bm*128 + (wr<<6) + mi*16 + rif + r;
        const float s = rowsc[grow] * wsc;
        const int tpos = grow & 511;
#pragma unroll
        for (int np=0;np<2;np++){
          const int d = np*16 + cif;
          float2 cs = *(const float2*)(tab + (size_t)((tpos<<5) + d)*2);
          float x1 = (float)acc[mi][np][r]   * s;
          float x2 = (float)acc[mi][np+2][r] * s;
          C[(size_t)grow*3072 + gcol0 + d]      = f2bfr(x1*cs.x - x2*cs.y);
          C[(size_t)grow*3072 + gcol0 + 32 + d] = f2bfr(x1*cs.y + x2*cs.x);
        }
      }
    }
  } else {
#pragma unroll
    for (int mi=0;mi<4;mi++){
#pragma unroll
      for (int r=0;r<4;r++){
        const int grow = bm*128 + (wr<<6) + mi*16 + rif + r;
        const float s = rowsc[grow] * wsc;
#pragma unroll
        for (int ni=0;ni<4;ni++)
          C[(size_t)grow*3072 + gcol0 + ni*16 + cif] = f2bfr((float)acc[mi][ni][r] * s);
      }
    }
  }
}

// ---------------- split-K(4) reduce: C = (res?) + (sum P)*rowsc*wsc ----------------
__global__ __launch_bounds__(256) void reduce4_k(const float* __restrict__ P,
                                                 const float* __restrict__ rowsc,
                                                 const float* __restrict__ wsc,
                                                 const float* __restrict__ res,
                                                 float* __restrict__ C){
  int m = blockIdx.x, t = threadIdx.x;
  float s0 = rowsc[m] * wsc[0];
  size_t off = (size_t)m*1024 + t*4;
  float4 a = *(const float4*)(P + off);
  float4 b = *(const float4*)(P + 1048576 + off);
  float4 c = *(const float4*)(P + 2097152 + off);
  float4 d = *(const float4*)(P + 3145728 + off);
  float4 o;
  o.x = (a.x+b.x+c.x+d.x)*s0;
  o.y = (a.y+b.y+c.y+d.y)*s0;
  o.z = (a.z+b.z+c.z+d.z)*s0;
  o.w = (a.w+b.w+c.w+d.w)*s0;
  if (res){
    float4 r = *(const float4*)(res + off);
    o.x += r.x; o.y += r.y; o.z += r.z; o.w += r.w;
  }
  *(float4*)(C + off) = o;
}

// ---------------- fused: split-K(4) reduce + residual + rmsnorm + quant ----------------
__global__ __launch_bounds__(256) void redq_norm_k(const float* __restrict__ P,
                                                   const float* rowsc,
                                                   const float* __restrict__ wsc,
                                                   const float* __restrict__ res,
                                                   const float* __restrict__ gamma,
                                                   float* __restrict__ Cout,
                                                   signed char* __restrict__ xq,
                                                   float* rs){
  __shared__ float red[4];
  int m = blockIdx.x, t = threadIdx.x;
  float s0 = rowsc[m] * wsc[0];
  size_t off = (size_t)m*1024 + t*4;
  float4 a = *(const float4*)(P + off);
  float4 b = *(const float4*)(P + 1048576 + off);
  float4 c = *(const float4*)(P + 2097152 + off);
  float4 d = *(const float4*)(P + 3145728 + off);
  float4 r4 = *(const float4*)(res + off);
  float v[4];
  v[0] = r4.x + (a.x+b.x+c.x+d.x)*s0;
  v[1] = r4.y + (a.y+b.y+c.y+d.y)*s0;
  v[2] = r4.z + (a.z+b.z+c.z+d.z)*s0;
  v[3] = r4.w + (a.w+b.w+c.w+d.w)*s0;
  float4 of; of.x=v[0]; of.y=v[1]; of.z=v[2]; of.w=v[3];
  *(float4*)(Cout + off) = of;
  float ss = v[0]*v[0]+v[1]*v[1]+v[2]*v[2]+v[3]*v[3];
  ss = bredsum(ss, red);
  float r1 = rsqrtf(ss*(1.f/1024.f) + 1e-6f);
  float y[4];
#pragma unroll
  for (int j=0;j<4;j++) y[j] = v[j]*r1*gamma[t*4+j];
  float am = fmaxf(fmaxf(fabsf(y[0]),fabsf(y[1])),fmaxf(fabsf(y[2]),fabsf(y[3])));
  am = bredmax(am, red);
  float aq = fmaxf(am, 1e-8f), inv = 127.f/aq;
  char4 q;
  q.x = f2i8(fminf(fmaxf(rintf(y[0]*inv),-128.f),127.f));
  q.y = f2i8(fminf(fmaxf(rintf(y[1]*inv),-128.f),127.f));
  q.z = f2i8(fminf(fmaxf(rintf(y[2]*inv),-128.f),127.f));
  q.w = f2i8(fminf(fmaxf(rintf(y[3]*inv),-128.f),127.f));
  *(char4*)(xq + (size_t)m*1024 + t*4) = q;
  if (t==0) rs[m] = aq/127.f;
}

// ---------------- fused tail: reduce + recurrence + quant + loraDown + topk
//                  + loraUp + act-sigmoid + h_out + ponder (+ next-iter loopnorm) ----------------
__global__ __launch_bounds__(256) void redfin_k(const float* __restrict__ P,
                                                const float* __restrict__ rowsc,
                                                const float* __restrict__ wsc,
                                                const float* __restrict__ res,
                                                float* __restrict__ h,
                                                const float* __restrict__ Be,
                                                const float* __restrict__ Araw,
                                                const float* __restrict__ alpha, int it,
                                                const signed char* __restrict__ ldq,
                                                const float* __restrict__ sld,
                                                const signed char* __restrict__ luq,
                                                const float* __restrict__ slu,
                                                const signed char* __restrict__ actq,
                                                const float* __restrict__ sact,
                                                const float* __restrict__ ig,
                                                float* __restrict__ hout,
                                                float* __restrict__ ponder,
                                                const float* __restrict__ dnext,
                                                const float* __restrict__ lnw,
                                                const float* __restrict__ n1,
                                                float* __restrict__ hin,
                                                signed char* __restrict__ xqn,
                                                float* __restrict__ rsn,
                                                int doNext){
  __shared__ float red[4];
  __shared__ float xrow[1024];
  __shared__ float part[256];
  __shared__ float xs[32];
  __shared__ float sh_thr, sh_gs;
  int m = blockIdx.x, t = threadIdx.x;
  float al = alpha[it];
  float s0 = rowsc[m] * wsc[0];
  size_t off = (size_t)m*1024 + t*4;
  float4 a = *(const float4*)(P + off);
  float4 b = *(const float4*)(P + 1048576 + off);
  float4 c = *(const float4*)(P + 2097152 + off);
  float4 d = *(const float4*)(P + 3145728 + off);
  float4 r4 = *(const float4*)(res + off);
  float4 hh = *(const float4*)(h + off);
  float4 be = *(const float4*)(Be + off);
  float4 ar = *(const float4*)(Araw + t*4);
  float v[4];
  v[0] = 0.99f*tanhf(ar.x)*hh.x + be.x + al*(r4.x + (a.x+b.x+c.x+d.x)*s0);
  v[1] = 0.99f*tanhf(ar.y)*hh.y + be.y + al*(r4.y + (a.y+b.y+c.y+d.y)*s0);
  v[2] = 0.99f*tanhf(ar.z)*hh.z + be.z + al*(r4.z + (a.z+b.z+c.z+d.z)*s0);
  v[3] = 0.99f*tanhf(ar.w)*hh.w + be.w + al*(r4.w + (a.w+b.w+c.w+d.w)*s0);
  float am = fmaxf(fmaxf(fabsf(v[0]),fabsf(v[1])),fmaxf(fabsf(v[2]),fabsf(v[3])));
  am = bredmax(am, red);
  float aq = fmaxf(am, 1e-8f), inv = 127.f/aq;
#pragma unroll
  for (int j=0;j<4;j++) xrow[t*4+j] = fminf(fmaxf(rintf(v[j]*inv),-128.f),127.f);
  float rsv = aq/127.f;
  __syncthreads();
  {
    int r = t & 31, seg = t >> 5;
    const signed char* wrow = ldq + (size_t)r*1024 + seg*128;
    const float* xr = xrow + seg*128;
    float acc = 0.f;
    for (int k=0;k<128;k+=4){
      char4 w4 = *(const char4*)(wrow + k);
      acc += xr[k]*(float)w4.x + xr[k+1]*(float)w4.y + xr[k+2]*(float)w4.z + xr[k+3]*(float)w4.w;
    }
    part[t] = acc;
  }
  __syncthreads();
  if (t < 32){
    float s = 0.f;
    for (int sg=0; sg<8; sg++) s += part[sg*32 + t];
    xs[t] = s * rsv * (*sld);
  }
  __syncthreads();
  float val = 0.f, av = 0.f, amax = 0.f;
  if (t < 32){
    val = xs[t]; av = fabsf(val);
    int rank = 0;
    for (int j=0;j<32;j++){
      float aj = fabsf(xs[j]);
      amax = fmaxf(amax, aj);
      if (aj > av || (aj == av && j < t)) rank++;
    }
    if (rank == 17) sh_thr = av;
  }
  __syncthreads();
  if (t < 32){
    float a2 = fmaxf(amax, 1e-8f);
    float q = 0.f;
    if (av >= sh_thr) q = fminf(fmaxf(rintf(val*(127.f/a2)), -128.f), 127.f);
    xs[t] = q;
    if (t == 0) sh_gs = ig[it] * (*slu) * (a2/127.f);
  }
  __syncthreads();
  float gs = sh_gs;
  float hn[4];
  int n0 = t*4;
#pragma unroll
  for (int ni=0;ni<4;ni++){
    const signed char* lr = luq + (size_t)(n0+ni)*32;
    float dd = 0.f;
    for (int k=0;k<32;k+=4){
      char4 w4 = *(const char4*)(lr + k);
      dd += xs[k]*(float)w4.x + xs[k+1]*(float)w4.y + xs[k+2]*(float)w4.z + xs[k+3]*(float)w4.w;
    }
    hn[ni] = v[ni] + gs*dd;
  }
  float am2 = fmaxf(fmaxf(fabsf(hn[0]),fabsf(hn[1])),fmaxf(fabsf(hn[2]),fabsf(hn[3])));
  am2 = bredmax(am2, red);
  float a2 = fmaxf(am2, 1e-8f), inv2 = 127.f/a2;
  float zp = 0.f;
#pragma unroll
  for (int ni=0;ni<4;ni++){
    float q = fminf(fmaxf(rintf(hn[ni]*inv2),-128.f),127.f);
    zp += q * (float)actq[n0+ni];
  }
  zp = bredsum(zp, red);
  float z = zp * (a2/127.f) * (*sact);
  float wv = 1.f/(1.f+expf(-z));
#pragma unroll
  for (int ni=0;ni<4;ni++){
    size_t o2 = (size_t)m*1024 + n0+ni;
    float ho = hout[o2];
    hout[o2] = ho + wv*(hn[ni]-ho);
    h[o2] = hn[ni];
  }
  if (t==0) atomicAdd(ponder, wv * (1.f/8192.f));

  // ---- fused next-iteration loopnorm + quant ----
  if (doNext){
    int b2 = m >> 9;
    float v2[4] = {hn[0], hn[1], hn[2], hn[3]};
    if (t < 16){
#pragma unroll
      for (int j=0;j<4;j++) v2[j] += dnext[b2*64 + t*4 + j];
    }
    float ss2 = v2[0]*v2[0]+v2[1]*v2[1]+v2[2]*v2[2]+v2[3]*v2[3];
    ss2 = bredsum(ss2, red);
    float r1 = rsqrtf(ss2*(1.f/1024.f) + 1e-6f);
    float w4[4];
#pragma unroll
    for (int j=0;j<4;j++) w4[j] = v2[j]*r1*lnw[t*4+j];
    float4 of; of.x=w4[0]; of.y=w4[1]; of.z=w4[2]; of.w=w4[3];
    *(float4*)(hin + off) = of;
    float s2 = w4[0]*w4[0]+w4[1]*w4[1]+w4[2]*w4[2]+w4[3]*w4[3];
    s2 = bredsum(s2, red);
    float r2 = rsqrtf(s2*(1.f/1024.f) + 1e-6f);
    float y[4];
#pragma unroll
    for (int j=0;j<4;j++) y[j] = w4[j]*r2*n1[t*4+j];
    float am3 = fmaxf(fmaxf(fabsf(y[0]),fabsf(y[1])),fmaxf(fabsf(y[2]),fabsf(y[3])));
    am3 = bredmax(am3, red);
    float aq3 = fmaxf(am3, 1e-8f), inv3 = 127.f/aq3;
    char4 q;
    q.x = f2i8(fminf(fmaxf(rintf(y[0]*inv3),-128.f),127.f));
    q.y = f2i8(fminf(fmaxf(rintf(y[1]*inv3),-128.f),127.f));
    q.z = f2i8(fminf(fmaxf(rintf(y[2]*inv3),-128.f),127.f));
    q.w = f2i8(fminf(fmaxf(rintf(y[3]*inv3),-128.f),127.f));
    *(char4*)(xqn + off) = q;
    if (t==0) rsn[m] = aq3/127.f;
  }
}

// ---------------- MFMA flash attention, split-k over 4 blocks; f32 partial out ----------------
DEV int swz64(int r, int c){ return r*64 + (c ^ ((r&7)<<3)); }

__global__ __launch_bounds__(256) void attn_split_k(const unsigned short* __restrict__ qkv,
                                                    float* __restrict__ Opart,
                                                    float* __restrict__ ml){
  __shared__ __align__(16) unsigned short Qs[4096];
  __shared__ __align__(16) unsigned short Ks[4096];
  __shared__ __align__(16) unsigned short Vt[4096];   // [d][k], swizzled on d
  __shared__ __align__(16) unsigned short Ps[4][1024];
  const int tid = threadIdx.x;
  const int lane = tid & 63, wv = tid >> 6;
  const int bidl = blockIdx.x & 255;
  const int z = blockIdx.x >> 8;          // 0..3
  const int qt = bidl & 7, bh = bidl >> 3;
  const int b = bh >> 4, h = bh & 15;
  const int tokb = b*512;
  const int l15 = lane & 15, lh = lane >> 4;

  { // stage Q (already scaled by 1/8)
    int r = tid >> 2, c0 = (tid & 3) << 4;
    const unsigned short* s = qkv + (size_t)(tokb + qt*64 + r)*3072 + h*64 + c0;
    u16x8 f0 = *(const u16x8*)s, f1 = *(const u16x8*)(s+8);
    *(u16x8*)(Qs + swz64(r, c0))   = f0;
    *(u16x8*)(Qs + swz64(r, c0+8)) = f1;
  }

  float m_run[4] = {-1e30f,-1e30f,-1e30f,-1e30f};
  float l_run[4] = {0.f,0.f,0.f,0.f};
  f32x4 accO[4] = {};

  const int nt = qt + 1;
  const int base = nt >> 2, rem = nt & 3;
  const int kA = z*base + (z < rem ? z : rem);
  const int kB = kA + base + (z < rem ? 1 : 0);

  for (int kt = kA; kt < kB; ++kt){
    __syncthreads();
    { // stage K
      int r = tid >> 2, c0 = (tid & 3) << 4;
      const unsigned short* s = qkv + (size_t)(tokb + kt*64 + r)*3072 + 1024 + h*64 + c0;
      u16x8 f0 = *(const u16x8*)s, f1 = *(const u16x8*)(s+8);
      *(u16x8*)(Ks + swz64(r, c0))   = f0;
      *(u16x8*)(Ks + swz64(r, c0+8)) = f1;
    }
    { // stage V transposed
      int r0 = (tid >> 3) << 1, cv = (tid & 7) << 3;
      const unsigned short* s0 = qkv + (size_t)(tokb + kt*64 + r0)*3072 + 2048 + h*64 + cv;
      u16x8 a = *(const u16x8*)s0;
      u16x8 b2 = *(const u16x8*)(s0 + 3072);
#pragma unroll
      for (int j=0;j<8;j++){
        int d = cv + j;
        unsigned int pk = (unsigned int)a[j] | ((unsigned int)b2[j]<<16);
        *(unsigned int*)(Vt + swz64(d, r0)) = pk;
      }
    }
    __syncthreads();

    f32x4 s4[4] = {};
#pragma unroll
    for (int kc=0; kc<2; ++kc){
      i32x4 aq = *(const i32x4*)(Qs + swz64(wv*16 + l15, kc*32 + lh*8));
#pragma unroll
      for (int nt2=0; nt2<4; ++nt2){
        i32x4 bk = *(const i32x4*)(Ks + swz64(nt2*16 + l15, kc*32 + lh*8));
        asm("v_mfma_f32_16x16x32_bf16 %0, %1, %2, %0" : "+v"(s4[nt2]) : "v"(aq), "v"(bk));
      }
    }
#pragma unroll
    for (int nt2=0; nt2<4; ++nt2) s4[nt2] = accfence(s4[nt2]);

    const bool diag = (kt == qt);
    float sf[4];
#pragma unroll
    for (int r=0;r<4;r++){
      int rl = lh*4 + r;
      float mx = -1e30f;
#pragma unroll
      for (int nt2=0; nt2<4; ++nt2){
        float v = s4[nt2][r];
        if (diag && (nt2*16 + l15) > (wv*16 + rl)) v = -1e30f;
        s4[nt2][r] = v;
        mx = fmaxf(mx, v);
      }
      mx = fmaxf(mx, __shfl_xor(mx,1));
      mx = fmaxf(mx, __shfl_xor(mx,2));
      mx = fmaxf(mx, __shfl_xor(mx,4));
      mx = fmaxf(mx, __shfl_xor(mx,8));
      float mn = fmaxf(m_run[r], mx);
      sf[r] = __expf(m_run[r] - mn);
      m_run[r] = mn;
      float ps = 0.f;
#pragma unroll
      for (int nt2=0; nt2<4; ++nt2){
        float p = __expf(s4[nt2][r] - mn);
        ps += p;
        Ps[wv][swz64(rl, nt2*16 + l15)] = f2bfr(p);
      }
      ps += __shfl_xor(ps,1); ps += __shfl_xor(ps,2);
      ps += __shfl_xor(ps,4); ps += __shfl_xor(ps,8);
      l_run[r] = l_run[r]*sf[r] + ps;
    }
#pragma unroll
    for (int dt=0; dt<4; ++dt){
#pragma unroll
      for (int r=0;r<4;r++) accO[dt][r] *= sf[r];
      accO[dt] = accfence(accO[dt]);
    }
#pragma unroll
    for (int kc=0; kc<2; ++kc){
      i32x4 pa = *(const i32x4*)(Ps[wv] + swz64(l15, kc*32 + lh*8));
#pragma unroll
      for (int dt=0; dt<4; ++dt){
        i32x4 vb3 = *(const i32x4*)(Vt + swz64(dt*16 + l15, kc*32 + lh*8));
        asm("v_mfma_f32_16x16x32_bf16 %0, %1, %2, %0" : "+v"(accO[dt]) : "v"(pa), "v"(vb3));
      }
    }
  }
#pragma unroll
  for (int dt=0; dt<4; ++dt) accO[dt] = accfence(accO[dt]);
  float* Op = Opart + ((size_t)z << 20);
#pragma unroll
  for (int r=0;r<4;r++){
    int row = tokb + qt*64 + wv*16 + lh*4 + r;
    float* op = Op + (size_t)row*1024 + h*64 + l15;
#pragma unroll
    for (int dt=0; dt<4; ++dt)
      op[dt*16] = accO[dt][r];
    if (l15 == 0){
      float2 v2 = make_float2(m_run[r], l_run[r]);
      *(float2*)(ml + ((size_t)(z*16 + h)*1024 + row)*2) = v2;
    }
  }
}

// ---------------- merge four attn partials + row quant -> i8 ----------------
__global__ __launch_bounds__(256) void attn_merge_quant_k(const float* __restrict__ Opart,
                                                          const float* __restrict__ ml,
                                                          signed char* __restrict__ xq,
                                                          float* __restrict__ rs){
  __shared__ float red[4];
  int m = blockIdx.x, t = threadIdx.x;
  int head = t >> 4;                       // 4 cols per thread, 4-aligned -> single head
  float2 mls[4];
#pragma unroll
  for (int z=0; z<4; ++z)
    mls[z] = *(const float2*)(ml + ((size_t)(z*16 + head)*1024 + m)*2);
  float mm = fmaxf(fmaxf(mls[0].x, mls[1].x), fmaxf(mls[2].x, mls[3].x));
  float w[4], lsum = 0.f;
#pragma unroll
  for (int z=0; z<4; ++z){ w[z] = __expf(mls[z].x - mm); lsum += mls[z].y * w[z]; }
  float invl = 1.f / lsum;
  size_t off = (size_t)m*1024 + t*4;
  float v[4] = {0.f,0.f,0.f,0.f};
#pragma unroll
  for (int z=0; z<4; ++z){
    float4 o = *(const float4*)(Opart + ((size_t)z << 20) + off);
    v[0] += o.x*w[z]; v[1] += o.y*w[z]; v[2] += o.z*w[z]; v[3] += o.w*w[z];
  }
  v[0] *= invl; v[1] *= invl; v[2] *= invl; v[3] *= invl;
  float am = fmaxf(fmaxf(fabsf(v[0]),fabsf(v[1])),fmaxf(fabsf(v[2]),fabsf(v[3])));
  am = bredmax(am, red);
  float a = fmaxf(am, 1e-8f), inv = 127.f/a;
  char4 q;
  q.x = f2i8(fminf(fmaxf(rintf(v[0]*inv),-128.f),127.f));
  q.y = f2i8(fminf(fmaxf(rintf(v[1]*inv),-128.f),127.f));
  q.z = f2i8(fminf(fmaxf(rintf(v[2]*inv),-128.f),127.f));
  q.w = f2i8(fminf(fmaxf(rintf(v[3]*inv),-128.f),127.f));
  *(char4*)(xq + (size_t)m*1024 + t*4) = q;
  if (t==0) rs[m] = a/127.f;
}

// ================= host =================
extern "C" void kernel_launch(void* const* d_in, const int* in_sizes, int n_in,
                              void* d_out, int out_size, void* d_ws, size_t ws_size,
                              hipStream_t stream)
{
  (void)in_sizes; (void)n_in;
  const float* x     = (const float*)d_in[0];
  const float* e     = (const float*)d_in[1];
  const float* temb  = (const float*)d_in[2];
  const float* bn1   = (const float*)d_in[3];
  const float* bwq   = (const float*)d_in[4];
  const float* bwk   = (const float*)d_in[5];
  const float* bwv   = (const float*)d_in[6];
  const float* bwo   = (const float*)d_in[7];
  const float* bn2   = (const float*)d_in[8];
  const float* bwg   = (const float*)d_in[9];
  const float* bwu   = (const float*)d_in[10];
  const float* bwd   = (const float*)d_in[11];
  const float* Araw  = (const float*)d_in[12];
  const float* Bw    = (const float*)d_in[13];
  const float* ldw   = (const float*)d_in[14];
  const float* luw   = (const float*)d_in[15];
  const float* ig    = (const float*)d_in[16];
  const float* actw  = (const float*)d_in[17];
  const float* alph  = (const float*)d_in[18];
  const float* lpw   = (const float*)d_in[19];
  const float* lp2w  = (const float*)d_in[20];
  const float* lp2b  = (const float*)d_in[21];
  const float* lnw   = (const float*)d_in[22];

  char* ws = (char*)d_ws;
  float* out = (float*)d_out;
  const size_t WS_NEEDED = 94600704ull;
  if (ws_size < WS_NEEDED){
    fill_k<<<(out_size+255)/256,256,0,stream>>>(out, out_size, 1.0e9f);
    return;
  }

  signed char* qw_qkv = (signed char*)(ws + 0);          // 6 MB
  signed char* qw_wo  = (signed char*)(ws + 6291456);    // 2 MB
  signed char* qw_gu  = (signed char*)(ws + 8388608);    // 16 MB (g/u row-interleaved)
  signed char* qw_wd  = (signed char*)(ws + 25165824);   // 8 MB
  signed char* qw_bw  = (signed char*)(ws + 33554432);   // 1 MB
  signed char* qw_ld  = (signed char*)(ws + 34603008);
  signed char* qw_lu  = (signed char*)(ws + 34635776);
  signed char* qw_act = (signed char*)(ws + 34668544);
  float* scales = (float*)(ws + 34669568);
  float* delta  = (float*)(ws + 34688512);
  float* hbuf   = (float*)(ws + 34692608);
  float* Bebuf  = (float*)(ws + 38886912);
  float* bufX   = (float*)(ws + 43081216);
  float* bufY   = (float*)(ws + 47275520);
  float* gub    = (float*)(ws + 51469824);               // scratch: partials / attn Opart(16MB) / silu out
  unsigned short* qkv_bf = (unsigned short*)(ws + 76635648);  // 6 MB bf16 qkv
  float* mlbuf  = (float*)(ws + 85024256);               // 512 KB attn m/l partials (4 z)
  signed char* xq1k = (signed char*)(ws + 89218560);
  float* rs1k   = (float*)(ws + 90267136);
  signed char* xqm  = (signed char*)(ws + 90271232);
  float* rsm    = (float*)(ws + 94465536);
  float* ropetab= (float*)(ws + 94469632);               // 128 KB
  float* part   = gub;                                   // absmean partials (setup only)

  // ---- setup: scales + ternary weights ----
  WSetup wsu;
  wsu.src[0]=Bw;
  wsu.src[1]=bwq; wsu.src[2]=bwq+1048576;
  wsu.src[3]=bwk; wsu.src[4]=bwk+1048576;
  wsu.src[5]=bwv; wsu.src[6]=bwv+1048576;
  wsu.src[7]=bwo; wsu.src[8]=bwo+1048576;
  wsu.src[9]=bwg; wsu.src[10]=bwg+4194304;
  wsu.src[11]=bwu; wsu.src[12]=bwu+4194304;
  wsu.src[13]=bwd; wsu.src[14]=bwd+4194304;
  wsu.src[15]=ldw; wsu.src[16]=luw; wsu.src[17]=actw;
  wsu.dst[0]=qw_bw;
  wsu.dst[1]=qw_qkv;             wsu.dst[2]=qw_qkv+3145728;
  wsu.dst[3]=qw_qkv+1048576;     wsu.dst[4]=qw_qkv+3145728+1048576;
  wsu.dst[5]=qw_qkv+2097152;     wsu.dst[6]=qw_qkv+3145728+2097152;
  wsu.dst[7]=qw_wo;              wsu.dst[8]=qw_wo+1048576;
  wsu.dst[9]=qw_gu;              wsu.dst[10]=qw_gu+8388608;
  wsu.dst[11]=qw_gu;             wsu.dst[12]=qw_gu+8388608;
  wsu.dst[13]=qw_wd;             wsu.dst[14]=qw_wd+4194304;
  wsu.dst[15]=qw_ld; wsu.dst[16]=qw_lu; wsu.dst[17]=qw_act;
  for (int i=0;i<18;i++) wsu.mode[i]=0;
  wsu.mode[9]=1;  wsu.mode[10]=1;   // wg -> even rows
  wsu.mode[11]=2; wsu.mode[12]=2;   // wu -> odd rows

  absmean_all_k<<<9216,256,0,stream>>>(wsu, part);
  finalize_scales_k<<<1,256,0,stream>>>(part, scales);
  quantw_all_k<<<8465,256,0,stream>>>(wsu, scales);

  // ---- misc setup (copy_init + delta + ropetab merged) ----
  setup_misc_k<<<1216,256,0,stream>>>(x, hbuf, out, temb, lpw, lp2w, lp2b, delta, ropetab);

  // Be = bitlinear(e, B_w)  (splitK x4)
  rowquant1k_k<false><<<1024,256,0,stream>>>(e, xq1k, rs1k);
  { dim3 g(8,8,4); gemm_i8<true,false><<<g,256,0,stream>>>(xq1k, qw_bw, nullptr, nullptr, nullptr, gub, 1024, 1024, 256); }
  reduce4_k<<<1024,256,0,stream>>>(gub, rs1k, scales+0, nullptr, Bebuf);

  // ---- main recurrent loop (n_loops = 8) ----
  for (int it=0; it<8; ++it){
    if (it==0)
      loopnorm_quant_k<<<1024,256,0,stream>>>(hbuf, delta, lnw, bn1, bufX, xq1k, rs1k);
    for (int l=0;l<2;l++){
      // qkv: 128x128 GEMM + fused scale/rope epilogue -> bf16 qkvb
      { dim3 g(24,8); gemm_qkv128<<<g,256,0,stream>>>(xq1k, qw_qkv + (size_t)l*3145728, rs1k, scales+18+l*3, ropetab, qkv_bf); }
      // attention split over 4 k-quarters (1024 blocks) + merge/quant
      attn_split_k<<<1024,256,0,stream>>>(qkv_bf, gub, mlbuf);
      attn_merge_quant_k<<<1024,256,0,stream>>>(gub, mlbuf, xq1k, rs1k);
      // wo (splitK x4) + fused reduce+residual+rmsnorm(bn2)+quant
      { dim3 g(8,8,4); gemm_i8<true,false><<<g,256,0,stream>>>(xq1k, qw_wo + (size_t)l*1048576, nullptr, nullptr, nullptr, gub, 1024, 1024, 256); }
      redq_norm_k<<<1024,256,0,stream>>>(gub, rs1k, scales+7+l, bufX, bn2 + (size_t)l*1024, bufY, xq1k, rs1k);
      // gu with fused silu epilogue -> bf16 [1024][4096]
      { dim3 g(64,8); gemm_i8<false,true><<<g,256,0,stream>>>(xq1k, qw_gu + (size_t)l*8388608, rs1k, scales+24+l*2, nullptr, gub, 8192, 1024, 1024); }
      rowquant4k_k<<<1024,256,0,stream>>>((const unsigned short*)gub, xqm, rsm);
      // wd (splitK x4)
      { dim3 g(8,8,4); gemm_i8<true,false><<<g,256,0,stream>>>(xqm, qw_wd + (size_t)l*4194304, nullptr, nullptr, nullptr, gub, 1024, 4096, 1024); }
      if (l==0){
        redq_norm_k<<<1024,256,0,stream>>>(gub, rsm, scales+13, bufY, bn1 + 1024, bufX, xq1k, rs1k);
      } else {
        redfin_k<<<1024,256,0,stream>>>(gub, rsm, scales+14, bufY, hbuf, Bebuf, Araw, alph, it,
                                        qw_ld, scales+15, qw_lu, scales+16, qw_act, scales+17,
                                        ig, out, out + 1048576,
                                        delta + (it+1 < 8 ? (it+1)*128 : 0), lnw, bn1, bufX, xq1k, rs1k,
                                        (it < 7) ? 1 : 0);
      }
    }
  }
}

// Round 14
// 1820.797 us; speedup vs baseline: 1.0410x; 1.0410x over previous
//
#include <hip/hip_runtime.h>
#include <stdint.h>

#define DEV static __device__ __forceinline__

typedef float f32x4 __attribute__((ext_vector_type(4)));
typedef int   i32x4 __attribute__((ext_vector_type(4)));
typedef unsigned short u16x8 __attribute__((ext_vector_type(8)));

DEV float bf2f(unsigned short u){ return __uint_as_float(((unsigned int)u)<<16); }
DEV unsigned short f2bfr(float f){ // round-to-nearest-even bf16
  unsigned int u = __float_as_uint(f);
  return (unsigned short)((u + 0x7FFF + ((u>>16)&1)) >> 16);
}
DEV signed char f2i8(float f){ return (signed char)(int)f; } // f already rint+clamped

// ---------------- block reductions (256-thread blocks, 4 waves) ----------------
DEV float wredsum(float v){
#pragma unroll
  for (int o=32;o;o>>=1) v += __shfl_xor(v,o);
  return v;
}
DEV float wredmax(float v){
#pragma unroll
  for (int o=32;o;o>>=1) v = fmaxf(v,__shfl_xor(v,o));
  return v;
}
DEV float bredsum(float v, float* red){
  v = wredsum(v);
  if ((threadIdx.x&63)==0) red[threadIdx.x>>6] = v;
  __syncthreads();
  float r = red[0]+red[1]+red[2]+red[3];
  __syncthreads();
  return r;
}
DEV float bredmax(float v, float* red){
  v = wredmax(v);
  if ((threadIdx.x&63)==0) red[threadIdx.x>>6] = v;
  __syncthreads();
  float r = fmaxf(fmaxf(red[0],red[1]),fmaxf(red[2],red[3]));
  __syncthreads();
  return r;
}

// ---------------- misc ----------------
__global__ void fill_k(float* p, int n, float v){
  int i = blockIdx.x*256 + threadIdx.x;
  if (i < n) p[i] = v;
}

// merged setup: copy_init (1024 blocks) + delta (128) + ropetab (64)
__global__ __launch_bounds__(256) void setup_misc_k(const float* __restrict__ x,
                                                    float* __restrict__ h, float* __restrict__ ho,
                                                    const float* __restrict__ temb,
                                                    const float* __restrict__ lpw,
                                                    const float* __restrict__ lp2w,
                                                    const float* __restrict__ lp2b,
                                                    float* __restrict__ delta,
                                                    float* __restrict__ tab){
  __shared__ float red[4];
  int bid = blockIdx.x, t = threadIdx.x;
  if (bid < 1024){
    int i = bid*256 + t;
    float4 v = *(const float4*)(x + (size_t)i*4);
    *(float4*)(h  + (size_t)i*4) = v;
    *(float4*)(ho + (size_t)i*4) = v;
    if (i==0) ho[1048576] = 0.f;
  } else if (bid < 1152){
    int blk = bid - 1024;
    int b = blk >> 6, j = blk & 63;
    float te = temb[b*256 + t];
    float p1 = bredsum(te * lpw[j*256 + t], red);
    float p2 = bredsum(te * lp2w[j*256 + t], red);
    if (t < 8){
      int i = t;
      float frac = (float)i / 7.f;
      int jj = j & 31;
      float fr = expf(-logf(10000.f) * (float)jj * (1.f/32.f));
      float ang = frac * fr;
      float sig = (j < 32) ? sinf(ang) : cosf(ang);
      delta[i*128 + b*64 + j] = sig*p1 + p2 + lp2b[j];
    }
  } else {
    int i = (bid-1152)*256 + t;   // 16384
    int tpos = i >> 5, d = i & 31;
    float inv = powf(10000.f, -(float)d * (1.f/32.f));
    float sv, cv; sincosf((float)tpos * inv, &sv, &cv);
    tab[i*2]   = cv;
    tab[i*2+1] = sv;
  }
}

// ---------------- fused setup: 18 weight matrices ----------------
struct WSetup {
  const float* src[18];
  signed char* dst[18];
  int mode[18];     // 0 normal; 1 row-interleave even; 2 row-interleave odd
};
DEV long n4of(int mat){ return mat<9 ? 262144 : (mat<15 ? 1048576 : (mat<17 ? 8192 : 256)); }

// grid 9216: mats 0-8 x256 segs, mats 9-14 x1024 segs, mats 15-17 x256 segs.
__global__ __launch_bounds__(256) void absmean_all_k(WSetup wsu, float* __restrict__ part){
  __shared__ float red[4];
  int bid = blockIdx.x, mat, seg;
  if (bid < 2304){ mat = bid >> 8; seg = bid & 255; }
  else if (bid < 8448){ mat = 9 + ((bid-2304) >> 10); seg = (bid-2304) & 1023; }
  else { mat = 15 + ((bid-8448) >> 8); seg = (bid-8448) & 255; }
  long n4 = n4of(mat);
  int segs = (mat >= 9 && mat < 15) ? 1024 : 256;
  long cnt = n4 / segs;
  const float4* p = (const float4*)wsu.src[mat] + (long)seg*cnt;
  float s0=0.f, s1=0.f, s2=0.f, s3=0.f;
  if (cnt >= 2048){            // 8 independent streams
    long oct = cnt >> 3;
    float s[8] = {0.f,0.f,0.f,0.f,0.f,0.f,0.f,0.f};
    for (long j = threadIdx.x; j < oct; j += 256){
#pragma unroll
      for (int k=0;k<8;k++){
        float4 a = p[j + (long)k*oct];
        s[k] += fabsf(a.x)+fabsf(a.y)+fabsf(a.z)+fabsf(a.w);
      }
    }
    s0 = s[0]+s[4]; s1 = s[1]+s[5]; s2 = s[2]+s[6]; s3 = s[3]+s[7];
  } else if (cnt >= 1024){
    long quar = cnt >> 2;
    const float4* p1 = p + quar;
    const float4* p2 = p + 2*quar;
    const float4* p3 = p + 3*quar;
    for (long j = threadIdx.x; j < quar; j += 256){
      float4 a = p[j], b = p1[j], c = p2[j], d = p3[j];
      s0 += fabsf(a.x)+fabsf(a.y)+fabsf(a.z)+fabsf(a.w);
      s1 += fabsf(b.x)+fabsf(b.y)+fabsf(b.z)+fabsf(b.w);
      s2 += fabsf(c.x)+fabsf(c.y)+fabsf(c.z)+fabsf(c.w);
      s3 += fabsf(d.x)+fabsf(d.y)+fabsf(d.z)+fabsf(d.w);
    }
  } else {
    for (long j = threadIdx.x; j < cnt; j += 256){
      float4 a = p[j];
      s0 += fabsf(a.x)+fabsf(a.y)+fabsf(a.z)+fabsf(a.w);
    }
  }
  float s = bredsum(s0+s1+s2+s3, red);
  if (threadIdx.x==0) part[(long)mat*1024 + seg] = s;
}

__global__ __launch_bounds__(256) void finalize_scales_k(const float* __restrict__ part,
                                                         float* __restrict__ scales){
  __shared__ float red[4];
  const long numel[18] = {1048576, 1048576,1048576, 1048576,1048576, 1048576,1048576,
                          1048576,1048576, 4194304,4194304, 4194304,4194304, 4194304,4194304,
                          32768, 32768, 1024};
  int t = threadIdx.x;
  for (int m=0;m<18;m++){
    int segs = (m >= 9 && m < 15) ? 1024 : 256;
    float v = 0.f;
    for (int j=t; j<segs; j+=256) v += part[(long)m*1024 + j];
    v = bredsum(v, red);
    if (t==0) scales[m] = v/(float)numel[m] + 1e-8f;
  }
  if (t==0){
    for (int l=0;l<2;l++){
      scales[18+l*3+0] = scales[1+l];   // wq
      scales[18+l*3+1] = scales[3+l];   // wk
      scales[18+l*3+2] = scales[5+l];   // wv
      scales[24+l*2+0] = scales[9+l];   // wg
      scales[24+l*2+1] = scales[11+l];  // wu
    }
  }
}

__global__ __launch_bounds__(256) void quantw_all_k(WSetup wsu, const float* __restrict__ scales){
  int bid = blockIdx.x;
  int mat = 0, c = 0;
  for (;;){
    int nb = mat<9 ? 256 : (mat<15 ? 1024 : (mat<17 ? 8 : 1));
    if (bid < c + nb) break;
    c += nb; mat++;
  }
  long seg = bid - c;
  long n4 = n4of(mat);
  float s = scales[mat];
  int md = wsu.mode[mat];
  const float4* src = (const float4*)wsu.src[mat];
  char4* dst = (char4*)wsu.dst[mat];
  long base = seg*1024;
#pragma unroll
  for (int k=0;k<4;k++){
    long i = base + k*256 + threadIdx.x;
    if (i < n4){
      float4 v = src[i];
      char4 q;
      q.x = f2i8(fminf(fmaxf(rintf(v.x/s), -1.f), 1.f));
      q.y = f2i8(fminf(fmaxf(rintf(v.y/s), -1.f), 1.f));
      q.z = f2i8(fminf(fmaxf(rintf(v.z/s), -1.f), 1.f));
      q.w = f2i8(fminf(fmaxf(rintf(v.w/s), -1.f), 1.f));
      if (md == 0) dst[i] = q;
      else {
        long r = i >> 8, cc = i & 255;    // K=1024 -> 256 char4/row
        dst[(((r<<1) | (md-1))<<8) | cc] = q;
      }
    }
  }
}

// ---------------- row quant (1024 wide) -> i8; input f32 or bf16 ----------------
template<bool BF>
__global__ __launch_bounds__(256) void rowquant1k_k(const void* __restrict__ xin,
                                                    signed char* __restrict__ xq,
                                                    float* __restrict__ rs){
  __shared__ float red[4];
  int m = blockIdx.x, t = threadIdx.x;
  float v[4];
  if (BF){
    ushort4 u = *(const ushort4*)((const unsigned short*)xin + (size_t)m*1024 + t*4);
    v[0]=bf2f(u.x); v[1]=bf2f(u.y); v[2]=bf2f(u.z); v[3]=bf2f(u.w);
  } else {
    float4 f = *(const float4*)((const float*)xin + (size_t)m*1024 + t*4);
    v[0]=f.x; v[1]=f.y; v[2]=f.z; v[3]=f.w;
  }
  float am = fmaxf(fmaxf(fabsf(v[0]),fabsf(v[1])),fmaxf(fabsf(v[2]),fabsf(v[3])));
  am = bredmax(am, red);
  float a = fmaxf(am, 1e-8f), inv = 127.f/a;
  char4 q;
  q.x = f2i8(fminf(fmaxf(rintf(v[0]*inv),-128.f),127.f));
  q.y = f2i8(fminf(fmaxf(rintf(v[1]*inv),-128.f),127.f));
  q.z = f2i8(fminf(fmaxf(rintf(v[2]*inv),-128.f),127.f));
  q.w = f2i8(fminf(fmaxf(rintf(v[3]*inv),-128.f),127.f));
  *(char4*)(xq + (size_t)m*1024 + t*4) = q;
  if (t==0) rs[m] = a/127.f;
}

// ---------------- row quant (4096 wide, bf16 input) -> i8 ----------------
__global__ __launch_bounds__(256) void rowquant4k_k(const unsigned short* __restrict__ x,
                                                    signed char* __restrict__ xq,
                                                    float* __restrict__ rs){
  __shared__ float red[4];
  int m = blockIdx.x, t = threadIdx.x;
  const unsigned short* p = x + (size_t)m*4096 + t*16;
  u16x8 u0 = *(const u16x8*)p;
  u16x8 u1 = *(const u16x8*)(p + 8);
  float v[16];
#pragma unroll
  for (int j=0;j<8;j++){ v[j] = bf2f(u0[j]); v[j+8] = bf2f(u1[j]); }
  float am = 0.f;
#pragma unroll
  for (int j=0;j<16;j++) am = fmaxf(am, fabsf(v[j]));
  am = bredmax(am, red);
  float a = fmaxf(am, 1e-8f), inv = 127.f/a;
#pragma unroll
  for (int j=0;j<16;j+=4){
    char4 q;
    q.x = f2i8(fminf(fmaxf(rintf(v[j+0]*inv),-128.f),127.f));
    q.y = f2i8(fminf(fmaxf(rintf(v[j+1]*inv),-128.f),127.f));
    q.z = f2i8(fminf(fmaxf(rintf(v[j+2]*inv),-128.f),127.f));
    q.w = f2i8(fminf(fmaxf(rintf(v[j+3]*inv),-128.f),127.f));
    *(char4*)(xq + (size_t)m*4096 + t*16 + j) = q;
  }
  if (t==0) rs[m] = a/127.f;
}

// ---------------- fused: h_in = rmsnorm(h+delta, lnw); a_in quant with n1 ----------------
__global__ __launch_bounds__(256) void loopnorm_quant_k(const float* __restrict__ h,
                                                        const float* __restrict__ delta,
                                                        const float* __restrict__ lnw,
                                                        const float* __restrict__ n1,
                                                        float* __restrict__ hin,
                                                        signed char* __restrict__ xq,
                                                        float* __restrict__ rs){
  __shared__ float red[4];
  int m = blockIdx.x, t = threadIdx.x;
  int b = m >> 9;
  float v[4];
  float4 f = *(const float4*)(h + (size_t)m*1024 + t*4);
  v[0]=f.x; v[1]=f.y; v[2]=f.z; v[3]=f.w;
  if (t < 16){
#pragma unroll
    for (int j=0;j<4;j++) v[j] += delta[b*64 + t*4 + j];
  }
  float ss = v[0]*v[0]+v[1]*v[1]+v[2]*v[2]+v[3]*v[3];
  ss = bredsum(ss, red);
  float r1 = rsqrtf(ss*(1.f/1024.f) + 1e-6f);
  float w4[4];
#pragma unroll
  for (int j=0;j<4;j++) w4[j] = v[j]*r1*lnw[t*4+j];
  float4 of; of.x=w4[0]; of.y=w4[1]; of.z=w4[2]; of.w=w4[3];
  *(float4*)(hin + (size_t)m*1024 + t*4) = of;
  float s2 = w4[0]*w4[0]+w4[1]*w4[1]+w4[2]*w4[2]+w4[3]*w4[3];
  s2 = bredsum(s2, red);
  float r2 = rsqrtf(s2*(1.f/1024.f) + 1e-6f);
  float y[4];
#pragma unroll
  for (int j=0;j<4;j++) y[j] = w4[j]*r2*n1[t*4+j];
  float am = fmaxf(fmaxf(fabsf(y[0]),fabsf(y[1])),fmaxf(fabsf(y[2]),fabsf(y[3])));
  am = bredmax(am, red);
  float a = fmaxf(am, 1e-8f), inv = 127.f/a;
  char4 q;
  q.x = f2i8(fminf(fmaxf(rintf(y[0]*inv),-128.f),127.f));
  q.y = f2i8(fminf(fmaxf(rintf(y[1]*inv),-128.f),127.f));
  q.z = f2i8(fminf(fmaxf(rintf(y[2]*inv),-128.f),127.f));
  q.w = f2i8(fminf(fmaxf(rintf(y[3]*inv),-128.f),127.f));
  *(char4*)(xq + (size_t)m*1024 + t*4) = q;
  if (t==0) rs[m] = a/127.f;
}

// ---------------- i8 MFMA GEMM (triple-buffered, 2-deep prefetch, swizzled) ----------------
DEV f32x4 accfence(f32x4 c){ asm volatile("s_nop 7\n\ts_nop 7" : "+v"(c)); return c; }
DEV i32x4 accfencei(i32x4 c){ asm volatile("s_nop 7\n\ts_nop 7" : "+v"(c)); return c; }

template<bool SPLITK, bool GUSILU>
__global__ __launch_bounds__(256)
void gemm_i8(const signed char* __restrict__ A, const signed char* __restrict__ W,
             const float* __restrict__ rowsc, const float* __restrict__ wscv,
             const float* __restrict__ res, float* __restrict__ C, int N, int Kf, int Kc)
{
  __shared__ __align__(16) signed char As[3][8192];
  __shared__ __align__(16) signed char Bs[3][8192];
  const int tid = threadIdx.x;
  const int lane = tid & 63, wvid = tid >> 6;
  const int wr = wvid >> 1, wc = wvid & 1;
  const int bm = blockIdx.y, bn = blockIdx.x;

  const int r0 = (wvid<<4) + (lane>>2);
  const int sw = (((lane&3) ^ ((r0>>1)&3)) << 4);        // byte offset of 16B chunk
  const long kstart = SPLITK ? (long)blockIdx.z * Kc : 0;
  const signed char* gA = A + (size_t)(bm*128 + r0)*Kf + kstart + sw;
  const signed char* gB = W + (size_t)(bn*128 + r0)*Kf + kstart + sw;
  const size_t row64 = (size_t)64*Kf;

#define STAGE(buf, koff) do { \
    __builtin_amdgcn_global_load_lds(gA + (koff),         &As[buf][(wvid<<10)],      16, 0, 0); \
    __builtin_amdgcn_global_load_lds(gA + (koff) + row64, &As[buf][(wvid<<10)+4096], 16, 0, 0); \
    __builtin_amdgcn_global_load_lds(gB + (koff),         &Bs[buf][(wvid<<10)],      16, 0, 0); \
    __builtin_amdgcn_global_load_lds(gB + (koff) + row64, &Bs[buf][(wvid<<10)+4096], 16, 0, 0); \
  } while(0)

  i32x4 acc[4][4] = {};
  const int rA = (wr<<6) + (lane&15);
  const int rB = (wc<<6) + (lane&15);
  const int psA = (((lane>>4) ^ (((lane&15)>>1)&3)) << 4);  // byte offset

  const int NT = Kc >> 6;   // >= 4 for all our shapes
  STAGE(0, 0);
  STAGE(1, 64);
  int cur = 0, nxt = 1, nx2 = 2;
  for (int kt = 0; kt < NT; ++kt){
    const int k2 = kt + 2;
    const int kn = (k2 < NT) ? (k2<<6) : 0;     // wrap: dead-buffer reload, keeps vmcnt count exact
    STAGE(nx2, kn);
    asm volatile("s_waitcnt vmcnt(8)" ::: "memory");   // tile kt's 4 DMAs done; 8 stay in flight
    __builtin_amdgcn_s_barrier();
    asm volatile("" ::: "memory");
    i32x4 a[4], b[4];
    const signed char* Ab = As[cur];
    const signed char* Bb = Bs[cur];
#pragma unroll
    for (int mi=0;mi<4;mi++) a[mi] = *(const i32x4*)(Ab + (rA + mi*16)*64 + psA);
#pragma unroll
    for (int ni=0;ni<4;ni++) b[ni] = *(const i32x4*)(Bb + (rB + ni*16)*64 + psA);
#pragma unroll
    for (int mi=0;mi<4;mi++)
#pragma unroll
      for (int ni=0;ni<4;ni++)
        asm("v_mfma_i32_16x16x64_i8 %0, %1, %2, %0" : "+v"(acc[mi][ni]) : "v"(a[mi]), "v"(b[ni]));
    asm volatile("s_waitcnt lgkmcnt(0)" ::: "memory");
    __builtin_amdgcn_s_barrier();
    int tmp = cur; cur = nxt; nxt = nx2; nx2 = tmp;
  }
#undef STAGE

#pragma unroll
  for (int mi=0;mi<4;mi++)
#pragma unroll
    for (int ni=0;ni<4;ni++)
      acc[mi][ni] = accfencei(acc[mi][ni]);

  const int rif = (lane>>4)<<2;
  const int cif = lane&15;
  const int gcol0 = bn*128 + (wc<<6);

  if constexpr (SPLITK){
    float* P = C + (size_t)blockIdx.z * ((size_t)N << 10);
#pragma unroll
    for (int mi=0;mi<4;mi++)
#pragma unroll
      for (int r=0;r<4;r++){
        const int grow = bm*128 + (wr<<6) + mi*16 + rif + r;
#pragma unroll
        for (int ni=0;ni<4;ni++)
          P[(size_t)grow*N + gcol0 + ni*16 + cif] = (float)acc[mi][ni][r];
      }
    return;
  }

  if constexpr (GUSILU){
    const float sg = wscv[0], su = wscv[1];
    unsigned short* Cb = (unsigned short*)C;   // bf16 [M][4096]
#pragma unroll
    for (int mi=0;mi<4;mi++){
#pragma unroll
      for (int r=0;r<4;r++){
        const int grow = bm*128 + (wr<<6) + mi*16 + rif + r;
        const float rsc = rowsc[grow];
#pragma unroll
        for (int ni=0;ni<4;ni++){
          const int gcol = gcol0 + ni*16 + cif;
          float val = (float)acc[mi][ni][r] * rsc * ((gcol & 1) ? su : sg);
          float other = __shfl_xor(val, 1);
          if (!(lane & 1)){
            float g = val, u = other;
            float outv = g/(1.f+expf(-g))*u;
            Cb[(size_t)grow*4096 + (gcol>>1)] = f2bfr(outv);
          }
        }
      }
    }
    return;
  }

#pragma unroll
  for (int mi=0;mi<4;mi++){
#pragma unroll
    for (int r=0;r<4;r++){
      const int grow = bm*128 + (wr<<6) + mi*16 + rif + r;
      const float rsc = rowsc[grow];
#pragma unroll
      for (int ni=0;ni<4;ni++){
        const int gcol = gcol0 + ni*16 + cif;
        float vvv = (float)acc[mi][ni][r] * rsc * wscv[0];
        const size_t off = (size_t)grow*N + gcol;
        if (res) vvv += res[off];
        C[off] = vvv;
      }
    }
  }
}

// ---------------- qkv GEMM: same triple-buffered loop + rope epilogue -> bf16 ----------------
// grid (24, 8). N=3072, K=1024. Each 64-col half-tile (wc) is one head-section.
__global__ __launch_bounds__(256)
void gemm_qkv128(const signed char* __restrict__ A, const signed char* __restrict__ W,
                 const float* __restrict__ rowsc, const float* __restrict__ wscv,
                 const float* __restrict__ tab, unsigned short* __restrict__ C)
{
  __shared__ __align__(16) signed char As[3][8192];
  __shared__ __align__(16) signed char Bs[3][8192];
  const int tid = threadIdx.x;
  const int lane = tid & 63, wvid = tid >> 6;
  const int wr = wvid >> 1, wc = wvid & 1;
  const int bm = blockIdx.y, bn = blockIdx.x;
  const int Kf = 1024;

  const int r0 = (wvid<<4) + (lane>>2);
  const int sw = (((lane&3) ^ ((r0>>1)&3)) << 4);
  const signed char* gA = A + (size_t)(bm*128 + r0)*Kf + sw;
  const signed char* gB = W + (size_t)(bn*128 + r0)*Kf + sw;
  const size_t row64 = (size_t)64*Kf;

#define STAGE(buf, koff) do { \
    __builtin_amdgcn_global_load_lds(gA + (koff),         &As[buf][(wvid<<10)],      16, 0, 0); \
    __builtin_amdgcn_global_load_lds(gA + (koff) + row64, &As[buf][(wvid<<10)+4096], 16, 0, 0); \
    __builtin_amdgcn_global_load_lds(gB + (koff),         &Bs[buf][(wvid<<10)],      16, 0, 0); \
    __builtin_amdgcn_global_load_lds(gB + (koff) + row64, &Bs[buf][(wvid<<10)+4096], 16, 0, 0); \
  } while(0)

  i32x4 acc[4][4] = {};
  const int rA = (wr<<6) + (lane&15);
  const int rB = (wc<<6) + (lane&15);
  const int psA = (((lane>>4) ^ (((lane&15)>>1)&3)) << 4);

  const int NT = 16;
  STAGE(0, 0);
  STAGE(1, 64);
  int cur = 0, nxt = 1, nx2 = 2;
  for (int kt = 0; kt < NT; ++kt){
    const int k2 = kt + 2;
    const int kn = (k2 < NT) ? (k2<<6) : 0;
    STAGE(nx2, kn);
    asm volatile("s_waitcnt vmcnt(8)" ::: "memory");
    __builtin_amdgcn_s_barrier();
    asm volatile("" ::: "memory");
    i32x4 a[4], b[4];
    const signed char* Ab = As[cur];
    const signed char* Bb = Bs[cur];
#pragma unroll
    for (int mi=0;mi<4;mi++) a[mi] = *(const i32x4*)(Ab + (rA + mi*16)*64 + psA);
#pragma unroll
    for (int ni=0;ni<4;ni++) b[ni] = *(const i32x4*)(Bb + (rB + ni*16)*64 + psA);
#pragma unroll
    for (int mi=0;mi<4;mi++)
#pragma unroll
      for (int ni=0;ni<4;ni++)
        asm("v_mfma_i32_16x16x64_i8 %0, %1, %2, %0" : "+v"(acc[mi][ni]) : "v"(a[mi]), "v"(b[ni]));
    asm volatile("s_waitcnt lgkmcnt(0)" ::: "memory");
    __builtin_amdgcn_s_barrier();
    int tmp = cur; cur = nxt; nxt = nx2; nx2 = tmp;
  }
#undef STAGE

#pragma unroll
  for (int mi=0;mi<4;mi++)
#pragma unroll
    for (int ni=0;ni<4;ni++)
      acc[mi][ni] = accfencei(acc[mi][ni]);

  const int rif = (lane>>4)<<2;
  const int cif = lane&15;
  const int gcol0 = bn*128 + (wc<<6);     // head-aligned 64-col span
  const int sec = gcol0 >> 10;            // 0=q, 1=k, 2=v
  const float wsc = wscv[sec] * ((sec==0) ? 0.125f : 1.f);

  if (sec < 2){
    // rope: col d pairs with d+32 -> acc[mi][np] with acc[mi][np+2], np in {0,1}
#pragma unroll
    for (int mi=0;mi<4;mi++){
#pragma unroll
      for (int r=0;r<4;r++){
        const int grow = bm*128 + (wr<<6) + mi*16 + rif + r;
        const float s = rowsc[grow] * wsc;
        const int tpos = grow & 511;
#pragma unroll
        for (int np=0;np<2;np++){
          const int d = np*16 + cif;
          float2 cs = *(const float2*)(tab + (size_t)((tpos<<5) + d)*2);
          float x1 = (float)acc[mi][np][r]   * s;
          float x2 = (float)acc[mi][np+2][r] * s;
          C[(size_t)grow*3072 + gcol0 + d]      = f2bfr(x1*cs.x - x2*cs.y);
          C[(size_t)grow*3072 + gcol0 + 32 + d] = f2bfr(x1*cs.y + x2*cs.x);
        }
      }
    }
  } else {
#pragma unroll
    for (int mi=0;mi<4;mi++){
#pragma unroll
      for (int r=0;r<4;r++){
        const int grow = bm*128 + (wr<<6) + mi*16 + rif + r;
        const float s = rowsc[grow] * wsc;
#pragma unroll
        for (int ni=0;ni<4;ni++)
          C[(size_t)grow*3072 + gcol0 + ni*16 + cif] = f2bfr((float)acc[mi][ni][r] * s);
      }
    }
  }
}

// ---------------- split-K(4) reduce: C = (res?) + (sum P)*rowsc*wsc ----------------
__global__ __launch_bounds__(256) void reduce4_k(const float* __restrict__ P,
                                                 const float* __restrict__ rowsc,
                                                 const float* __restrict__ wsc,
                                                 const float* __restrict__ res,
                                                 float* __restrict__ C){
  int m = blockIdx.x, t = threadIdx.x;
  float s0 = rowsc[m] * wsc[0];
  size_t off = (size_t)m*1024 + t*4;
  float4 a = *(const float4*)(P + off);
  float4 b = *(const float4*)(P + 1048576 + off);
  float4 c = *(const float4*)(P + 2097152 + off);
  float4 d = *(const float4*)(P + 3145728 + off);
  float4 o;
  o.x = (a.x+b.x+c.x+d.x)*s0;
  o.y = (a.y+b.y+c.y+d.y)*s0;
  o.z = (a.z+b.z+c.z+d.z)*s0;
  o.w = (a.w+b.w+c.w+d.w)*s0;
  if (res){
    float4 r = *(const float4*)(res + off);
    o.x += r.x; o.y += r.y; o.z += r.z; o.w += r.w;
  }
  *(float4*)(C + off) = o;
}

// ---------------- fused: split-K(4) reduce + residual + rmsnorm + quant ----------------
__global__ __launch_bounds__(256) void redq_norm_k(const float* __restrict__ P,
                                                   const float* rowsc,
                                                   const float* __restrict__ wsc,
                                                   const float* __restrict__ res,
                                                   const float* __restrict__ gamma,
                                                   float* __restrict__ Cout,
                                                   signed char* __restrict__ xq,
                                                   float* rs){
  __shared__ float red[4];
  int m = blockIdx.x, t = threadIdx.x;
  float s0 = rowsc[m] * wsc[0];
  size_t off = (size_t)m*1024 + t*4;
  float4 a = *(const float4*)(P + off);
  float4 b = *(const float4*)(P + 1048576 + off);
  float4 c = *(const float4*)(P + 2097152 + off);
  float4 d = *(const float4*)(P + 3145728 + off);
  float4 r4 = *(const float4*)(res + off);
  float v[4];
  v[0] = r4.x + (a.x+b.x+c.x+d.x)*s0;
  v[1] = r4.y + (a.y+b.y+c.y+d.y)*s0;
  v[2] = r4.z + (a.z+b.z+c.z+d.z)*s0;
  v[3] = r4.w + (a.w+b.w+c.w+d.w)*s0;
  float4 of; of.x=v[0]; of.y=v[1]; of.z=v[2]; of.w=v[3];
  *(float4*)(Cout + off) = of;
  float ss = v[0]*v[0]+v[1]*v[1]+v[2]*v[2]+v[3]*v[3];
  ss = bredsum(ss, red);
  float r1 = rsqrtf(ss*(1.f/1024.f) + 1e-6f);
  float y[4];
#pragma unroll
  for (int j=0;j<4;j++) y[j] = v[j]*r1*gamma[t*4+j];
  float am = fmaxf(fmaxf(fabsf(y[0]),fabsf(y[1])),fmaxf(fabsf(y[2]),fabsf(y[3])));
  am = bredmax(am, red);
  float aq = fmaxf(am, 1e-8f), inv = 127.f/aq;
  char4 q;
  q.x = f2i8(fminf(fmaxf(rintf(y[0]*inv),-128.f),127.f));
  q.y = f2i8(fminf(fmaxf(rintf(y[1]*inv),-128.f),127.f));
  q.z = f2i8(fminf(fmaxf(rintf(y[2]*inv),-128.f),127.f));
  q.w = f2i8(fminf(fmaxf(rintf(y[3]*inv),-128.f),127.f));
  *(char4*)(xq + (size_t)m*1024 + t*4) = q;
  if (t==0) rs[m] = aq/127.f;
}

// ---------------- fused tail: reduce + recurrence + quant + loraDown + topk
//                  + loraUp + act-sigmoid + h_out + ponder (+ next-iter loopnorm) ----------------
__global__ __launch_bounds__(256) void redfin_k(const float* __restrict__ P,
                                                const float* __restrict__ rowsc,
                                                const float* __restrict__ wsc,
                                                const float* __restrict__ res,
                                                float* __restrict__ h,
                                                const float* __restrict__ Be,
                                                const float* __restrict__ Araw,
                                                const float* __restrict__ alpha, int it,
                                                const signed char* __restrict__ ldq,
                                                const float* __restrict__ sld,
                                                const signed char* __restrict__ luq,
                                                const float* __restrict__ slu,
                                                const signed char* __restrict__ actq,
                                                const float* __restrict__ sact,
                                                const float* __restrict__ ig,
                                                float* __restrict__ hout,
                                                float* __restrict__ ponder,
                                                const float* __restrict__ dnext,
                                                const float* __restrict__ lnw,
                                                const float* __restrict__ n1,
                                                float* __restrict__ hin,
                                                signed char* __restrict__ xqn,
                                                float* __restrict__ rsn,
                                                int doNext){
  __shared__ float red[4];
  __shared__ float xrow[1024];
  __shared__ float part[256];
  __shared__ float xs[32];
  __shared__ float sh_thr, sh_gs;
  int m = blockIdx.x, t = threadIdx.x;
  float al = alpha[it];
  float s0 = rowsc[m] * wsc[0];
  size_t off = (size_t)m*1024 + t*4;
  float4 a = *(const float4*)(P + off);
  float4 b = *(const float4*)(P + 1048576 + off);
  float4 c = *(const float4*)(P + 2097152 + off);
  float4 d = *(const float4*)(P + 3145728 + off);
  float4 r4 = *(const float4*)(res + off);
  float4 hh = *(const float4*)(h + off);
  float4 be = *(const float4*)(Be + off);
  float4 ar = *(const float4*)(Araw + t*4);
  float v[4];
  v[0] = 0.99f*tanhf(ar.x)*hh.x + be.x + al*(r4.x + (a.x+b.x+c.x+d.x)*s0);
  v[1] = 0.99f*tanhf(ar.y)*hh.y + be.y + al*(r4.y + (a.y+b.y+c.y+d.y)*s0);
  v[2] = 0.99f*tanhf(ar.z)*hh.z + be.z + al*(r4.z + (a.z+b.z+c.z+d.z)*s0);
  v[3] = 0.99f*tanhf(ar.w)*hh.w + be.w + al*(r4.w + (a.w+b.w+c.w+d.w)*s0);
  float am = fmaxf(fmaxf(fabsf(v[0]),fabsf(v[1])),fmaxf(fabsf(v[2]),fabsf(v[3])));
  am = bredmax(am, red);
  float aq = fmaxf(am, 1e-8f), inv = 127.f/aq;
#pragma unroll
  for (int j=0;j<4;j++) xrow[t*4+j] = fminf(fmaxf(rintf(v[j]*inv),-128.f),127.f);
  float rsv = aq/127.f;
  __syncthreads();
  {
    int r = t & 31, seg = t >> 5;
    const signed char* wrow = ldq + (size_t)r*1024 + seg*128;
    const float* xr = xrow + seg*128;
    float acc = 0.f;
    for (int k=0;k<128;k+=4){
      char4 w4 = *(const char4*)(wrow + k);
      acc += xr[k]*(float)w4.x + xr[k+1]*(float)w4.y + xr[k+2]*(float)w4.z + xr[k+3]*(float)w4.w;
    }
    part[t] = acc;
  }
  __syncthreads();
  if (t < 32){
    float s = 0.f;
    for (int sg=0; sg<8; sg++) s += part[sg*32 + t];
    xs[t] = s * rsv * (*sld);
  }
  __syncthreads();
  float val = 0.f, av = 0.f, amax = 0.f;
  if (t < 32){
    val = xs[t]; av = fabsf(val);
    int rank = 0;
    for (int j=0;j<32;j++){
      float aj = fabsf(xs[j]);
      amax = fmaxf(amax, aj);
      if (aj > av || (aj == av && j < t)) rank++;
    }
    if (rank == 17) sh_thr = av;
  }
  __syncthreads();
  if (t < 32){
    float a2 = fmaxf(amax, 1e-8f);
    float q = 0.f;
    if (av >= sh_thr) q = fminf(fmaxf(rintf(val*(127.f/a2)), -128.f), 127.f);
    xs[t] = q;
    if (t == 0) sh_gs = ig[it] * (*slu) * (a2/127.f);
  }
  __syncthreads();
  float gs = sh_gs;
  float hn[4];
  int n0 = t*4;
#pragma unroll
  for (int ni=0;ni<4;ni++){
    const signed char* lr = luq + (size_t)(n0+ni)*32;
    float dd = 0.f;
    for (int k=0;k<32;k+=4){
      char4 w4 = *(const char4*)(lr + k);
      dd += xs[k]*(float)w4.x + xs[k+1]*(float)w4.y + xs[k+2]*(float)w4.z + xs[k+3]*(float)w4.w;
    }
    hn[ni] = v[ni] + gs*dd;
  }
  float am2 = fmaxf(fmaxf(fabsf(hn[0]),fabsf(hn[1])),fmaxf(fabsf(hn[2]),fabsf(hn[3])));
  am2 = bredmax(am2, red);
  float a2 = fmaxf(am2, 1e-8f), inv2 = 127.f/a2;
  float zp = 0.f;
#pragma unroll
  for (int ni=0;ni<4;ni++){
    float q = fminf(fmaxf(rintf(hn[ni]*inv2),-128.f),127.f);
    zp += q * (float)actq[n0+ni];
  }
  zp = bredsum(zp, red);
  float z = zp * (a2/127.f) * (*sact);
  float wv = 1.f/(1.f+expf(-z));
#pragma unroll
  for (int ni=0;ni<4;ni++){
    size_t o2 = (size_t)m*1024 + n0+ni;
    float ho = hout[o2];
    hout[o2] = ho + wv*(hn[ni]-ho);
    h[o2] = hn[ni];
  }
  if (t==0) atomicAdd(ponder, wv * (1.f/8192.f));

  // ---- fused next-iteration loopnorm + quant ----
  if (doNext){
    int b2 = m >> 9;
    float v2[4] = {hn[0], hn[1], hn[2], hn[3]};
    if (t < 16){
#pragma unroll
      for (int j=0;j<4;j++) v2[j] += dnext[b2*64 + t*4 + j];
    }
    float ss2 = v2[0]*v2[0]+v2[1]*v2[1]+v2[2]*v2[2]+v2[3]*v2[3];
    ss2 = bredsum(ss2, red);
    float r1 = rsqrtf(ss2*(1.f/1024.f) + 1e-6f);
    float w4[4];
#pragma unroll
    for (int j=0;j<4;j++) w4[j] = v2[j]*r1*lnw[t*4+j];
    float4 of; of.x=w4[0]; of.y=w4[1]; of.z=w4[2]; of.w=w4[3];
    *(float4*)(hin + off) = of;
    float s2 = w4[0]*w4[0]+w4[1]*w4[1]+w4[2]*w4[2]+w4[3]*w4[3];
    s2 = bredsum(s2, red);
    float r2 = rsqrtf(s2*(1.f/1024.f) + 1e-6f);
    float y[4];
#pragma unroll
    for (int j=0;j<4;j++) y[j] = w4[j]*r2*n1[t*4+j];
    float am3 = fmaxf(fmaxf(fabsf(y[0]),fabsf(y[1])),fmaxf(fabsf(y[2]),fabsf(y[3])));
    am3 = bredmax(am3, red);
    float aq3 = fmaxf(am3, 1e-8f), inv3 = 127.f/aq3;
    char4 q;
    q.x = f2i8(fminf(fmaxf(rintf(y[0]*inv3),-128.f),127.f));
    q.y = f2i8(fminf(fmaxf(rintf(y[1]*inv3),-128.f),127.f));
    q.z = f2i8(fminf(fmaxf(rintf(y[2]*inv3),-128.f),127.f));
    q.w = f2i8(fminf(fmaxf(rintf(y[3]*inv3),-128.f),127.f));
    *(char4*)(xqn + off) = q;
    if (t==0) rsn[m] = aq3/127.f;
  }
}

// ---------------- MFMA flash attention, split-k over 2 blocks; bf16 partial out ----------------
DEV int swz64(int r, int c){ return r*64 + (c ^ ((r&7)<<3)); }

__global__ __launch_bounds__(256) void attn_split_k(const unsigned short* __restrict__ qkv,
                                                    unsigned short* __restrict__ Opart,
                                                    float* __restrict__ ml){
  __shared__ __align__(16) unsigned short Qs[4096];
  __shared__ __align__(16) unsigned short Ks[4096];
  __shared__ __align__(16) unsigned short Vt[4096];   // [d][k], swizzled on d
  __shared__ __align__(16) unsigned short Ps[4][1024];
  const int tid = threadIdx.x;
  const int lane = tid & 63, wv = tid >> 6;
  const int bidl = blockIdx.x & 255;
  const int z = blockIdx.x >> 8;          // 0..1
  const int qt = bidl & 7, bh = bidl >> 3;
  const int b = bh >> 4, h = bh & 15;
  const int tokb = b*512;
  const int l15 = lane & 15, lh = lane >> 4;

  { // stage Q (already scaled by 1/8)
    int r = tid >> 2, c0 = (tid & 3) << 4;
    const unsigned short* s = qkv + (size_t)(tokb + qt*64 + r)*3072 + h*64 + c0;
    u16x8 f0 = *(const u16x8*)s, f1 = *(const u16x8*)(s+8);
    *(u16x8*)(Qs + swz64(r, c0))   = f0;
    *(u16x8*)(Qs + swz64(r, c0+8)) = f1;
  }

  float m_run[4] = {-1e30f,-1e30f,-1e30f,-1e30f};
  float l_run[4] = {0.f,0.f,0.f,0.f};
  f32x4 accO[4] = {};

  const int nt = qt + 1;
  const int half = (nt + 1) >> 1;
  const int kA = z ? half : 0;
  const int kB = z ? nt : half;

  for (int kt = kA; kt < kB; ++kt){
    __syncthreads();
    { // stage K
      int r = tid >> 2, c0 = (tid & 3) << 4;
      const unsigned short* s = qkv + (size_t)(tokb + kt*64 + r)*3072 + 1024 + h*64 + c0;
      u16x8 f0 = *(const u16x8*)s, f1 = *(const u16x8*)(s+8);
      *(u16x8*)(Ks + swz64(r, c0))   = f0;
      *(u16x8*)(Ks + swz64(r, c0+8)) = f1;
    }
    { // stage V transposed
      int r0 = (tid >> 3) << 1, cv = (tid & 7) << 3;
      const unsigned short* s0 = qkv + (size_t)(tokb + kt*64 + r0)*3072 + 2048 + h*64 + cv;
      u16x8 a = *(const u16x8*)s0;
      u16x8 b2 = *(const u16x8*)(s0 + 3072);
#pragma unroll
      for (int j=0;j<8;j++){
        int d = cv + j;
        unsigned int pk = (unsigned int)a[j] | ((unsigned int)b2[j]<<16);
        *(unsigned int*)(Vt + swz64(d, r0)) = pk;
      }
    }
    __syncthreads();

    f32x4 s4[4] = {};
#pragma unroll
    for (int kc=0; kc<2; ++kc){
      i32x4 aq = *(const i32x4*)(Qs + swz64(wv*16 + l15, kc*32 + lh*8));
#pragma unroll
      for (int nt2=0; nt2<4; ++nt2){
        i32x4 bk = *(const i32x4*)(Ks + swz64(nt2*16 + l15, kc*32 + lh*8));
        asm("v_mfma_f32_16x16x32_bf16 %0, %1, %2, %0" : "+v"(s4[nt2]) : "v"(aq), "v"(bk));
      }
    }
#pragma unroll
    for (int nt2=0; nt2<4; ++nt2) s4[nt2] = accfence(s4[nt2]);

    const bool diag = (kt == qt);
    float sf[4];
#pragma unroll
    for (int r=0;r<4;r++){
      int rl = lh*4 + r;
      float mx = -1e30f;
#pragma unroll
      for (int nt2=0; nt2<4; ++nt2){
        float v = s4[nt2][r];
        if (diag && (nt2*16 + l15) > (wv*16 + rl)) v = -1e30f;
        s4[nt2][r] = v;
        mx = fmaxf(mx, v);
      }
      mx = fmaxf(mx, __shfl_xor(mx,1));
      mx = fmaxf(mx, __shfl_xor(mx,2));
      mx = fmaxf(mx, __shfl_xor(mx,4));
      mx = fmaxf(mx, __shfl_xor(mx,8));
      float mn = fmaxf(m_run[r], mx);
      sf[r] = __expf(m_run[r] - mn);
      m_run[r] = mn;
      float ps = 0.f;
#pragma unroll
      for (int nt2=0; nt2<4; ++nt2){
        float p = __expf(s4[nt2][r] - mn);
        ps += p;
        Ps[wv][swz64(rl, nt2*16 + l15)] = f2bfr(p);
      }
      ps += __shfl_xor(ps,1); ps += __shfl_xor(ps,2);
      ps += __shfl_xor(ps,4); ps += __shfl_xor(ps,8);
      l_run[r] = l_run[r]*sf[r] + ps;
    }
#pragma unroll
    for (int dt=0; dt<4; ++dt){
#pragma unroll
      for (int r=0;r<4;r++) accO[dt][r] *= sf[r];
      accO[dt] = accfence(accO[dt]);
    }
#pragma unroll
    for (int kc=0; kc<2; ++kc){
      i32x4 pa = *(const i32x4*)(Ps[wv] + swz64(l15, kc*32 + lh*8));
#pragma unroll
      for (int dt=0; dt<4; ++dt){
        i32x4 vb3 = *(const i32x4*)(Vt + swz64(dt*16 + l15, kc*32 + lh*8));
        asm("v_mfma_f32_16x16x32_bf16 %0, %1, %2, %0" : "+v"(accO[dt]) : "v"(pa), "v"(vb3));
      }
    }
  }
#pragma unroll
  for (int dt=0; dt<4; ++dt) accO[dt] = accfence(accO[dt]);
  unsigned short* Op = Opart + ((size_t)z << 20);
#pragma unroll
  for (int r=0;r<4;r++){
    int row = tokb + qt*64 + wv*16 + lh*4 + r;
    unsigned short* op = Op + (size_t)row*1024 + h*64 + l15;
#pragma unroll
    for (int dt=0; dt<4; ++dt)
      op[dt*16] = f2bfr(accO[dt][r]);
    if (l15 == 0){
      float2 v2 = make_float2(m_run[r], l_run[r]);
      *(float2*)(ml + ((size_t)(z*16 + h)*1024 + row)*2) = v2;
    }
  }
}

// ---------------- merge two attn partials (bf16) + row quant -> i8 ----------------
__global__ __launch_bounds__(256) void attn_merge_quant_k(const unsigned short* __restrict__ Opart,
                                                          const float* __restrict__ ml,
                                                          signed char* __restrict__ xq,
                                                          float* __restrict__ rs){
  __shared__ float red[4];
  int m = blockIdx.x, t = threadIdx.x;
  int head = t >> 4;                       // 4 cols per thread, 4-aligned -> single head
  float2 ml0 = *(const float2*)(ml + ((size_t)head*1024 + m)*2);
  float2 ml1 = *(const float2*)(ml + ((size_t)(16 + head)*1024 + m)*2);
  float mm = fmaxf(ml0.x, ml1.x);
  float w0 = __expf(ml0.x - mm), w1 = __expf(ml1.x - mm);
  float invl = 1.f / (ml0.y*w0 + ml1.y*w1);
  size_t off = (size_t)m*1024 + t*4;
  ushort4 u0 = *(const ushort4*)(Opart + off);
  ushort4 u1 = *(const ushort4*)(Opart + 1048576 + off);
  float v[4];
  v[0] = (bf2f(u0.x)*w0 + bf2f(u1.x)*w1)*invl;
  v[1] = (bf2f(u0.y)*w0 + bf2f(u1.y)*w1)*invl;
  v[2] = (bf2f(u0.z)*w0 + bf2f(u1.z)*w1)*invl;
  v[3] = (bf2f(u0.w)*w0 + bf2f(u1.w)*w1)*invl;
  float am = fmaxf(fmaxf(fabsf(v[0]),fabsf(v[1])),fmaxf(fabsf(v[2]),fabsf(v[3])));
  am = bredmax(am, red);
  float a = fmaxf(am, 1e-8f), inv = 127.f/a;
  char4 q;
  q.x = f2i8(fminf(fmaxf(rintf(v[0]*inv),-128.f),127.f));
  q.y = f2i8(fminf(fmaxf(rintf(v[1]*inv),-128.f),127.f));
  q.z = f2i8(fminf(fmaxf(rintf(v[2]*inv),-128.f),127.f));
  q.w = f2i8(fminf(fmaxf(rintf(v[3]*inv),-128.f),127.f));
  *(char4*)(xq + (size_t)m*1024 + t*4) = q;
  if (t==0) rs[m] = a/127.f;
}

// ================= host =================
extern "C" void kernel_launch(void* const* d_in, const int* in_sizes, int n_in,
                              void* d_out, int out_size, void* d_ws, size_t ws_size,
                              hipStream_t stream)
{
  (void)in_sizes; (void)n_in;
  const float* x     = (const float*)d_in[0];
  const float* e     = (const float*)d_in[1];
  const float* temb  = (const float*)d_in[2];
  const float* bn1   = (const float*)d_in[3];
  const float* bwq   = (const float*)d_in[4];
  const float* bwk   = (const float*)d_in[5];
  const float* bwv   = (const float*)d_in[6];
  const float* bwo   = (const float*)d_in[7];
  const float* bn2   = (const float*)d_in[8];
  const float* bwg   = (const float*)d_in[9];
  const float* bwu   = (const float*)d_in[10];
  const float* bwd   = (const float*)d_in[11];
  const float* Araw  = (const float*)d_in[12];
  const float* Bw    = (const float*)d_in[13];
  const float* ldw   = (const float*)d_in[14];
  const float* luw   = (const float*)d_in[15];
  const float* ig    = (const float*)d_in[16];
  const float* actw  = (const float*)d_in[17];
  const float* alph  = (const float*)d_in[18];
  const float* lpw   = (const float*)d_in[19];
  const float* lp2w  = (const float*)d_in[20];
  const float* lp2b  = (const float*)d_in[21];
  const float* lnw   = (const float*)d_in[22];

  char* ws = (char*)d_ws;
  float* out = (float*)d_out;
  const size_t WS_NEEDED = 94600704ull;
  if (ws_size < WS_NEEDED){
    fill_k<<<(out_size+255)/256,256,0,stream>>>(out, out_size, 1.0e9f);
    return;
  }

  signed char* qw_qkv = (signed char*)(ws + 0);          // 6 MB
  signed char* qw_wo  = (signed char*)(ws + 6291456);    // 2 MB
  signed char* qw_gu  = (signed char*)(ws + 8388608);    // 16 MB (g/u row-interleaved)
  signed char* qw_wd  = (signed char*)(ws + 25165824);   // 8 MB
  signed char* qw_bw  = (signed char*)(ws + 33554432);   // 1 MB
  signed char* qw_ld  = (signed char*)(ws + 34603008);
  signed char* qw_lu  = (signed char*)(ws + 34635776);
  signed char* qw_act = (signed char*)(ws + 34668544);
  float* scales = (float*)(ws + 34669568);
  float* delta  = (float*)(ws + 34688512);
  float* hbuf   = (float*)(ws + 34692608);
  float* Bebuf  = (float*)(ws + 38886912);
  float* bufX   = (float*)(ws + 43081216);
  float* bufY   = (float*)(ws + 47275520);
  float* gub    = (float*)(ws + 51469824);               // scratch: partials / attn Opart(4MB bf16) / silu out
  unsigned short* qkv_bf = (unsigned short*)(ws + 76635648);  // 6 MB bf16 qkv
  float* mlbuf  = (float*)(ws + 85024256);               // 256 KB attn m/l partials
  signed char* xq1k = (signed char*)(ws + 89218560);
  float* rs1k   = (float*)(ws + 90267136);
  signed char* xqm  = (signed char*)(ws + 90271232);
  float* rsm    = (float*)(ws + 94465536);
  float* ropetab= (float*)(ws + 94469632);               // 128 KB
  float* part   = gub;                                   // absmean partials (setup only)

  // ---- setup: scales + ternary weights ----
  WSetup wsu;
  wsu.src[0]=Bw;
  wsu.src[1]=bwq; wsu.src[2]=bwq+1048576;
  wsu.src[3]=bwk; wsu.src[4]=bwk+1048576;
  wsu.src[5]=bwv; wsu.src[6]=bwv+1048576;
  wsu.src[7]=bwo; wsu.src[8]=bwo+1048576;
  wsu.src[9]=bwg; wsu.src[10]=bwg+4194304;
  wsu.src[11]=bwu; wsu.src[12]=bwu+4194304;
  wsu.src[13]=bwd; wsu.src[14]=bwd+4194304;
  wsu.src[15]=ldw; wsu.src[16]=luw; wsu.src[17]=actw;
  wsu.dst[0]=qw_bw;
  wsu.dst[1]=qw_qkv;             wsu.dst[2]=qw_qkv+3145728;
  wsu.dst[3]=qw_qkv+1048576;     wsu.dst[4]=qw_qkv+3145728+1048576;
  wsu.dst[5]=qw_qkv+2097152;     wsu.dst[6]=qw_qkv+3145728+2097152;
  wsu.dst[7]=qw_wo;              wsu.dst[8]=qw_wo+1048576;
  wsu.dst[9]=qw_gu;              wsu.dst[10]=qw_gu+8388608;
  wsu.dst[11]=qw_gu;             wsu.dst[12]=qw_gu+8388608;
  wsu.dst[13]=qw_wd;             wsu.dst[14]=qw_wd+4194304;
  wsu.dst[15]=qw_ld; wsu.dst[16]=qw_lu; wsu.dst[17]=qw_act;
  for (int i=0;i<18;i++) wsu.mode[i]=0;
  wsu.mode[9]=1;  wsu.mode[10]=1;   // wg -> even rows
  wsu.mode[11]=2; wsu.mode[12]=2;   // wu -> odd rows

  absmean_all_k<<<9216,256,0,stream>>>(wsu, part);
  finalize_scales_k<<<1,256,0,stream>>>(part, scales);
  quantw_all_k<<<8465,256,0,stream>>>(wsu, scales);

  // ---- misc setup (copy_init + delta + ropetab merged) ----
  setup_misc_k<<<1216,256,0,stream>>>(x, hbuf, out, temb, lpw, lp2w, lp2b, delta, ropetab);

  // Be = bitlinear(e, B_w)  (splitK x4)
  rowquant1k_k<false><<<1024,256,0,stream>>>(e, xq1k, rs1k);
  { dim3 g(8,8,4); gemm_i8<true,false><<<g,256,0,stream>>>(xq1k, qw_bw, nullptr, nullptr, nullptr, gub, 1024, 1024, 256); }
  reduce4_k<<<1024,256,0,stream>>>(gub, rs1k, scales+0, nullptr, Bebuf);

  // ---- main recurrent loop (n_loops = 8) ----
  for (int it=0; it<8; ++it){
    if (it==0)
      loopnorm_quant_k<<<1024,256,0,stream>>>(hbuf, delta, lnw, bn1, bufX, xq1k, rs1k);
    for (int l=0;l<2;l++){
      // qkv: 128x128 GEMM + fused scale/rope epilogue -> bf16 qkvb
      { dim3 g(24,8); gemm_qkv128<<<g,256,0,stream>>>(xq1k, qw_qkv + (size_t)l*3145728, rs1k, scales+18+l*3, ropetab, qkv_bf); }
      // attention split over 2 k-halves (512 blocks) + merge/quant; bf16 partials
      attn_split_k<<<512,256,0,stream>>>(qkv_bf, (unsigned short*)gub, mlbuf);
      attn_merge_quant_k<<<1024,256,0,stream>>>((const unsigned short*)gub, mlbuf, xq1k, rs1k);
      // wo (splitK x4) + fused reduce+residual+rmsnorm(bn2)+quant
      { dim3 g(8,8,4); gemm_i8<true,false><<<g,256,0,stream>>>(xq1k, qw_wo + (size_t)l*1048576, nullptr, nullptr, nullptr, gub, 1024, 1024, 256); }
      redq_norm_k<<<1024,256,0,stream>>>(gub, rs1k, scales+7+l, bufX, bn2 + (size_t)l*1024, bufY, xq1k, rs1k);
      // gu with fused silu epilogue -> bf16 [1024][4096]
      { dim3 g(64,8); gemm_i8<false,true><<<g,256,0,stream>>>(xq1k, qw_gu + (size_t)l*8388608, rs1k, scales+24+l*2, nullptr, gub, 8192, 1024, 1024); }
      rowquant4k_k<<<1024,256,0,stream>>>((const unsigned short*)gub, xqm, rsm);
      // wd (splitK x4)
      { dim3 g(8,8,4); gemm_i8<true,false><<<g,256,0,stream>>>(xqm, qw_wd + (size_t)l*4194304, nullptr, nullptr, nullptr, gub, 1024, 4096, 1024); }
      if (l==0){
        redq_norm_k<<<1024,256,0,stream>>>(gub, rsm, scales+13, bufY, bn1 + 1024, bufX, xq1k, rs1k);
      } else {
        redfin_k<<<1024,256,0,stream>>>(gub, rsm, scales+14, bufY, hbuf, Bebuf, Araw, alph, it,
                                        qw_ld, scales+15, qw_lu, scales+16, qw_act, scales+17,
                                        ig, out, out + 1048576,
                                        delta + (it+1 < 8 ? (it+1)*128 : 0), lnw, bn1, bufX, xq1k, rs1k,
                                        (it < 7) ? 1 : 0);
      }
    }
  }
}

// Round 15
// 1786.433 us; speedup vs baseline: 1.0610x; 1.0192x over previous
//
#include <hip/hip_runtime.h>
#include <stdint.h>

#define DEV static __device__ __forceinline__

typedef float f32x4 __attribute__((ext_vector_type(4)));
typedef int   i32x4 __attribute__((ext_vector_type(4)));
typedef unsigned short u16x8 __attribute__((ext_vector_type(8)));

DEV float bf2f(unsigned short u){ return __uint_as_float(((unsigned int)u)<<16); }
DEV unsigned short f2bfr(float f){ // round-to-nearest-even bf16
  unsigned int u = __float_as_uint(f);
  return (unsigned short)((u + 0x7FFF + ((u>>16)&1)) >> 16);
}
DEV signed char f2i8(float f){ return (signed char)(int)f; } // f already rint+clamped

// ---------------- block reductions (256-thread blocks, 4 waves) ----------------
DEV float wredsum(float v){
#pragma unroll
  for (int o=32;o;o>>=1) v += __shfl_xor(v,o);
  return v;
}
DEV float wredmax(float v){
#pragma unroll
  for (int o=32;o;o>>=1) v = fmaxf(v,__shfl_xor(v,o));
  return v;
}
DEV float bredsum(float v, float* red){
  v = wredsum(v);
  if ((threadIdx.x&63)==0) red[threadIdx.x>>6] = v;
  __syncthreads();
  float r = red[0]+red[1]+red[2]+red[3];
  __syncthreads();
  return r;
}
DEV float bredmax(float v, float* red){
  v = wredmax(v);
  if ((threadIdx.x&63)==0) red[threadIdx.x>>6] = v;
  __syncthreads();
  float r = fmaxf(fmaxf(red[0],red[1]),fmaxf(red[2],red[3]));
  __syncthreads();
  return r;
}

// ---------------- misc ----------------
__global__ void fill_k(float* p, int n, float v){
  int i = blockIdx.x*256 + threadIdx.x;
  if (i < n) p[i] = v;
}

// merged setup: copy_init (1024 blocks) + delta (128) + ropetab (64)
__global__ __launch_bounds__(256) void setup_misc_k(const float* __restrict__ x,
                                                    float* __restrict__ h, float* __restrict__ ho,
                                                    const float* __restrict__ temb,
                                                    const float* __restrict__ lpw,
                                                    const float* __restrict__ lp2w,
                                                    const float* __restrict__ lp2b,
                                                    float* __restrict__ delta,
                                                    float* __restrict__ tab){
  __shared__ float red[4];
  int bid = blockIdx.x, t = threadIdx.x;
  if (bid < 1024){
    int i = bid*256 + t;
    float4 v = *(const float4*)(x + (size_t)i*4);
    *(float4*)(h  + (size_t)i*4) = v;
    *(float4*)(ho + (size_t)i*4) = v;
    if (i==0) ho[1048576] = 0.f;
  } else if (bid < 1152){
    int blk = bid - 1024;
    int b = blk >> 6, j = blk & 63;
    float te = temb[b*256 + t];
    float p1 = bredsum(te * lpw[j*256 + t], red);
    float p2 = bredsum(te * lp2w[j*256 + t], red);
    if (t < 8){
      int i = t;
      float frac = (float)i / 7.f;
      int jj = j & 31;
      float fr = expf(-logf(10000.f) * (float)jj * (1.f/32.f));
      float ang = frac * fr;
      float sig = (j < 32) ? sinf(ang) : cosf(ang);
      delta[i*128 + b*64 + j] = sig*p1 + p2 + lp2b[j];
    }
  } else {
    int i = (bid-1152)*256 + t;   // 16384
    int tpos = i >> 5, d = i & 31;
    float inv = powf(10000.f, -(float)d * (1.f/32.f));
    float sv, cv; sincosf((float)tpos * inv, &sv, &cv);
    tab[i*2]   = cv;
    tab[i*2+1] = sv;
  }
}

// ---------------- fused setup: 18 weight matrices ----------------
struct WSetup {
  const float* src[18];
  signed char* dst[18];
  int mode[18];     // 0 normal; 1 row-interleave even; 2 row-interleave odd
};
DEV long n4of(int mat){ return mat<9 ? 262144 : (mat<15 ? 1048576 : (mat<17 ? 8192 : 256)); }

// grid 9216: mats 0-8 x256 segs, mats 9-14 x1024 segs, mats 15-17 x256 segs.
__global__ __launch_bounds__(256) void absmean_all_k(WSetup wsu, float* __restrict__ part){
  __shared__ float red[4];
  int bid = blockIdx.x, mat, seg;
  if (bid < 2304){ mat = bid >> 8; seg = bid & 255; }
  else if (bid < 8448){ mat = 9 + ((bid-2304) >> 10); seg = (bid-2304) & 1023; }
  else { mat = 15 + ((bid-8448) >> 8); seg = (bid-8448) & 255; }
  long n4 = n4of(mat);
  int segs = (mat >= 9 && mat < 15) ? 1024 : 256;
  long cnt = n4 / segs;
  const float4* p = (const float4*)wsu.src[mat] + (long)seg*cnt;
  float s0=0.f, s1=0.f, s2=0.f, s3=0.f;
  if (cnt >= 2048){            // 8 independent streams
    long oct = cnt >> 3;
    float s[8] = {0.f,0.f,0.f,0.f,0.f,0.f,0.f,0.f};
    for (long j = threadIdx.x; j < oct; j += 256){
#pragma unroll
      for (int k=0;k<8;k++){
        float4 a = p[j + (long)k*oct];
        s[k] += fabsf(a.x)+fabsf(a.y)+fabsf(a.z)+fabsf(a.w);
      }
    }
    s0 = s[0]+s[4]; s1 = s[1]+s[5]; s2 = s[2]+s[6]; s3 = s[3]+s[7];
  } else if (cnt >= 1024){
    long quar = cnt >> 2;
    const float4* p1 = p + quar;
    const float4* p2 = p + 2*quar;
    const float4* p3 = p + 3*quar;
    for (long j = threadIdx.x; j < quar; j += 256){
      float4 a = p[j], b = p1[j], c = p2[j], d = p3[j];
      s0 += fabsf(a.x)+fabsf(a.y)+fabsf(a.z)+fabsf(a.w);
      s1 += fabsf(b.x)+fabsf(b.y)+fabsf(b.z)+fabsf(b.w);
      s2 += fabsf(c.x)+fabsf(c.y)+fabsf(c.z)+fabsf(c.w);
      s3 += fabsf(d.x)+fabsf(d.y)+fabsf(d.z)+fabsf(d.w);
    }
  } else {
    for (long j = threadIdx.x; j < cnt; j += 256){
      float4 a = p[j];
      s0 += fabsf(a.x)+fabsf(a.y)+fabsf(a.z)+fabsf(a.w);
    }
  }
  float s = bredsum(s0+s1+s2+s3, red);
  if (threadIdx.x==0) part[(long)mat*1024 + seg] = s;
}

__global__ __launch_bounds__(256) void finalize_scales_k(const float* __restrict__ part,
                                                         float* __restrict__ scales){
  __shared__ float red[4];
  const long numel[18] = {1048576, 1048576,1048576, 1048576,1048576, 1048576,1048576,
                          1048576,1048576, 4194304,4194304, 4194304,4194304, 4194304,4194304,
                          32768, 32768, 1024};
  int t = threadIdx.x;
  for (int m=0;m<18;m++){
    int segs = (m >= 9 && m < 15) ? 1024 : 256;
    float v = 0.f;
    for (int j=t; j<segs; j+=256) v += part[(long)m*1024 + j];
    v = bredsum(v, red);
    if (t==0) scales[m] = v/(float)numel[m] + 1e-8f;
  }
  if (t==0){
    for (int l=0;l<2;l++){
      scales[18+l*3+0] = scales[1+l];   // wq
      scales[18+l*3+1] = scales[3+l];   // wk
      scales[18+l*3+2] = scales[5+l];   // wv
      scales[24+l*2+0] = scales[9+l];   // wg
      scales[24+l*2+1] = scales[11+l];  // wu
    }
  }
}

__global__ __launch_bounds__(256) void quantw_all_k(WSetup wsu, const float* __restrict__ scales){
  int bid = blockIdx.x;
  int mat = 0, c = 0;
  for (;;){
    int nb = mat<9 ? 256 : (mat<15 ? 1024 : (mat<17 ? 8 : 1));
    if (bid < c + nb) break;
    c += nb; mat++;
  }
  long seg = bid - c;
  long n4 = n4of(mat);
  float s = scales[mat];
  int md = wsu.mode[mat];
  const float4* src = (const float4*)wsu.src[mat];
  char4* dst = (char4*)wsu.dst[mat];
  long base = seg*1024;
#pragma unroll
  for (int k=0;k<4;k++){
    long i = base + k*256 + threadIdx.x;
    if (i < n4){
      float4 v = src[i];
      char4 q;
      q.x = f2i8(fminf(fmaxf(rintf(v.x/s), -1.f), 1.f));
      q.y = f2i8(fminf(fmaxf(rintf(v.y/s), -1.f), 1.f));
      q.z = f2i8(fminf(fmaxf(rintf(v.z/s), -1.f), 1.f));
      q.w = f2i8(fminf(fmaxf(rintf(v.w/s), -1.f), 1.f));
      if (md == 0) dst[i] = q;
      else {
        long r = i >> 8, cc = i & 255;    // K=1024 -> 256 char4/row
        dst[(((r<<1) | (md-1))<<8) | cc] = q;
      }
    }
  }
}

// ---------------- row quant (1024 wide) -> i8; input f32 or bf16 ----------------
template<bool BF>
__global__ __launch_bounds__(256) void rowquant1k_k(const void* __restrict__ xin,
                                                    signed char* __restrict__ xq,
                                                    float* __restrict__ rs){
  __shared__ float red[4];
  int m = blockIdx.x, t = threadIdx.x;
  float v[4];
  if (BF){
    ushort4 u = *(const ushort4*)((const unsigned short*)xin + (size_t)m*1024 + t*4);
    v[0]=bf2f(u.x); v[1]=bf2f(u.y); v[2]=bf2f(u.z); v[3]=bf2f(u.w);
  } else {
    float4 f = *(const float4*)((const float*)xin + (size_t)m*1024 + t*4);
    v[0]=f.x; v[1]=f.y; v[2]=f.z; v[3]=f.w;
  }
  float am = fmaxf(fmaxf(fabsf(v[0]),fabsf(v[1])),fmaxf(fabsf(v[2]),fabsf(v[3])));
  am = bredmax(am, red);
  float a = fmaxf(am, 1e-8f), inv = 127.f/a;
  char4 q;
  q.x = f2i8(fminf(fmaxf(rintf(v[0]*inv),-128.f),127.f));
  q.y = f2i8(fminf(fmaxf(rintf(v[1]*inv),-128.f),127.f));
  q.z = f2i8(fminf(fmaxf(rintf(v[2]*inv),-128.f),127.f));
  q.w = f2i8(fminf(fmaxf(rintf(v[3]*inv),-128.f),127.f));
  *(char4*)(xq + (size_t)m*1024 + t*4) = q;
  if (t==0) rs[m] = a/127.f;
}

// ---------------- row quant (4096 wide, bf16 input) -> i8 ----------------
__global__ __launch_bounds__(256) void rowquant4k_k(const unsigned short* __restrict__ x,
                                                    signed char* __restrict__ xq,
                                                    float* __restrict__ rs){
  __shared__ float red[4];
  int m = blockIdx.x, t = threadIdx.x;
  const unsigned short* p = x + (size_t)m*4096 + t*16;
  u16x8 u0 = *(const u16x8*)p;
  u16x8 u1 = *(const u16x8*)(p + 8);
  float v[16];
#pragma unroll
  for (int j=0;j<8;j++){ v[j] = bf2f(u0[j]); v[j+8] = bf2f(u1[j]); }
  float am = 0.f;
#pragma unroll
  for (int j=0;j<16;j++) am = fmaxf(am, fabsf(v[j]));
  am = bredmax(am, red);
  float a = fmaxf(am, 1e-8f), inv = 127.f/a;
#pragma unroll
  for (int j=0;j<16;j+=4){
    char4 q;
    q.x = f2i8(fminf(fmaxf(rintf(v[j+0]*inv),-128.f),127.f));
    q.y = f2i8(fminf(fmaxf(rintf(v[j+1]*inv),-128.f),127.f));
    q.z = f2i8(fminf(fmaxf(rintf(v[j+2]*inv),-128.f),127.f));
    q.w = f2i8(fminf(fmaxf(rintf(v[j+3]*inv),-128.f),127.f));
    *(char4*)(xq + (size_t)m*4096 + t*16 + j) = q;
  }
  if (t==0) rs[m] = a/127.f;
}

// ---------------- fused: h_in = rmsnorm(h+delta, lnw); a_in quant with n1 ----------------
__global__ __launch_bounds__(256) void loopnorm_quant_k(const float* __restrict__ h,
                                                        const float* __restrict__ delta,
                                                        const float* __restrict__ lnw,
                                                        const float* __restrict__ n1,
                                                        float* __restrict__ hin,
                                                        signed char* __restrict__ xq,
                                                        float* __restrict__ rs){
  __shared__ float red[4];
  int m = blockIdx.x, t = threadIdx.x;
  int b = m >> 9;
  float v[4];
  float4 f = *(const float4*)(h + (size_t)m*1024 + t*4);
  v[0]=f.x; v[1]=f.y; v[2]=f.z; v[3]=f.w;
  if (t < 16){
#pragma unroll
    for (int j=0;j<4;j++) v[j] += delta[b*64 + t*4 + j];
  }
  float ss = v[0]*v[0]+v[1]*v[1]+v[2]*v[2]+v[3]*v[3];
  ss = bredsum(ss, red);
  float r1 = rsqrtf(ss*(1.f/1024.f) + 1e-6f);
  float w4[4];
#pragma unroll
  for (int j=0;j<4;j++) w4[j] = v[j]*r1*lnw[t*4+j];
  float4 of; of.x=w4[0]; of.y=w4[1]; of.z=w4[2]; of.w=w4[3];
  *(float4*)(hin + (size_t)m*1024 + t*4) = of;
  float s2 = w4[0]*w4[0]+w4[1]*w4[1]+w4[2]*w4[2]+w4[3]*w4[3];
  s2 = bredsum(s2, red);
  float r2 = rsqrtf(s2*(1.f/1024.f) + 1e-6f);
  float y[4];
#pragma unroll
  for (int j=0;j<4;j++) y[j] = w4[j]*r2*n1[t*4+j];
  float am = fmaxf(fmaxf(fabsf(y[0]),fabsf(y[1])),fmaxf(fabsf(y[2]),fabsf(y[3])));
  am = bredmax(am, red);
  float a = fmaxf(am, 1e-8f), inv = 127.f/a;
  char4 q;
  q.x = f2i8(fminf(fmaxf(rintf(y[0]*inv),-128.f),127.f));
  q.y = f2i8(fminf(fmaxf(rintf(y[1]*inv),-128.f),127.f));
  q.z = f2i8(fminf(fmaxf(rintf(y[2]*inv),-128.f),127.f));
  q.w = f2i8(fminf(fmaxf(rintf(y[3]*inv),-128.f),127.f));
  *(char4*)(xq + (size_t)m*1024 + t*4) = q;
  if (t==0) rs[m] = a/127.f;
}

// ---------------- i8 MFMA GEMM (triple-buffered, 2-deep prefetch, swizzled) ----------------
DEV f32x4 accfence(f32x4 c){ asm volatile("s_nop 7\n\ts_nop 7" : "+v"(c)); return c; }
DEV i32x4 accfencei(i32x4 c){ asm volatile("s_nop 7\n\ts_nop 7" : "+v"(c)); return c; }

template<bool SPLITK, bool GUSILU, bool PB16>
__global__ __launch_bounds__(256)
void gemm_i8(const signed char* __restrict__ A, const signed char* __restrict__ W,
             const float* __restrict__ rowsc, const float* __restrict__ wscv,
             const float* __restrict__ res, float* __restrict__ C, int N, int Kf, int Kc)
{
  __shared__ __align__(16) signed char As[3][8192];
  __shared__ __align__(16) signed char Bs[3][8192];
  const int tid = threadIdx.x;
  const int lane = tid & 63, wvid = tid >> 6;
  const int wr = wvid >> 1, wc = wvid & 1;
  const int bm = blockIdx.y, bn = blockIdx.x;

  const int r0 = (wvid<<4) + (lane>>2);
  const int sw = (((lane&3) ^ ((r0>>1)&3)) << 4);        // byte offset of 16B chunk
  const long kstart = SPLITK ? (long)blockIdx.z * Kc : 0;
  const signed char* gA = A + (size_t)(bm*128 + r0)*Kf + kstart + sw;
  const signed char* gB = W + (size_t)(bn*128 + r0)*Kf + kstart + sw;
  const size_t row64 = (size_t)64*Kf;

#define STAGE(buf, koff) do { \
    __builtin_amdgcn_global_load_lds(gA + (koff),         &As[buf][(wvid<<10)],      16, 0, 0); \
    __builtin_amdgcn_global_load_lds(gA + (koff) + row64, &As[buf][(wvid<<10)+4096], 16, 0, 0); \
    __builtin_amdgcn_global_load_lds(gB + (koff),         &Bs[buf][(wvid<<10)],      16, 0, 0); \
    __builtin_amdgcn_global_load_lds(gB + (koff) + row64, &Bs[buf][(wvid<<10)+4096], 16, 0, 0); \
  } while(0)

  i32x4 acc[4][4] = {};
  const int rA = (wr<<6) + (lane&15);
  const int rB = (wc<<6) + (lane&15);
  const int psA = (((lane>>4) ^ (((lane&15)>>1)&3)) << 4);  // byte offset

  const int NT = Kc >> 6;   // >= 4 for all our shapes
  STAGE(0, 0);
  STAGE(1, 64);
  int cur = 0, nxt = 1, nx2 = 2;
  for (int kt = 0; kt < NT; ++kt){
    const int k2 = kt + 2;
    const int kn = (k2 < NT) ? (k2<<6) : 0;     // wrap: dead-buffer reload, keeps vmcnt count exact
    STAGE(nx2, kn);
    asm volatile("s_waitcnt vmcnt(8)" ::: "memory");   // tile kt's 4 DMAs done; 8 stay in flight
    __builtin_amdgcn_s_barrier();
    asm volatile("" ::: "memory");
    i32x4 a[4], b[4];
    const signed char* Ab = As[cur];
    const signed char* Bb = Bs[cur];
#pragma unroll
    for (int mi=0;mi<4;mi++) a[mi] = *(const i32x4*)(Ab + (rA + mi*16)*64 + psA);
#pragma unroll
    for (int ni=0;ni<4;ni++) b[ni] = *(const i32x4*)(Bb + (rB + ni*16)*64 + psA);
#pragma unroll
    for (int mi=0;mi<4;mi++)
#pragma unroll
      for (int ni=0;ni<4;ni++)
        asm("v_mfma_i32_16x16x64_i8 %0, %1, %2, %0" : "+v"(acc[mi][ni]) : "v"(a[mi]), "v"(b[ni]));
    asm volatile("s_waitcnt lgkmcnt(0)" ::: "memory");
    __builtin_amdgcn_s_barrier();
    int tmp = cur; cur = nxt; nxt = nx2; nx2 = tmp;
  }
#undef STAGE

#pragma unroll
  for (int mi=0;mi<4;mi++)
#pragma unroll
    for (int ni=0;ni<4;ni++)
      acc[mi][ni] = accfencei(acc[mi][ni]);

  const int rif = (lane>>4)<<2;
  const int cif = lane&15;
  const int gcol0 = bn*128 + (wc<<6);

  if constexpr (SPLITK){
    if constexpr (PB16){
      unsigned short* P = (unsigned short*)C + (size_t)blockIdx.z * ((size_t)N << 10);
#pragma unroll
      for (int mi=0;mi<4;mi++)
#pragma unroll
        for (int r=0;r<4;r++){
          const int grow = bm*128 + (wr<<6) + mi*16 + rif + r;
#pragma unroll
          for (int ni=0;ni<4;ni++)
            P[(size_t)grow*N + gcol0 + ni*16 + cif] = f2bfr((float)acc[mi][ni][r]);
        }
    } else {
      float* P = C + (size_t)blockIdx.z * ((size_t)N << 10);
#pragma unroll
      for (int mi=0;mi<4;mi++)
#pragma unroll
        for (int r=0;r<4;r++){
          const int grow = bm*128 + (wr<<6) + mi*16 + rif + r;
#pragma unroll
          for (int ni=0;ni<4;ni++)
            P[(size_t)grow*N + gcol0 + ni*16 + cif] = (float)acc[mi][ni][r];
        }
    }
    return;
  }

  if constexpr (GUSILU){
    const float sg = wscv[0], su = wscv[1];
    unsigned short* Cb = (unsigned short*)C;   // bf16 [M][4096]
#pragma unroll
    for (int mi=0;mi<4;mi++){
#pragma unroll
      for (int r=0;r<4;r++){
        const int grow = bm*128 + (wr<<6) + mi*16 + rif + r;
        const float rsc = rowsc[grow];
#pragma unroll
        for (int ni=0;ni<4;ni++){
          const int gcol = gcol0 + ni*16 + cif;
          float val = (float)acc[mi][ni][r] * rsc * ((gcol & 1) ? su : sg);
          float other = __shfl_xor(val, 1);
          if (!(lane & 1)){
            float g = val, u = other;
            float outv = g/(1.f+expf(-g))*u;
            Cb[(size_t)grow*4096 + (gcol>>1)] = f2bfr(outv);
          }
        }
      }
    }
    return;
  }

#pragma unroll
  for (int mi=0;mi<4;mi++){
#pragma unroll
    for (int r=0;r<4;r++){
      const int grow = bm*128 + (wr<<6) + mi*16 + rif + r;
      const float rsc = rowsc[grow];
#pragma unroll
      for (int ni=0;ni<4;ni++){
        const int gcol = gcol0 + ni*16 + cif;
        float vvv = (float)acc[mi][ni][r] * rsc * wscv[0];
        const size_t off = (size_t)grow*N + gcol;
        if (res) vvv += res[off];
        C[off] = vvv;
      }
    }
  }
}

// ---------------- qkv GEMM: same triple-buffered loop + rope epilogue -> bf16 ----------------
// grid (24, 8). N=3072, K=1024. Each 64-col half-tile (wc) is one head-section.
__global__ __launch_bounds__(256)
void gemm_qkv128(const signed char* __restrict__ A, const signed char* __restrict__ W,
                 const float* __restrict__ rowsc, const float* __restrict__ wscv,
                 const float* __restrict__ tab, unsigned short* __restrict__ C)
{
  __shared__ __align__(16) signed char As[3][8192];
  __shared__ __align__(16) signed char Bs[3][8192];
  const int tid = threadIdx.x;
  const int lane = tid & 63, wvid = tid >> 6;
  const int wr = wvid >> 1, wc = wvid & 1;
  const int bm = blockIdx.y, bn = blockIdx.x;
  const int Kf = 1024;

  const int r0 = (wvid<<4) + (lane>>2);
  const int sw = (((lane&3) ^ ((r0>>1)&3)) << 4);
  const signed char* gA = A + (size_t)(bm*128 + r0)*Kf + sw;
  const signed char* gB = W + (size_t)(bn*128 + r0)*Kf + sw;
  const size_t row64 = (size_t)64*Kf;

#define STAGE(buf, koff) do { \
    __builtin_amdgcn_global_load_lds(gA + (koff),         &As[buf][(wvid<<10)],      16, 0, 0); \
    __builtin_amdgcn_global_load_lds(gA + (koff) + row64, &As[buf][(wvid<<10)+4096], 16, 0, 0); \
    __builtin_amdgcn_global_load_lds(gB + (koff),         &Bs[buf][(wvid<<10)],      16, 0, 0); \
    __builtin_amdgcn_global_load_lds(gB + (koff) + row64, &Bs[buf][(wvid<<10)+4096], 16, 0, 0); \
  } while(0)

  i32x4 acc[4][4] = {};
  const int rA = (wr<<6) + (lane&15);
  const int rB = (wc<<6) + (lane&15);
  const int psA = (((lane>>4) ^ (((lane&15)>>1)&3)) << 4);

  const int NT = 16;
  STAGE(0, 0);
  STAGE(1, 64);
  int cur = 0, nxt = 1, nx2 = 2;
  for (int kt = 0; kt < NT; ++kt){
    const int k2 = kt + 2;
    const int kn = (k2 < NT) ? (k2<<6) : 0;
    STAGE(nx2, kn);
    asm volatile("s_waitcnt vmcnt(8)" ::: "memory");
    __builtin_amdgcn_s_barrier();
    asm volatile("" ::: "memory");
    i32x4 a[4], b[4];
    const signed char* Ab = As[cur];
    const signed char* Bb = Bs[cur];
#pragma unroll
    for (int mi=0;mi<4;mi++) a[mi] = *(const i32x4*)(Ab + (rA + mi*16)*64 + psA);
#pragma unroll
    for (int ni=0;ni<4;ni++) b[ni] = *(const i32x4*)(Bb + (rB + ni*16)*64 + psA);
#pragma unroll
    for (int mi=0;mi<4;mi++)
#pragma unroll
      for (int ni=0;ni<4;ni++)
        asm("v_mfma_i32_16x16x64_i8 %0, %1, %2, %0" : "+v"(acc[mi][ni]) : "v"(a[mi]), "v"(b[ni]));
    asm volatile("s_waitcnt lgkmcnt(0)" ::: "memory");
    __builtin_amdgcn_s_barrier();
    int tmp = cur; cur = nxt; nxt = nx2; nx2 = tmp;
  }
#undef STAGE

#pragma unroll
  for (int mi=0;mi<4;mi++)
#pragma unroll
    for (int ni=0;ni<4;ni++)
      acc[mi][ni] = accfencei(acc[mi][ni]);

  const int rif = (lane>>4)<<2;
  const int cif = lane&15;
  const int gcol0 = bn*128 + (wc<<6);     // head-aligned 64-col span
  const int sec = gcol0 >> 10;            // 0=q, 1=k, 2=v
  const float wsc = wscv[sec] * ((sec==0) ? 0.125f : 1.f);

  if (sec < 2){
    // rope: col d pairs with d+32 -> acc[mi][np] with acc[mi][np+2], np in {0,1}
#pragma unroll
    for (int mi=0;mi<4;mi++){
#pragma unroll
      for (int r=0;r<4;r++){
        const int grow = bm*128 + (wr<<6) + mi*16 + rif + r;
        const float s = rowsc[grow] * wsc;
        const int tpos = grow & 511;
#pragma unroll
        for (int np=0;np<2;np++){
          const int d = np*16 + cif;
          float2 cs = *(const float2*)(tab + (size_t)((tpos<<5) + d)*2);
          float x1 = (float)acc[mi][np][r]   * s;
          float x2 = (float)acc[mi][np+2][r] * s;
          C[(size_t)grow*3072 + gcol0 + d]      = f2bfr(x1*cs.x - x2*cs.y);
          C[(size_t)grow*3072 + gcol0 + 32 + d] = f2bfr(x1*cs.y + x2*cs.x);
        }
      }
    }
  } else {
#pragma unroll
    for (int mi=0;mi<4;mi++){
#pragma unroll
      for (int r=0;r<4;r++){
        const int grow = bm*128 + (wr<<6) + mi*16 + rif + r;
        const float s = rowsc[grow] * wsc;
#pragma unroll
        for (int ni=0;ni<4;ni++)
          C[(size_t)grow*3072 + gcol0 + ni*16 + cif] = f2bfr((float)acc[mi][ni][r] * s);
      }
    }
  }
}

// ---------------- split-K(4) reduce (f32 partials): C = (res?) + (sum P)*rowsc*wsc ----------------
__global__ __launch_bounds__(256) void reduce4_k(const float* __restrict__ P,
                                                 const float* __restrict__ rowsc,
                                                 const float* __restrict__ wsc,
                                                 const float* __restrict__ res,
                                                 float* __restrict__ C){
  int m = blockIdx.x, t = threadIdx.x;
  float s0 = rowsc[m] * wsc[0];
  size_t off = (size_t)m*1024 + t*4;
  float4 a = *(const float4*)(P + off);
  float4 b = *(const float4*)(P + 1048576 + off);
  float4 c = *(const float4*)(P + 2097152 + off);
  float4 d = *(const float4*)(P + 3145728 + off);
  float4 o;
  o.x = (a.x+b.x+c.x+d.x)*s0;
  o.y = (a.y+b.y+c.y+d.y)*s0;
  o.z = (a.z+b.z+c.z+d.z)*s0;
  o.w = (a.w+b.w+c.w+d.w)*s0;
  if (res){
    float4 r = *(const float4*)(res + off);
    o.x += r.x; o.y += r.y; o.z += r.z; o.w += r.w;
  }
  *(float4*)(C + off) = o;
}

// ---------------- fused: split-K(4) bf16-partial reduce + residual + rmsnorm + quant ----------------
__global__ __launch_bounds__(256) void redq_norm_k(const unsigned short* __restrict__ P,
                                                   const float* rowsc,
                                                   const float* __restrict__ wsc,
                                                   const float* __restrict__ res,
                                                   const float* __restrict__ gamma,
                                                   float* __restrict__ Cout,
                                                   signed char* __restrict__ xq,
                                                   float* rs){
  __shared__ float red[4];
  int m = blockIdx.x, t = threadIdx.x;
  float s0 = rowsc[m] * wsc[0];
  size_t off = (size_t)m*1024 + t*4;
  ushort4 a = *(const ushort4*)(P + off);
  ushort4 b = *(const ushort4*)(P + 1048576 + off);
  ushort4 c = *(const ushort4*)(P + 2097152 + off);
  ushort4 d = *(const ushort4*)(P + 3145728 + off);
  float4 r4 = *(const float4*)(res + off);
  float v[4];
  v[0] = r4.x + (bf2f(a.x)+bf2f(b.x)+bf2f(c.x)+bf2f(d.x))*s0;
  v[1] = r4.y + (bf2f(a.y)+bf2f(b.y)+bf2f(c.y)+bf2f(d.y))*s0;
  v[2] = r4.z + (bf2f(a.z)+bf2f(b.z)+bf2f(c.z)+bf2f(d.z))*s0;
  v[3] = r4.w + (bf2f(a.w)+bf2f(b.w)+bf2f(c.w)+bf2f(d.w))*s0;
  float4 of; of.x=v[0]; of.y=v[1]; of.z=v[2]; of.w=v[3];
  *(float4*)(Cout + off) = of;
  float ss = v[0]*v[0]+v[1]*v[1]+v[2]*v[2]+v[3]*v[3];
  ss = bredsum(ss, red);
  float r1 = rsqrtf(ss*(1.f/1024.f) + 1e-6f);
  float y[4];
#pragma unroll
  for (int j=0;j<4;j++) y[j] = v[j]*r1*gamma[t*4+j];
  float am = fmaxf(fmaxf(fabsf(y[0]),fabsf(y[1])),fmaxf(fabsf(y[2]),fabsf(y[3])));
  am = bredmax(am, red);
  float aq = fmaxf(am, 1e-8f), inv = 127.f/aq;
  char4 q;
  q.x = f2i8(fminf(fmaxf(rintf(y[0]*inv),-128.f),127.f));
  q.y = f2i8(fminf(fmaxf(rintf(y[1]*inv),-128.f),127.f));
  q.z = f2i8(fminf(fmaxf(rintf(y[2]*inv),-128.f),127.f));
  q.w = f2i8(fminf(fmaxf(rintf(y[3]*inv),-128.f),127.f));
  *(char4*)(xq + (size_t)m*1024 + t*4) = q;
  if (t==0) rs[m] = aq/127.f;
}

// ---------------- fused tail (bf16 partials): reduce + recurrence + quant + loraDown + topk
//                  + loraUp + act-sigmoid + h_out + ponder (+ next-iter loopnorm) ----------------
__global__ __launch_bounds__(256) void redfin_k(const unsigned short* __restrict__ P,
                                                const float* __restrict__ rowsc,
                                                const float* __restrict__ wsc,
                                                const float* __restrict__ res,
                                                float* __restrict__ h,
                                                const float* __restrict__ Be,
                                                const float* __restrict__ Araw,
                                                const float* __restrict__ alpha, int it,
                                                const signed char* __restrict__ ldq,
                                                const float* __restrict__ sld,
                                                const signed char* __restrict__ luq,
                                                const float* __restrict__ slu,
                                                const signed char* __restrict__ actq,
                                                const float* __restrict__ sact,
                                                const float* __restrict__ ig,
                                                float* __restrict__ hout,
                                                float* __restrict__ ponder,
                                                const float* __restrict__ dnext,
                                                const float* __restrict__ lnw,
                                                const float* __restrict__ n1,
                                                float* __restrict__ hin,
                                                signed char* __restrict__ xqn,
                                                float* __restrict__ rsn,
                                                int doNext){
  __shared__ float red[4];
  __shared__ float xrow[1024];
  __shared__ float part[256];
  __shared__ float xs[32];
  __shared__ float sh_thr, sh_gs;
  int m = blockIdx.x, t = threadIdx.x;
  float al = alpha[it];
  float s0 = rowsc[m] * wsc[0];
  size_t off = (size_t)m*1024 + t*4;
  ushort4 a = *(const ushort4*)(P + off);
  ushort4 b = *(const ushort4*)(P + 1048576 + off);
  ushort4 c = *(const ushort4*)(P + 2097152 + off);
  ushort4 d = *(const ushort4*)(P + 3145728 + off);
  float4 r4 = *(const float4*)(res + off);
  float4 hh = *(const float4*)(h + off);
  float4 be = *(const float4*)(Be + off);
  float4 ar = *(const float4*)(Araw + t*4);
  float v[4];
  v[0] = 0.99f*tanhf(ar.x)*hh.x + be.x + al*(r4.x + (bf2f(a.x)+bf2f(b.x)+bf2f(c.x)+bf2f(d.x))*s0);
  v[1] = 0.99f*tanhf(ar.y)*hh.y + be.y + al*(r4.y + (bf2f(a.y)+bf2f(b.y)+bf2f(c.y)+bf2f(d.y))*s0);
  v[2] = 0.99f*tanhf(ar.z)*hh.z + be.z + al*(r4.z + (bf2f(a.z)+bf2f(b.z)+bf2f(c.z)+bf2f(d.z))*s0);
  v[3] = 0.99f*tanhf(ar.w)*hh.w + be.w + al*(r4.w + (bf2f(a.w)+bf2f(b.w)+bf2f(c.w)+bf2f(d.w))*s0);
  float am = fmaxf(fmaxf(fabsf(v[0]),fabsf(v[1])),fmaxf(fabsf(v[2]),fabsf(v[3])));
  am = bredmax(am, red);
  float aq = fmaxf(am, 1e-8f), inv = 127.f/aq;
#pragma unroll
  for (int j=0;j<4;j++) xrow[t*4+j] = fminf(fmaxf(rintf(v[j]*inv),-128.f),127.f);
  float rsv = aq/127.f;
  __syncthreads();
  {
    int r = t & 31, seg = t >> 5;
    const signed char* wrow = ldq + (size_t)r*1024 + seg*128;
    const float* xr = xrow + seg*128;
    float acc = 0.f;
    for (int k=0;k<128;k+=4){
      char4 w4 = *(const char4*)(wrow + k);
      acc += xr[k]*(float)w4.x + xr[k+1]*(float)w4.y + xr[k+2]*(float)w4.z + xr[k+3]*(float)w4.w;
    }
    part[t] = acc;
  }
  __syncthreads();
  if (t < 32){
    float s = 0.f;
    for (int sg=0; sg<8; sg++) s += part[sg*32 + t];
    xs[t] = s * rsv * (*sld);
  }
  __syncthreads();
  float val = 0.f, av = 0.f, amax = 0.f;
  if (t < 32){
    val = xs[t]; av = fabsf(val);
    int rank = 0;
    for (int j=0;j<32;j++){
      float aj = fabsf(xs[j]);
      amax = fmaxf(amax, aj);
      if (aj > av || (aj == av && j < t)) rank++;
    }
    if (rank == 17) sh_thr = av;
  }
  __syncthreads();
  if (t < 32){
    float a2 = fmaxf(amax, 1e-8f);
    float q = 0.f;
    if (av >= sh_thr) q = fminf(fmaxf(rintf(val*(127.f/a2)), -128.f), 127.f);
    xs[t] = q;
    if (t == 0) sh_gs = ig[it] * (*slu) * (a2/127.f);
  }
  __syncthreads();
  float gs = sh_gs;
  float hn[4];
  int n0 = t*4;
#pragma unroll
  for (int ni=0;ni<4;ni++){
    const signed char* lr = luq + (size_t)(n0+ni)*32;
    float dd = 0.f;
    for (int k=0;k<32;k+=4){
      char4 w4 = *(const char4*)(lr + k);
      dd += xs[k]*(float)w4.x + xs[k+1]*(float)w4.y + xs[k+2]*(float)w4.z + xs[k+3]*(float)w4.w;
    }
    hn[ni] = v[ni] + gs*dd;
  }
  float am2 = fmaxf(fmaxf(fabsf(hn[0]),fabsf(hn[1])),fmaxf(fabsf(hn[2]),fabsf(hn[3])));
  am2 = bredmax(am2, red);
  float a2 = fmaxf(am2, 1e-8f), inv2 = 127.f/a2;
  float zp = 0.f;
#pragma unroll
  for (int ni=0;ni<4;ni++){
    float q = fminf(fmaxf(rintf(hn[ni]*inv2),-128.f),127.f);
    zp += q * (float)actq[n0+ni];
  }
  zp = bredsum(zp, red);
  float z = zp * (a2/127.f) * (*sact);
  float wv = 1.f/(1.f+expf(-z));
#pragma unroll
  for (int ni=0;ni<4;ni++){
    size_t o2 = (size_t)m*1024 + n0+ni;
    float ho = hout[o2];
    hout[o2] = ho + wv*(hn[ni]-ho);
    h[o2] = hn[ni];
  }
  if (t==0) atomicAdd(ponder, wv * (1.f/8192.f));

  // ---- fused next-iteration loopnorm + quant ----
  if (doNext){
    int b2 = m >> 9;
    float v2[4] = {hn[0], hn[1], hn[2], hn[3]};
    if (t < 16){
#pragma unroll
      for (int j=0;j<4;j++) v2[j] += dnext[b2*64 + t*4 + j];
    }
    float ss2 = v2[0]*v2[0]+v2[1]*v2[1]+v2[2]*v2[2]+v2[3]*v2[3];
    ss2 = bredsum(ss2, red);
    float r1 = rsqrtf(ss2*(1.f/1024.f) + 1e-6f);
    float w4[4];
#pragma unroll
    for (int j=0;j<4;j++) w4[j] = v2[j]*r1*lnw[t*4+j];
    float4 of; of.x=w4[0]; of.y=w4[1]; of.z=w4[2]; of.w=w4[3];
    *(float4*)(hin + off) = of;
    float s2 = w4[0]*w4[0]+w4[1]*w4[1]+w4[2]*w4[2]+w4[3]*w4[3];
    s2 = bredsum(s2, red);
    float r2 = rsqrtf(s2*(1.f/1024.f) + 1e-6f);
    float y[4];
#pragma unroll
    for (int j=0;j<4;j++) y[j] = w4[j]*r2*n1[t*4+j];
    float am3 = fmaxf(fmaxf(fabsf(y[0]),fabsf(y[1])),fmaxf(fabsf(y[2]),fabsf(y[3])));
    am3 = bredmax(am3, red);
    float aq3 = fmaxf(am3, 1e-8f), inv3 = 127.f/aq3;
    char4 q;
    q.x = f2i8(fminf(fmaxf(rintf(y[0]*inv3),-128.f),127.f));
    q.y = f2i8(fminf(fmaxf(rintf(y[1]*inv3),-128.f),127.f));
    q.z = f2i8(fminf(fmaxf(rintf(y[2]*inv3),-128.f),127.f));
    q.w = f2i8(fminf(fmaxf(rintf(y[3]*inv3),-128.f),127.f));
    *(char4*)(xqn + off) = q;
    if (t==0) rsn[m] = aq3/127.f;
  }
}

// ---------------- MFMA flash attention, split-k over 2 blocks; bf16 partial out ----------------
DEV int swz64(int r, int c){ return r*64 + (c ^ ((r&7)<<3)); }

__global__ __launch_bounds__(256) void attn_split_k(const unsigned short* __restrict__ qkv,
                                                    unsigned short* __restrict__ Opart,
                                                    float* __restrict__ ml){
  __shared__ __align__(16) unsigned short Qs[4096];
  __shared__ __align__(16) unsigned short Ks[4096];
  __shared__ __align__(16) unsigned short Vt[4096];   // [d][k], swizzled on d
  __shared__ __align__(16) unsigned short Ps[4][1024];
  const int tid = threadIdx.x;
  const int lane = tid & 63, wv = tid >> 6;
  const int bidl = blockIdx.x & 255;
  const int z = blockIdx.x >> 8;          // 0..1
  const int qt = bidl & 7, bh = bidl >> 3;
  const int b = bh >> 4, h = bh & 15;
  const int tokb = b*512;
  const int l15 = lane & 15, lh = lane >> 4;

  { // stage Q (already scaled by 1/8)
    int r = tid >> 2, c0 = (tid & 3) << 4;
    const unsigned short* s = qkv + (size_t)(tokb + qt*64 + r)*3072 + h*64 + c0;
    u16x8 f0 = *(const u16x8*)s, f1 = *(const u16x8*)(s+8);
    *(u16x8*)(Qs + swz64(r, c0))   = f0;
    *(u16x8*)(Qs + swz64(r, c0+8)) = f1;
  }

  float m_run[4] = {-1e30f,-1e30f,-1e30f,-1e30f};
  float l_run[4] = {0.f,0.f,0.f,0.f};
  f32x4 accO[4] = {};

  const int nt = qt + 1;
  const int half = (nt + 1) >> 1;
  const int kA = z ? half : 0;
  const int kB = z ? nt : half;

  for (int kt = kA; kt < kB; ++kt){
    __syncthreads();
    { // stage K
      int r = tid >> 2, c0 = (tid & 3) << 4;
      const unsigned short* s = qkv + (size_t)(tokb + kt*64 + r)*3072 + 1024 + h*64 + c0;
      u16x8 f0 = *(const u16x8*)s, f1 = *(const u16x8*)(s+8);
      *(u16x8*)(Ks + swz64(r, c0))   = f0;
      *(u16x8*)(Ks + swz64(r, c0+8)) = f1;
    }
    { // stage V transposed
      int r0 = (tid >> 3) << 1, cv = (tid & 7) << 3;
      const unsigned short* s0 = qkv + (size_t)(tokb + kt*64 + r0)*3072 + 2048 + h*64 + cv;
      u16x8 a = *(const u16x8*)s0;
      u16x8 b2 = *(const u16x8*)(s0 + 3072);
#pragma unroll
      for (int j=0;j<8;j++){
        int d = cv + j;
        unsigned int pk = (unsigned int)a[j] | ((unsigned int)b2[j]<<16);
        *(unsigned int*)(Vt + swz64(d, r0)) = pk;
      }
    }
    __syncthreads();

    f32x4 s4[4] = {};
#pragma unroll
    for (int kc=0; kc<2; ++kc){
      i32x4 aq = *(const i32x4*)(Qs + swz64(wv*16 + l15, kc*32 + lh*8));
#pragma unroll
      for (int nt2=0; nt2<4; ++nt2){
        i32x4 bk = *(const i32x4*)(Ks + swz64(nt2*16 + l15, kc*32 + lh*8));
        asm("v_mfma_f32_16x16x32_bf16 %0, %1, %2, %0" : "+v"(s4[nt2]) : "v"(aq), "v"(bk));
      }
    }
#pragma unroll
    for (int nt2=0; nt2<4; ++nt2) s4[nt2] = accfence(s4[nt2]);

    const bool diag = (kt == qt);
    float sf[4];
#pragma unroll
    for (int r=0;r<4;r++){
      int rl = lh*4 + r;
      float mx = -1e30f;
#pragma unroll
      for (int nt2=0; nt2<4; ++nt2){
        float v = s4[nt2][r];
        if (diag && (nt2*16 + l15) > (wv*16 + rl)) v = -1e30f;
        s4[nt2][r] = v;
        mx = fmaxf(mx, v);
      }
      mx = fmaxf(mx, __shfl_xor(mx,1));
      mx = fmaxf(mx, __shfl_xor(mx,2));
      mx = fmaxf(mx, __shfl_xor(mx,4));
      mx = fmaxf(mx, __shfl_xor(mx,8));
      float mn = fmaxf(m_run[r], mx);
      sf[r] = __expf(m_run[r] - mn);
      m_run[r] = mn;
      float ps = 0.f;
#pragma unroll
      for (int nt2=0; nt2<4; ++nt2){
        float p = __expf(s4[nt2][r] - mn);
        ps += p;
        Ps[wv][swz64(rl, nt2*16 + l15)] = f2bfr(p);
      }
      ps += __shfl_xor(ps,1); ps += __shfl_xor(ps,2);
      ps += __shfl_xor(ps,4); ps += __shfl_xor(ps,8);
      l_run[r] = l_run[r]*sf[r] + ps;
    }
#pragma unroll
    for (int dt=0; dt<4; ++dt){
#pragma unroll
      for (int r=0;r<4;r++) accO[dt][r] *= sf[r];
      accO[dt] = accfence(accO[dt]);
    }
#pragma unroll
    for (int kc=0; kc<2; ++kc){
      i32x4 pa = *(const i32x4*)(Ps[wv] + swz64(l15, kc*32 + lh*8));
#pragma unroll
      for (int dt=0; dt<4; ++dt){
        i32x4 vb3 = *(const i32x4*)(Vt + swz64(dt*16 + l15, kc*32 + lh*8));
        asm("v_mfma_f32_16x16x32_bf16 %0, %1, %2, %0" : "+v"(accO[dt]) : "v"(pa), "v"(vb3));
      }
    }
  }
#pragma unroll
  for (int dt=0; dt<4; ++dt) accO[dt] = accfence(accO[dt]);
  unsigned short* Op = Opart + ((size_t)z << 20);
#pragma unroll
  for (int r=0;r<4;r++){
    int row = tokb + qt*64 + wv*16 + lh*4 + r;
    unsigned short* op = Op + (size_t)row*1024 + h*64 + l15;
#pragma unroll
    for (int dt=0; dt<4; ++dt)
      op[dt*16] = f2bfr(accO[dt][r]);
    if (l15 == 0){
      float2 v2 = make_float2(m_run[r], l_run[r]);
      *(float2*)(ml + ((size_t)(z*16 + h)*1024 + row)*2) = v2;
    }
  }
}

// ---------------- merge two attn partials (bf16) + row quant -> i8 ----------------
__global__ __launch_bounds__(256) void attn_merge_quant_k(const unsigned short* __restrict__ Opart,
                                                          const float* __restrict__ ml,
                                                          signed char* __restrict__ xq,
                                                          float* __restrict__ rs){
  __shared__ float red[4];
  int m = blockIdx.x, t = threadIdx.x;
  int head = t >> 4;                       // 4 cols per thread, 4-aligned -> single head
  float2 ml0 = *(const float2*)(ml + ((size_t)head*1024 + m)*2);
  float2 ml1 = *(const float2*)(ml + ((size_t)(16 + head)*1024 + m)*2);
  float mm = fmaxf(ml0.x, ml1.x);
  float w0 = __expf(ml0.x - mm), w1 = __expf(ml1.x - mm);
  float invl = 1.f / (ml0.y*w0 + ml1.y*w1);
  size_t off = (size_t)m*1024 + t*4;
  ushort4 u0 = *(const ushort4*)(Opart + off);
  ushort4 u1 = *(const ushort4*)(Opart + 1048576 + off);
  float v[4];
  v[0] = (bf2f(u0.x)*w0 + bf2f(u1.x)*w1)*invl;
  v[1] = (bf2f(u0.y)*w0 + bf2f(u1.y)*w1)*invl;
  v[2] = (bf2f(u0.z)*w0 + bf2f(u1.z)*w1)*invl;
  v[3] = (bf2f(u0.w)*w0 + bf2f(u1.w)*w1)*invl;
  float am = fmaxf(fmaxf(fabsf(v[0]),fabsf(v[1])),fmaxf(fabsf(v[2]),fabsf(v[3])));
  am = bredmax(am, red);
  float a = fmaxf(am, 1e-8f), inv = 127.f/a;
  char4 q;
  q.x = f2i8(fminf(fmaxf(rintf(v[0]*inv),-128.f),127.f));
  q.y = f2i8(fminf(fmaxf(rintf(v[1]*inv),-128.f),127.f));
  q.z = f2i8(fminf(fmaxf(rintf(v[2]*inv),-128.f),127.f));
  q.w = f2i8(fminf(fmaxf(rintf(v[3]*inv),-128.f),127.f));
  *(char4*)(xq + (size_t)m*1024 + t*4) = q;
  if (t==0) rs[m] = a/127.f;
}

// ================= host =================
extern "C" void kernel_launch(void* const* d_in, const int* in_sizes, int n_in,
                              void* d_out, int out_size, void* d_ws, size_t ws_size,
                              hipStream_t stream)
{
  (void)in_sizes; (void)n_in;
  const float* x     = (const float*)d_in[0];
  const float* e     = (const float*)d_in[1];
  const float* temb  = (const float*)d_in[2];
  const float* bn1   = (const float*)d_in[3];
  const float* bwq   = (const float*)d_in[4];
  const float* bwk   = (const float*)d_in[5];
  const float* bwv   = (const float*)d_in[6];
  const float* bwo   = (const float*)d_in[7];
  const float* bn2   = (const float*)d_in[8];
  const float* bwg   = (const float*)d_in[9];
  const float* bwu   = (const float*)d_in[10];
  const float* bwd   = (const float*)d_in[11];
  const float* Araw  = (const float*)d_in[12];
  const float* Bw    = (const float*)d_in[13];
  const float* ldw   = (const float*)d_in[14];
  const float* luw   = (const float*)d_in[15];
  const float* ig    = (const float*)d_in[16];
  const float* actw  = (const float*)d_in[17];
  const float* alph  = (const float*)d_in[18];
  const float* lpw   = (const float*)d_in[19];
  const float* lp2w  = (const float*)d_in[20];
  const float* lp2b  = (const float*)d_in[21];
  const float* lnw   = (const float*)d_in[22];

  char* ws = (char*)d_ws;
  float* out = (float*)d_out;
  const size_t WS_NEEDED = 94600704ull;
  if (ws_size < WS_NEEDED){
    fill_k<<<(out_size+255)/256,256,0,stream>>>(out, out_size, 1.0e9f);
    return;
  }

  signed char* qw_qkv = (signed char*)(ws + 0);          // 6 MB
  signed char* qw_wo  = (signed char*)(ws + 6291456);    // 2 MB
  signed char* qw_gu  = (signed char*)(ws + 8388608);    // 16 MB (g/u row-interleaved)
  signed char* qw_wd  = (signed char*)(ws + 25165824);   // 8 MB
  signed char* qw_bw  = (signed char*)(ws + 33554432);   // 1 MB
  signed char* qw_ld  = (signed char*)(ws + 34603008);
  signed char* qw_lu  = (signed char*)(ws + 34635776);
  signed char* qw_act = (signed char*)(ws + 34668544);
  float* scales = (float*)(ws + 34669568);
  float* delta  = (float*)(ws + 34688512);
  float* hbuf   = (float*)(ws + 34692608);
  float* Bebuf  = (float*)(ws + 38886912);
  float* bufX   = (float*)(ws + 43081216);
  float* bufY   = (float*)(ws + 47275520);
  float* gub    = (float*)(ws + 51469824);               // scratch: partials / attn Opart / silu out
  unsigned short* qkv_bf = (unsigned short*)(ws + 76635648);  // 6 MB bf16 qkv
  float* mlbuf  = (float*)(ws + 85024256);               // 256 KB attn m/l partials
  signed char* xq1k = (signed char*)(ws + 89218560);
  float* rs1k   = (float*)(ws + 90267136);
  signed char* xqm  = (signed char*)(ws + 90271232);
  float* rsm    = (float*)(ws + 94465536);
  float* ropetab= (float*)(ws + 94469632);               // 128 KB
  float* part   = gub;                                   // absmean partials (setup only)

  // ---- setup: scales + ternary weights ----
  WSetup wsu;
  wsu.src[0]=Bw;
  wsu.src[1]=bwq; wsu.src[2]=bwq+1048576;
  wsu.src[3]=bwk; wsu.src[4]=bwk+1048576;
  wsu.src[5]=bwv; wsu.src[6]=bwv+1048576;
  wsu.src[7]=bwo; wsu.src[8]=bwo+1048576;
  wsu.src[9]=bwg; wsu.src[10]=bwg+4194304;
  wsu.src[11]=bwu; wsu.src[12]=bwu+4194304;
  wsu.src[13]=bwd; wsu.src[14]=bwd+4194304;
  wsu.src[15]=ldw; wsu.src[16]=luw; wsu.src[17]=actw;
  wsu.dst[0]=qw_bw;
  wsu.dst[1]=qw_qkv;             wsu.dst[2]=qw_qkv+3145728;
  wsu.dst[3]=qw_qkv+1048576;     wsu.dst[4]=qw_qkv+3145728+1048576;
  wsu.dst[5]=qw_qkv+2097152;     wsu.dst[6]=qw_qkv+3145728+2097152;
  wsu.dst[7]=qw_wo;              wsu.dst[8]=qw_wo+1048576;
  wsu.dst[9]=qw_gu;              wsu.dst[10]=qw_gu+8388608;
  wsu.dst[11]=qw_gu;             wsu.dst[12]=qw_gu+8388608;
  wsu.dst[13]=qw_wd;             wsu.dst[14]=qw_wd+4194304;
  wsu.dst[15]=qw_ld; wsu.dst[16]=qw_lu; wsu.dst[17]=qw_act;
  for (int i=0;i<18;i++) wsu.mode[i]=0;
  wsu.mode[9]=1;  wsu.mode[10]=1;   // wg -> even rows
  wsu.mode[11]=2; wsu.mode[12]=2;   // wu -> odd rows

  absmean_all_k<<<9216,256,0,stream>>>(wsu, part);
  finalize_scales_k<<<1,256,0,stream>>>(part, scales);
  quantw_all_k<<<8465,256,0,stream>>>(wsu, scales);

  // ---- misc setup (copy_init + delta + ropetab merged) ----
  setup_misc_k<<<1216,256,0,stream>>>(x, hbuf, out, temb, lpw, lp2w, lp2b, delta, ropetab);

  // Be = bitlinear(e, B_w)  (splitK x4, f32 partials — setup only)
  rowquant1k_k<false><<<1024,256,0,stream>>>(e, xq1k, rs1k);
  { dim3 g(8,8,4); gemm_i8<true,false,false><<<g,256,0,stream>>>(xq1k, qw_bw, nullptr, nullptr, nullptr, gub, 1024, 1024, 256); }
  reduce4_k<<<1024,256,0,stream>>>(gub, rs1k, scales+0, nullptr, Bebuf);

  // ---- main recurrent loop (n_loops = 8) ----
  for (int it=0; it<8; ++it){
    if (it==0)
      loopnorm_quant_k<<<1024,256,0,stream>>>(hbuf, delta, lnw, bn1, bufX, xq1k, rs1k);
    for (int l=0;l<2;l++){
      // qkv: 128x128 GEMM + fused scale/rope epilogue -> bf16 qkvb
      { dim3 g(24,8); gemm_qkv128<<<g,256,0,stream>>>(xq1k, qw_qkv + (size_t)l*3145728, rs1k, scales+18+l*3, ropetab, qkv_bf); }
      // attention split over 2 k-halves (512 blocks) + merge/quant; bf16 partials
      attn_split_k<<<512,256,0,stream>>>(qkv_bf, (unsigned short*)gub, mlbuf);
      attn_merge_quant_k<<<1024,256,0,stream>>>((const unsigned short*)gub, mlbuf, xq1k, rs1k);
      // wo (splitK x4, bf16 partials) + fused reduce+residual+rmsnorm(bn2)+quant
      { dim3 g(8,8,4); gemm_i8<true,false,true><<<g,256,0,stream>>>(xq1k, qw_wo + (size_t)l*1048576, nullptr, nullptr, nullptr, gub, 1024, 1024, 256); }
      redq_norm_k<<<1024,256,0,stream>>>((const unsigned short*)gub, rs1k, scales+7+l, bufX, bn2 + (size_t)l*1024, bufY, xq1k, rs1k);
      // gu with fused silu epilogue -> bf16 [1024][4096]
      { dim3 g(64,8); gemm_i8<false,true,false><<<g,256,0,stream>>>(xq1k, qw_gu + (size_t)l*8388608, rs1k, scales+24+l*2, nullptr, gub, 8192, 1024, 1024); }
      rowquant4k_k<<<1024,256,0,stream>>>((const unsigned short*)gub, xqm, rsm);
      // wd (splitK x4, bf16 partials)
      { dim3 g(8,8,4); gemm_i8<true,false,true><<<g,256,0,stream>>>(xqm, qw_wd + (size_t)l*4194304, nullptr, nullptr, nullptr, gub, 1024, 4096, 1024); }
      if (l==0){
        redq_norm_k<<<1024,256,0,stream>>>((const unsigned short*)gub, rsm, scales+13, bufY, bn1 + 1024, bufX, xq1k, rs1k);
      } else {
        redfin_k<<<1024,256,0,stream>>>((const unsigned short*)gub, rsm, scales+14, bufY, hbuf, Bebuf, Araw, alph, it,
                                        qw_ld, scales+15, qw_lu, scales+16, qw_act, scales+17,
                                        ig, out, out + 1048576,
                                        delta + (it+1 < 8 ? (it+1)*128 : 0), lnw, bn1, bufX, xq1k, rs1k,
                                        (it < 7) ? 1 : 0);
      }
    }
  }
}

// Round 16
// 1782.127 us; speedup vs baseline: 1.0636x; 1.0024x over previous
//
#include <hip/hip_runtime.h>
#include <stdint.h>

#define DEV static __device__ __forceinline__

typedef float f32x4 __attribute__((ext_vector_type(4)));
typedef int   i32x4 __attribute__((ext_vector_type(4)));
typedef unsigned short u16x8 __attribute__((ext_vector_type(8)));

DEV float bf2f(unsigned short u){ return __uint_as_float(((unsigned int)u)<<16); }
DEV unsigned short f2bfr(float f){ // round-to-nearest-even bf16
  unsigned int u = __float_as_uint(f);
  return (unsigned short)((u + 0x7FFF + ((u>>16)&1)) >> 16);
}
DEV signed char f2i8(float f){ return (signed char)(int)f; } // f already rint+clamped

// ---------------- block reductions (256-thread blocks, 4 waves) ----------------
DEV float wredsum(float v){
#pragma unroll
  for (int o=32;o;o>>=1) v += __shfl_xor(v,o);
  return v;
}
DEV float wredmax(float v){
#pragma unroll
  for (int o=32;o;o>>=1) v = fmaxf(v,__shfl_xor(v,o));
  return v;
}
DEV float bredsum(float v, float* red){
  v = wredsum(v);
  if ((threadIdx.x&63)==0) red[threadIdx.x>>6] = v;
  __syncthreads();
  float r = red[0]+red[1]+red[2]+red[3];
  __syncthreads();
  return r;
}
DEV float bredmax(float v, float* red){
  v = wredmax(v);
  if ((threadIdx.x&63)==0) red[threadIdx.x>>6] = v;
  __syncthreads();
  float r = fmaxf(fmaxf(red[0],red[1]),fmaxf(red[2],red[3]));
  __syncthreads();
  return r;
}

// ---------------- misc ----------------
__global__ void fill_k(float* p, int n, float v){
  int i = blockIdx.x*256 + threadIdx.x;
  if (i < n) p[i] = v;
}

// merged setup: copy_init (1024 blocks) + delta (128) + ropetab (64)
__global__ __launch_bounds__(256) void setup_misc_k(const float* __restrict__ x,
                                                    float* __restrict__ h, float* __restrict__ ho,
                                                    const float* __restrict__ temb,
                                                    const float* __restrict__ lpw,
                                                    const float* __restrict__ lp2w,
                                                    const float* __restrict__ lp2b,
                                                    float* __restrict__ delta,
                                                    float* __restrict__ tab){
  __shared__ float red[4];
  int bid = blockIdx.x, t = threadIdx.x;
  if (bid < 1024){
    int i = bid*256 + t;
    float4 v = *(const float4*)(x + (size_t)i*4);
    *(float4*)(h  + (size_t)i*4) = v;
    *(float4*)(ho + (size_t)i*4) = v;
    if (i==0) ho[1048576] = 0.f;
  } else if (bid < 1152){
    int blk = bid - 1024;
    int b = blk >> 6, j = blk & 63;
    float te = temb[b*256 + t];
    float p1 = bredsum(te * lpw[j*256 + t], red);
    float p2 = bredsum(te * lp2w[j*256 + t], red);
    if (t < 8){
      int i = t;
      float frac = (float)i / 7.f;
      int jj = j & 31;
      float fr = expf(-logf(10000.f) * (float)jj * (1.f/32.f));
      float ang = frac * fr;
      float sig = (j < 32) ? sinf(ang) : cosf(ang);
      delta[i*128 + b*64 + j] = sig*p1 + p2 + lp2b[j];
    }
  } else {
    int i = (bid-1152)*256 + t;   // 16384
    int tpos = i >> 5, d = i & 31;
    float inv = powf(10000.f, -(float)d * (1.f/32.f));
    float sv, cv; sincosf((float)tpos * inv, &sv, &cv);
    tab[i*2]   = cv;
    tab[i*2+1] = sv;
  }
}

// ---------------- fused setup: 18 weight matrices ----------------
struct WSetup {
  const float* src[18];
  signed char* dst[18];
  int mode[18];     // 0 normal; 1 row-interleave even; 2 row-interleave odd
};
DEV long n4of(int mat){ return mat<9 ? 262144 : (mat<15 ? 1048576 : (mat<17 ? 8192 : 256)); }

// block -> (mat, seg of 4096 float4 = 64 KB). grid 2117:
// mats 0-8: 64 segs each (0..575); mats 9-14: 256 segs (576..2111);
// mats 15,16: 2 segs (2112..2115); mat 17: 1 seg (2116).
DEV void setup_map(int bid, int& mat, int& seg){
  if (bid < 576){ mat = bid >> 6; seg = bid & 63; }
  else if (bid < 2112){ mat = 9 + ((bid-576) >> 8); seg = (bid-576) & 255; }
  else if (bid < 2116){ mat = 15 + ((bid-2112) >> 1); seg = (bid-2112) & 1; }
  else { mat = 17; seg = 0; }
}

__global__ __launch_bounds__(256) void absmean_all_k(WSetup wsu, float* __restrict__ part){
  __shared__ float red[4];
  int mat, seg;
  setup_map(blockIdx.x, mat, seg);
  long n4 = n4of(mat);
  long base = (long)seg*4096;
  long chunk = (n4 - base < 4096) ? (n4 - base) : 4096;
  const float4* p = (const float4*)wsu.src[mat] + base;
  float s0=0.f, s1=0.f, s2=0.f, s3=0.f;
  if (chunk == 4096){
    const long quar = 1024;
    const float4* p1 = p + quar;
    const float4* p2 = p + 2*quar;
    const float4* p3 = p + 3*quar;
#pragma unroll
    for (int jj=0;jj<4;jj++){
      long j = threadIdx.x + jj*256;
      float4 a = p[j], b = p1[j], c = p2[j], d = p3[j];
      s0 += fabsf(a.x)+fabsf(a.y)+fabsf(a.z)+fabsf(a.w);
      s1 += fabsf(b.x)+fabsf(b.y)+fabsf(b.z)+fabsf(b.w);
      s2 += fabsf(c.x)+fabsf(c.y)+fabsf(c.z)+fabsf(c.w);
      s3 += fabsf(d.x)+fabsf(d.y)+fabsf(d.z)+fabsf(d.w);
    }
  } else {
    for (long j = threadIdx.x; j < chunk; j += 256){
      float4 a = p[j];
      s0 += fabsf(a.x)+fabsf(a.y)+fabsf(a.z)+fabsf(a.w);
    }
  }
  float s = bredsum(s0+s1+s2+s3, red);
  if (threadIdx.x==0) part[(long)mat*1024 + seg] = s;
}

__global__ __launch_bounds__(256) void finalize_scales_k(const float* __restrict__ part,
                                                         float* __restrict__ scales){
  __shared__ float red[4];
  const long numel[18] = {1048576, 1048576,1048576, 1048576,1048576, 1048576,1048576,
                          1048576,1048576, 4194304,4194304, 4194304,4194304, 4194304,4194304,
                          32768, 32768, 1024};
  int t = threadIdx.x;
  for (int m=0;m<18;m++){
    int segs = (m < 9) ? 64 : (m < 15 ? 256 : (m < 17 ? 2 : 1));
    float v = 0.f;
    for (int j=t; j<segs; j+=256) v += part[(long)m*1024 + j];
    v = bredsum(v, red);
    if (t==0) scales[m] = v/(float)numel[m] + 1e-8f;
  }
  if (t==0){
    for (int l=0;l<2;l++){
      scales[18+l*3+0] = scales[1+l];   // wq
      scales[18+l*3+1] = scales[3+l];   // wk
      scales[18+l*3+2] = scales[5+l];   // wv
      scales[24+l*2+0] = scales[9+l];   // wg
      scales[24+l*2+1] = scales[11+l];  // wu
    }
  }
}

__global__ __launch_bounds__(256) void quantw_all_k(WSetup wsu, const float* __restrict__ scales){
  int mat, seg;
  setup_map(blockIdx.x, mat, seg);
  long n4 = n4of(mat);
  float s = scales[mat];
  int md = wsu.mode[mat];
  const float4* src = (const float4*)wsu.src[mat];
  char4* dst = (char4*)wsu.dst[mat];
  long base = (long)seg*4096;
  long end = (base + 4096 < n4) ? (base + 4096) : n4;
#pragma unroll 4
  for (long i = base + threadIdx.x; i < end; i += 256){
    float4 v = src[i];
    char4 q;
    q.x = f2i8(fminf(fmaxf(rintf(v.x/s), -1.f), 1.f));
    q.y = f2i8(fminf(fmaxf(rintf(v.y/s), -1.f), 1.f));
    q.z = f2i8(fminf(fmaxf(rintf(v.z/s), -1.f), 1.f));
    q.w = f2i8(fminf(fmaxf(rintf(v.w/s), -1.f), 1.f));
    if (md == 0) dst[i] = q;
    else {
      long r = i >> 8, cc = i & 255;    // K=1024 -> 256 char4/row
      dst[(((r<<1) | (md-1))<<8) | cc] = q;
    }
  }
}

// ---------------- row quant (1024 wide) -> i8; input f32 or bf16 ----------------
template<bool BF>
__global__ __launch_bounds__(256) void rowquant1k_k(const void* __restrict__ xin,
                                                    signed char* __restrict__ xq,
                                                    float* __restrict__ rs){
  __shared__ float red[4];
  int m = blockIdx.x, t = threadIdx.x;
  float v[4];
  if (BF){
    ushort4 u = *(const ushort4*)((const unsigned short*)xin + (size_t)m*1024 + t*4);
    v[0]=bf2f(u.x); v[1]=bf2f(u.y); v[2]=bf2f(u.z); v[3]=bf2f(u.w);
  } else {
    float4 f = *(const float4*)((const float*)xin + (size_t)m*1024 + t*4);
    v[0]=f.x; v[1]=f.y; v[2]=f.z; v[3]=f.w;
  }
  float am = fmaxf(fmaxf(fabsf(v[0]),fabsf(v[1])),fmaxf(fabsf(v[2]),fabsf(v[3])));
  am = bredmax(am, red);
  float a = fmaxf(am, 1e-8f), inv = 127.f/a;
  char4 q;
  q.x = f2i8(fminf(fmaxf(rintf(v[0]*inv),-128.f),127.f));
  q.y = f2i8(fminf(fmaxf(rintf(v[1]*inv),-128.f),127.f));
  q.z = f2i8(fminf(fmaxf(rintf(v[2]*inv),-128.f),127.f));
  q.w = f2i8(fminf(fmaxf(rintf(v[3]*inv),-128.f),127.f));
  *(char4*)(xq + (size_t)m*1024 + t*4) = q;
  if (t==0) rs[m] = a/127.f;
}

// ---------------- row quant (4096 wide, bf16 input) -> i8 ----------------
__global__ __launch_bounds__(256) void rowquant4k_k(const unsigned short* __restrict__ x,
                                                    signed char* __restrict__ xq,
                                                    float* __restrict__ rs){
  __shared__ float red[4];
  int m = blockIdx.x, t = threadIdx.x;
  const unsigned short* p = x + (size_t)m*4096 + t*16;
  u16x8 u0 = *(const u16x8*)p;
  u16x8 u1 = *(const u16x8*)(p + 8);
  float v[16];
#pragma unroll
  for (int j=0;j<8;j++){ v[j] = bf2f(u0[j]); v[j+8] = bf2f(u1[j]); }
  float am = 0.f;
#pragma unroll
  for (int j=0;j<16;j++) am = fmaxf(am, fabsf(v[j]));
  am = bredmax(am, red);
  float a = fmaxf(am, 1e-8f), inv = 127.f/a;
#pragma unroll
  for (int j=0;j<16;j+=4){
    char4 q;
    q.x = f2i8(fminf(fmaxf(rintf(v[j+0]*inv),-128.f),127.f));
    q.y = f2i8(fminf(fmaxf(rintf(v[j+1]*inv),-128.f),127.f));
    q.z = f2i8(fminf(fmaxf(rintf(v[j+2]*inv),-128.f),127.f));
    q.w = f2i8(fminf(fmaxf(rintf(v[j+3]*inv),-128.f),127.f));
    *(char4*)(xq + (size_t)m*4096 + t*16 + j) = q;
  }
  if (t==0) rs[m] = a/127.f;
}

// ---------------- fused: h_in = rmsnorm(h+delta, lnw); a_in quant with n1 ----------------
__global__ __launch_bounds__(256) void loopnorm_quant_k(const float* __restrict__ h,
                                                        const float* __restrict__ delta,
                                                        const float* __restrict__ lnw,
                                                        const float* __restrict__ n1,
                                                        float* __restrict__ hin,
                                                        signed char* __restrict__ xq,
                                                        float* __restrict__ rs){
  __shared__ float red[4];
  int m = blockIdx.x, t = threadIdx.x;
  int b = m >> 9;
  float v[4];
  float4 f = *(const float4*)(h + (size_t)m*1024 + t*4);
  v[0]=f.x; v[1]=f.y; v[2]=f.z; v[3]=f.w;
  if (t < 16){
#pragma unroll
    for (int j=0;j<4;j++) v[j] += delta[b*64 + t*4 + j];
  }
  float ss = v[0]*v[0]+v[1]*v[1]+v[2]*v[2]+v[3]*v[3];
  ss = bredsum(ss, red);
  float r1 = rsqrtf(ss*(1.f/1024.f) + 1e-6f);
  float w4[4];
#pragma unroll
  for (int j=0;j<4;j++) w4[j] = v[j]*r1*lnw[t*4+j];
  float4 of; of.x=w4[0]; of.y=w4[1]; of.z=w4[2]; of.w=w4[3];
  *(float4*)(hin + (size_t)m*1024 + t*4) = of;
  float s2 = w4[0]*w4[0]+w4[1]*w4[1]+w4[2]*w4[2]+w4[3]*w4[3];
  s2 = bredsum(s2, red);
  float r2 = rsqrtf(s2*(1.f/1024.f) + 1e-6f);
  float y[4];
#pragma unroll
  for (int j=0;j<4;j++) y[j] = w4[j]*r2*n1[t*4+j];
  float am = fmaxf(fmaxf(fabsf(y[0]),fabsf(y[1])),fmaxf(fabsf(y[2]),fabsf(y[3])));
  am = bredmax(am, red);
  float a = fmaxf(am, 1e-8f), inv = 127.f/a;
  char4 q;
  q.x = f2i8(fminf(fmaxf(rintf(y[0]*inv),-128.f),127.f));
  q.y = f2i8(fminf(fmaxf(rintf(y[1]*inv),-128.f),127.f));
  q.z = f2i8(fminf(fmaxf(rintf(y[2]*inv),-128.f),127.f));
  q.w = f2i8(fminf(fmaxf(rintf(y[3]*inv),-128.f),127.f));
  *(char4*)(xq + (size_t)m*1024 + t*4) = q;
  if (t==0) rs[m] = a/127.f;
}

// ---------------- i8 MFMA GEMM (triple-buffered, 2-deep prefetch, swizzled) ----------------
DEV f32x4 accfence(f32x4 c){ asm volatile("s_nop 7\n\ts_nop 7" : "+v"(c)); return c; }
DEV i32x4 accfencei(i32x4 c){ asm volatile("s_nop 7\n\ts_nop 7" : "+v"(c)); return c; }

template<bool SPLITK, bool GUSILU, bool PB16>
__global__ __launch_bounds__(256)
void gemm_i8(const signed char* __restrict__ A, const signed char* __restrict__ W,
             const float* __restrict__ rowsc, const float* __restrict__ wscv,
             const float* __restrict__ res, float* __restrict__ C, int N, int Kf, int Kc)
{
  __shared__ __align__(16) signed char As[3][8192];
  __shared__ __align__(16) signed char Bs[3][8192];
  const int tid = threadIdx.x;
  const int lane = tid & 63, wvid = tid >> 6;
  const int wr = wvid >> 1, wc = wvid & 1;
  const int bm = blockIdx.y, bn = blockIdx.x;

  const int r0 = (wvid<<4) + (lane>>2);
  const int sw = (((lane&3) ^ ((r0>>1)&3)) << 4);        // byte offset of 16B chunk
  const long kstart = SPLITK ? (long)blockIdx.z * Kc : 0;
  const signed char* gA = A + (size_t)(bm*128 + r0)*Kf + kstart + sw;
  const signed char* gB = W + (size_t)(bn*128 + r0)*Kf + kstart + sw;
  const size_t row64 = (size_t)64*Kf;

#define STAGE(buf, koff) do { \
    __builtin_amdgcn_global_load_lds(gA + (koff),         &As[buf][(wvid<<10)],      16, 0, 0); \
    __builtin_amdgcn_global_load_lds(gA + (koff) + row64, &As[buf][(wvid<<10)+4096], 16, 0, 0); \
    __builtin_amdgcn_global_load_lds(gB + (koff),         &Bs[buf][(wvid<<10)],      16, 0, 0); \
    __builtin_amdgcn_global_load_lds(gB + (koff) + row64, &Bs[buf][(wvid<<10)+4096], 16, 0, 0); \
  } while(0)

  i32x4 acc[4][4] = {};
  const int rA = (wr<<6) + (lane&15);
  const int rB = (wc<<6) + (lane&15);
  const int psA = (((lane>>4) ^ (((lane&15)>>1)&3)) << 4);  // byte offset

  const int NT = Kc >> 6;   // >= 4 for all our shapes
  STAGE(0, 0);
  STAGE(1, 64);
  int cur = 0, nxt = 1, nx2 = 2;
  for (int kt = 0; kt < NT; ++kt){
    const int k2 = kt + 2;
    const int kn = (k2 < NT) ? (k2<<6) : 0;     // wrap: dead-buffer reload, keeps vmcnt count exact
    STAGE(nx2, kn);
    asm volatile("s_waitcnt vmcnt(8)" ::: "memory");   // tile kt's 4 DMAs done; 8 stay in flight
    __builtin_amdgcn_s_barrier();
    asm volatile("" ::: "memory");
    i32x4 a[4], b[4];
    const signed char* Ab = As[cur];
    const signed char* Bb = Bs[cur];
#pragma unroll
    for (int mi=0;mi<4;mi++) a[mi] = *(const i32x4*)(Ab + (rA + mi*16)*64 + psA);
#pragma unroll
    for (int ni=0;ni<4;ni++) b[ni] = *(const i32x4*)(Bb + (rB + ni*16)*64 + psA);
#pragma unroll
    for (int mi=0;mi<4;mi++)
#pragma unroll
      for (int ni=0;ni<4;ni++)
        asm("v_mfma_i32_16x16x64_i8 %0, %1, %2, %0" : "+v"(acc[mi][ni]) : "v"(a[mi]), "v"(b[ni]));
    asm volatile("s_waitcnt lgkmcnt(0)" ::: "memory");
    __builtin_amdgcn_s_barrier();
    int tmp = cur; cur = nxt; nxt = nx2; nx2 = tmp;
  }
#undef STAGE

#pragma unroll
  for (int mi=0;mi<4;mi++)
#pragma unroll
    for (int ni=0;ni<4;ni++)
      acc[mi][ni] = accfencei(acc[mi][ni]);

  const int rif = (lane>>4)<<2;
  const int cif = lane&15;
  const int gcol0 = bn*128 + (wc<<6);

  if constexpr (SPLITK){
    if constexpr (PB16){
      unsigned short* P = (unsigned short*)C + (size_t)blockIdx.z * ((size_t)N << 10);
#pragma unroll
      for (int mi=0;mi<4;mi++)
#pragma unroll
        for (int r=0;r<4;r++){
          const int grow = bm*128 + (wr<<6) + mi*16 + rif + r;
#pragma unroll
          for (int ni=0;ni<4;ni++)
            P[(size_t)grow*N + gcol0 + ni*16 + cif] = f2bfr((float)acc[mi][ni][r]);
        }
    } else {
      float* P = C + (size_t)blockIdx.z * ((size_t)N << 10);
#pragma unroll
      for (int mi=0;mi<4;mi++)
#pragma unroll
        for (int r=0;r<4;r++){
          const int grow = bm*128 + (wr<<6) + mi*16 + rif + r;
#pragma unroll
          for (int ni=0;ni<4;ni++)
            P[(size_t)grow*N + gcol0 + ni*16 + cif] = (float)acc[mi][ni][r];
        }
    }
    return;
  }

  if constexpr (GUSILU){
    const float sg = wscv[0], su = wscv[1];
    unsigned short* Cb = (unsigned short*)C;   // bf16 [M][4096]
#pragma unroll
    for (int mi=0;mi<4;mi++){
#pragma unroll
      for (int r=0;r<4;r++){
        const int grow = bm*128 + (wr<<6) + mi*16 + rif + r;
        const float rsc = rowsc[grow];
#pragma unroll
        for (int ni=0;ni<4;ni++){
          const int gcol = gcol0 + ni*16 + cif;
          float val = (float)acc[mi][ni][r] * rsc * ((gcol & 1) ? su : sg);
          float other = __shfl_xor(val, 1);
          if (!(lane & 1)){
            float g = val, u = other;
            float outv = g/(1.f+expf(-g))*u;
            Cb[(size_t)grow*4096 + (gcol>>1)] = f2bfr(outv);
          }
        }
      }
    }
    return;
  }

#pragma unroll
  for (int mi=0;mi<4;mi++){
#pragma unroll
    for (int r=0;r<4;r++){
      const int grow = bm*128 + (wr<<6) + mi*16 + rif + r;
      const float rsc = rowsc[grow];
#pragma unroll
      for (int ni=0;ni<4;ni++){
        const int gcol = gcol0 + ni*16 + cif;
        float vvv = (float)acc[mi][ni][r] * rsc * wscv[0];
        const size_t off = (size_t)grow*N + gcol;
        if (res) vvv += res[off];
        C[off] = vvv;
      }
    }
  }
}

// ---------------- qkv GEMM: same triple-buffered loop + rope epilogue -> bf16 ----------------
// grid (24, 8). N=3072, K=1024. Each 64-col half-tile (wc) is one head-section.
__global__ __launch_bounds__(256)
void gemm_qkv128(const signed char* __restrict__ A, const signed char* __restrict__ W,
                 const float* __restrict__ rowsc, const float* __restrict__ wscv,
                 const float* __restrict__ tab, unsigned short* __restrict__ C)
{
  __shared__ __align__(16) signed char As[3][8192];
  __shared__ __align__(16) signed char Bs[3][8192];
  const int tid = threadIdx.x;
  const int lane = tid & 63, wvid = tid >> 6;
  const int wr = wvid >> 1, wc = wvid & 1;
  const int bm = blockIdx.y, bn = blockIdx.x;
  const int Kf = 1024;

  const int r0 = (wvid<<4) + (lane>>2);
  const int sw = (((lane&3) ^ ((r0>>1)&3)) << 4);
  const signed char* gA = A + (size_t)(bm*128 + r0)*Kf + sw;
  const signed char* gB = W + (size_t)(bn*128 + r0)*Kf + sw;
  const size_t row64 = (size_t)64*Kf;

#define STAGE(buf, koff) do { \
    __builtin_amdgcn_global_load_lds(gA + (koff),         &As[buf][(wvid<<10)],      16, 0, 0); \
    __builtin_amdgcn_global_load_lds(gA + (koff) + row64, &As[buf][(wvid<<10)+4096], 16, 0, 0); \
    __builtin_amdgcn_global_load_lds(gB + (koff),         &Bs[buf][(wvid<<10)],      16, 0, 0); \
    __builtin_amdgcn_global_load_lds(gB + (koff) + row64, &Bs[buf][(wvid<<10)+4096], 16, 0, 0); \
  } while(0)

  i32x4 acc[4][4] = {};
  const int rA = (wr<<6) + (lane&15);
  const int rB = (wc<<6) + (lane&15);
  const int psA = (((lane>>4) ^ (((lane&15)>>1)&3)) << 4);

  const int NT = 16;
  STAGE(0, 0);
  STAGE(1, 64);
  int cur = 0, nxt = 1, nx2 = 2;
  for (int kt = 0; kt < NT; ++kt){
    const int k2 = kt + 2;
    const int kn = (k2 < NT) ? (k2<<6) : 0;
    STAGE(nx2, kn);
    asm volatile("s_waitcnt vmcnt(8)" ::: "memory");
    __builtin_amdgcn_s_barrier();
    asm volatile("" ::: "memory");
    i32x4 a[4], b[4];
    const signed char* Ab = As[cur];
    const signed char* Bb = Bs[cur];
#pragma unroll
    for (int mi=0;mi<4;mi++) a[mi] = *(const i32x4*)(Ab + (rA + mi*16)*64 + psA);
#pragma unroll
    for (int ni=0;ni<4;ni++) b[ni] = *(const i32x4*)(Bb + (rB + ni*16)*64 + psA);
#pragma unroll
    for (int mi=0;mi<4;mi++)
#pragma unroll
      for (int ni=0;ni<4;ni++)
        asm("v_mfma_i32_16x16x64_i8 %0, %1, %2, %0" : "+v"(acc[mi][ni]) : "v"(a[mi]), "v"(b[ni]));
    asm volatile("s_waitcnt lgkmcnt(0)" ::: "memory");
    __builtin_amdgcn_s_barrier();
    int tmp = cur; cur = nxt; nxt = nx2; nx2 = tmp;
  }
#undef STAGE

#pragma unroll
  for (int mi=0;mi<4;mi++)
#pragma unroll
    for (int ni=0;ni<4;ni++)
      acc[mi][ni] = accfencei(acc[mi][ni]);

  const int rif = (lane>>4)<<2;
  const int cif = lane&15;
  const int gcol0 = bn*128 + (wc<<6);     // head-aligned 64-col span
  const int sec = gcol0 >> 10;            // 0=q, 1=k, 2=v
  const float wsc = wscv[sec] * ((sec==0) ? 0.125f : 1.f);

  if (sec < 2){
    // rope: col d pairs with d+32 -> acc[mi][np] with acc[mi][np+2], np in {0,1}
#pragma unroll
    for (int mi=0;mi<4;mi++){
#pragma unroll
      for (int r=0;r<4;r++){
        const int grow = bm*128 + (wr<<6) + mi*16 + rif + r;
        const float s = rowsc[grow] * wsc;
        const int tpos = grow & 511;
#pragma unroll
        for (int np=0;np<2;np++){
          const int d = np*16 + cif;
          float2 cs = *(const float2*)(tab + (size_t)((tpos<<5) + d)*2);
          float x1 = (float)acc[mi][np][r]   * s;
          float x2 = (float)acc[mi][np+2][r] * s;
          C[(size_t)grow*3072 + gcol0 + d]      = f2bfr(x1*cs.x - x2*cs.y);
          C[(size_t)grow*3072 + gcol0 + 32 + d] = f2bfr(x1*cs.y + x2*cs.x);
        }
      }
    }
  } else {
#pragma unroll
    for (int mi=0;mi<4;mi++){
#pragma unroll
      for (int r=0;r<4;r++){
        const int grow = bm*128 + (wr<<6) + mi*16 + rif + r;
        const float s = rowsc[grow] * wsc;
#pragma unroll
        for (int ni=0;ni<4;ni++)
          C[(size_t)grow*3072 + gcol0 + ni*16 + cif] = f2bfr((float)acc[mi][ni][r] * s);
      }
    }
  }
}

// ---------------- split-K(4) reduce (f32 partials): C = (res?) + (sum P)*rowsc*wsc ----------------
__global__ __launch_bounds__(256) void reduce4_k(const float* __restrict__ P,
                                                 const float* __restrict__ rowsc,
                                                 const float* __restrict__ wsc,
                                                 const float* __restrict__ res,
                                                 float* __restrict__ C){
  int m = blockIdx.x, t = threadIdx.x;
  float s0 = rowsc[m] * wsc[0];
  size_t off = (size_t)m*1024 + t*4;
  float4 a = *(const float4*)(P + off);
  float4 b = *(const float4*)(P + 1048576 + off);
  float4 c = *(const float4*)(P + 2097152 + off);
  float4 d = *(const float4*)(P + 3145728 + off);
  float4 o;
  o.x = (a.x+b.x+c.x+d.x)*s0;
  o.y = (a.y+b.y+c.y+d.y)*s0;
  o.z = (a.z+b.z+c.z+d.z)*s0;
  o.w = (a.w+b.w+c.w+d.w)*s0;
  if (res){
    float4 r = *(const float4*)(res + off);
    o.x += r.x; o.y += r.y; o.z += r.z; o.w += r.w;
  }
  *(float4*)(C + off) = o;
}

// ---------------- fused: split-K(4) bf16-partial reduce + residual + rmsnorm + quant ----------------
__global__ __launch_bounds__(256) void redq_norm_k(const unsigned short* __restrict__ P,
                                                   const float* rowsc,
                                                   const float* __restrict__ wsc,
                                                   const float* __restrict__ res,
                                                   const float* __restrict__ gamma,
                                                   float* __restrict__ Cout,
                                                   signed char* __restrict__ xq,
                                                   float* rs){
  __shared__ float red[4];
  int m = blockIdx.x, t = threadIdx.x;
  float s0 = rowsc[m] * wsc[0];
  size_t off = (size_t)m*1024 + t*4;
  ushort4 a = *(const ushort4*)(P + off);
  ushort4 b = *(const ushort4*)(P + 1048576 + off);
  ushort4 c = *(const ushort4*)(P + 2097152 + off);
  ushort4 d = *(const ushort4*)(P + 3145728 + off);
  float4 r4 = *(const float4*)(res + off);
  float v[4];
  v[0] = r4.x + (bf2f(a.x)+bf2f(b.x)+bf2f(c.x)+bf2f(d.x))*s0;
  v[1] = r4.y + (bf2f(a.y)+bf2f(b.y)+bf2f(c.y)+bf2f(d.y))*s0;
  v[2] = r4.z + (bf2f(a.z)+bf2f(b.z)+bf2f(c.z)+bf2f(d.z))*s0;
  v[3] = r4.w + (bf2f(a.w)+bf2f(b.w)+bf2f(c.w)+bf2f(d.w))*s0;
  float4 of; of.x=v[0]; of.y=v[1]; of.z=v[2]; of.w=v[3];
  *(float4*)(Cout + off) = of;
  float ss = v[0]*v[0]+v[1]*v[1]+v[2]*v[2]+v[3]*v[3];
  ss = bredsum(ss, red);
  float r1 = rsqrtf(ss*(1.f/1024.f) + 1e-6f);
  float y[4];
#pragma unroll
  for (int j=0;j<4;j++) y[j] = v[j]*r1*gamma[t*4+j];
  float am = fmaxf(fmaxf(fabsf(y[0]),fabsf(y[1])),fmaxf(fabsf(y[2]),fabsf(y[3])));
  am = bredmax(am, red);
  float aq = fmaxf(am, 1e-8f), inv = 127.f/aq;
  char4 q;
  q.x = f2i8(fminf(fmaxf(rintf(y[0]*inv),-128.f),127.f));
  q.y = f2i8(fminf(fmaxf(rintf(y[1]*inv),-128.f),127.f));
  q.z = f2i8(fminf(fmaxf(rintf(y[2]*inv),-128.f),127.f));
  q.w = f2i8(fminf(fmaxf(rintf(y[3]*inv),-128.f),127.f));
  *(char4*)(xq + (size_t)m*1024 + t*4) = q;
  if (t==0) rs[m] = aq/127.f;
}

// ---------------- fused tail (bf16 partials): reduce + recurrence + quant + loraDown + topk
//                  + loraUp + act-sigmoid + h_out + ponder (+ next-iter loopnorm) ----------------
__global__ __launch_bounds__(256) void redfin_k(const unsigned short* __restrict__ P,
                                                const float* __restrict__ rowsc,
                                                const float* __restrict__ wsc,
                                                const float* __restrict__ res,
                                                float* __restrict__ h,
                                                const float* __restrict__ Be,
                                                const float* __restrict__ Araw,
                                                const float* __restrict__ alpha, int it,
                                                const signed char* __restrict__ ldq,
                                                const float* __restrict__ sld,
                                                const signed char* __restrict__ luq,
                                                const float* __restrict__ slu,
                                                const signed char* __restrict__ actq,
                                                const float* __restrict__ sact,
                                                const float* __restrict__ ig,
                                                float* __restrict__ hout,
                                                float* __restrict__ ponder,
                                                const float* __restrict__ dnext,
                                                const float* __restrict__ lnw,
                                                const float* __restrict__ n1,
                                                float* __restrict__ hin,
                                                signed char* __restrict__ xqn,
                                                float* __restrict__ rsn,
                                                int doNext){
  __shared__ float red[4];
  __shared__ float xrow[1024];
  __shared__ float part[256];
  __shared__ float xs[32];
  __shared__ float sh_thr, sh_gs;
  int m = blockIdx.x, t = threadIdx.x;
  float al = alpha[it];
  float s0 = rowsc[m] * wsc[0];
  size_t off = (size_t)m*1024 + t*4;
  ushort4 a = *(const ushort4*)(P + off);
  ushort4 b = *(const ushort4*)(P + 1048576 + off);
  ushort4 c = *(const ushort4*)(P + 2097152 + off);
  ushort4 d = *(const ushort4*)(P + 3145728 + off);
  float4 r4 = *(const float4*)(res + off);
  float4 hh = *(const float4*)(h + off);
  float4 be = *(const float4*)(Be + off);
  float4 ar = *(const float4*)(Araw + t*4);
  float v[4];
  v[0] = 0.99f*tanhf(ar.x)*hh.x + be.x + al*(r4.x + (bf2f(a.x)+bf2f(b.x)+bf2f(c.x)+bf2f(d.x))*s0);
  v[1] = 0.99f*tanhf(ar.y)*hh.y + be.y + al*(r4.y + (bf2f(a.y)+bf2f(b.y)+bf2f(c.y)+bf2f(d.y))*s0);
  v[2] = 0.99f*tanhf(ar.z)*hh.z + be.z + al*(r4.z + (bf2f(a.z)+bf2f(b.z)+bf2f(c.z)+bf2f(d.z))*s0);
  v[3] = 0.99f*tanhf(ar.w)*hh.w + be.w + al*(r4.w + (bf2f(a.w)+bf2f(b.w)+bf2f(c.w)+bf2f(d.w))*s0);
  float am = fmaxf(fmaxf(fabsf(v[0]),fabsf(v[1])),fmaxf(fabsf(v[2]),fabsf(v[3])));
  am = bredmax(am, red);
  float aq = fmaxf(am, 1e-8f), inv = 127.f/aq;
#pragma unroll
  for (int j=0;j<4;j++) xrow[t*4+j] = fminf(fmaxf(rintf(v[j]*inv),-128.f),127.f);
  float rsv = aq/127.f;
  __syncthreads();
  {
    int r = t & 31, seg = t >> 5;
    const signed char* wrow = ldq + (size_t)r*1024 + seg*128;
    const float* xr = xrow + seg*128;
    float acc = 0.f;
    for (int k=0;k<128;k+=4){
      char4 w4 = *(const char4*)(wrow + k);
      acc += xr[k]*(float)w4.x + xr[k+1]*(float)w4.y + xr[k+2]*(float)w4.z + xr[k+3]*(float)w4.w;
    }
    part[t] = acc;
  }
  __syncthreads();
  if (t < 32){
    float s = 0.f;
    for (int sg=0; sg<8; sg++) s += part[sg*32 + t];
    xs[t] = s * rsv * (*sld);
  }
  __syncthreads();
  float val = 0.f, av = 0.f, amax = 0.f;
  if (t < 32){
    val = xs[t]; av = fabsf(val);
    int rank = 0;
    for (int j=0;j<32;j++){
      float aj = fabsf(xs[j]);
      amax = fmaxf(amax, aj);
      if (aj > av || (aj == av && j < t)) rank++;
    }
    if (rank == 17) sh_thr = av;
  }
  __syncthreads();
  if (t < 32){
    float a2 = fmaxf(amax, 1e-8f);
    float q = 0.f;
    if (av >= sh_thr) q = fminf(fmaxf(rintf(val*(127.f/a2)), -128.f), 127.f);
    xs[t] = q;
    if (t == 0) sh_gs = ig[it] * (*slu) * (a2/127.f);
  }
  __syncthreads();
  float gs = sh_gs;
  float hn[4];
  int n0 = t*4;
#pragma unroll
  for (int ni=0;ni<4;ni++){
    const signed char* lr = luq + (size_t)(n0+ni)*32;
    float dd = 0.f;
    for (int k=0;k<32;k+=4){
      char4 w4 = *(const char4*)(lr + k);
      dd += xs[k]*(float)w4.x + xs[k+1]*(float)w4.y + xs[k+2]*(float)w4.z + xs[k+3]*(float)w4.w;
    }
    hn[ni] = v[ni] + gs*dd;
  }
  float am2 = fmaxf(fmaxf(fabsf(hn[0]),fabsf(hn[1])),fmaxf(fabsf(hn[2]),fabsf(hn[3])));
  am2 = bredmax(am2, red);
  float a2 = fmaxf(am2, 1e-8f), inv2 = 127.f/a2;
  float zp = 0.f;
#pragma unroll
  for (int ni=0;ni<4;ni++){
    float q = fminf(fmaxf(rintf(hn[ni]*inv2),-128.f),127.f);
    zp += q * (float)actq[n0+ni];
  }
  zp = bredsum(zp, red);
  float z = zp * (a2/127.f) * (*sact);
  float wv = 1.f/(1.f+expf(-z));
#pragma unroll
  for (int ni=0;ni<4;ni++){
    size_t o2 = (size_t)m*1024 + n0+ni;
    float ho = hout[o2];
    hout[o2] = ho + wv*(hn[ni]-ho);
    h[o2] = hn[ni];
  }
  if (t==0) atomicAdd(ponder, wv * (1.f/8192.f));

  // ---- fused next-iteration loopnorm + quant ----
  if (doNext){
    int b2 = m >> 9;
    float v2[4] = {hn[0], hn[1], hn[2], hn[3]};
    if (t < 16){
#pragma unroll
      for (int j=0;j<4;j++) v2[j] += dnext[b2*64 + t*4 + j];
    }
    float ss2 = v2[0]*v2[0]+v2[1]*v2[1]+v2[2]*v2[2]+v2[3]*v2[3];
    ss2 = bredsum(ss2, red);
    float r1 = rsqrtf(ss2*(1.f/1024.f) + 1e-6f);
    float w4[4];
#pragma unroll
    for (int j=0;j<4;j++) w4[j] = v2[j]*r1*lnw[t*4+j];
    float4 of; of.x=w4[0]; of.y=w4[1]; of.z=w4[2]; of.w=w4[3];
    *(float4*)(hin + off) = of;
    float s2 = w4[0]*w4[0]+w4[1]*w4[1]+w4[2]*w4[2]+w4[3]*w4[3];
    s2 = bredsum(s2, red);
    float r2 = rsqrtf(s2*(1.f/1024.f) + 1e-6f);
    float y[4];
#pragma unroll
    for (int j=0;j<4;j++) y[j] = w4[j]*r2*n1[t*4+j];
    float am3 = fmaxf(fmaxf(fabsf(y[0]),fabsf(y[1])),fmaxf(fabsf(y[2]),fabsf(y[3])));
    am3 = bredmax(am3, red);
    float aq3 = fmaxf(am3, 1e-8f), inv3 = 127.f/aq3;
    char4 q;
    q.x = f2i8(fminf(fmaxf(rintf(y[0]*inv3),-128.f),127.f));
    q.y = f2i8(fminf(fmaxf(rintf(y[1]*inv3),-128.f),127.f));
    q.z = f2i8(fminf(fmaxf(rintf(y[2]*inv3),-128.f),127.f));
    q.w = f2i8(fminf(fmaxf(rintf(y[3]*inv3),-128.f),127.f));
    *(char4*)(xqn + off) = q;
    if (t==0) rsn[m] = aq3/127.f;
  }
}

// ---------------- MFMA flash attention, split-k over 2 blocks; bf16 partial out ----------------
DEV int swz64(int r, int c){ return r*64 + (c ^ ((r&7)<<3)); }

__global__ __launch_bounds__(256) void attn_split_k(const unsigned short* __restrict__ qkv,
                                                    unsigned short* __restrict__ Opart,
                                                    float* __restrict__ ml){
  __shared__ __align__(16) unsigned short Qs[4096];
  __shared__ __align__(16) unsigned short Ks[4096];
  __shared__ __align__(16) unsigned short Vt[4096];   // [d][k], swizzled on d
  __shared__ __align__(16) unsigned short Ps[4][1024];
  const int tid = threadIdx.x;
  const int lane = tid & 63, wv = tid >> 6;
  const int bidl = blockIdx.x & 255;
  const int z = blockIdx.x >> 8;          // 0..1
  const int qt = bidl & 7, bh = bidl >> 3;
  const int b = bh >> 4, h = bh & 15;
  const int tokb = b*512;
  const int l15 = lane & 15, lh = lane >> 4;

  { // stage Q (already scaled by 1/8)
    int r = tid >> 2, c0 = (tid & 3) << 4;
    const unsigned short* s = qkv + (size_t)(tokb + qt*64 + r)*3072 + h*64 + c0;
    u16x8 f0 = *(const u16x8*)s, f1 = *(const u16x8*)(s+8);
    *(u16x8*)(Qs + swz64(r, c0))   = f0;
    *(u16x8*)(Qs + swz64(r, c0+8)) = f1;
  }

  float m_run[4] = {-1e30f,-1e30f,-1e30f,-1e30f};
  float l_run[4] = {0.f,0.f,0.f,0.f};
  f32x4 accO[4] = {};

  const int nt = qt + 1;
  const int half = (nt + 1) >> 1;
  const int kA = z ? half : 0;
  const int kB = z ? nt : half;

  for (int kt = kA; kt < kB; ++kt){
    __syncthreads();
    { // stage K
      int r = tid >> 2, c0 = (tid & 3) << 4;
      const unsigned short* s = qkv + (size_t)(tokb + kt*64 + r)*3072 + 1024 + h*64 + c0;
      u16x8 f0 = *(const u16x8*)s, f1 = *(const u16x8*)(s+8);
      *(u16x8*)(Ks + swz64(r, c0))   = f0;
      *(u16x8*)(Ks + swz64(r, c0+8)) = f1;
    }
    { // stage V transposed
      int r0 = (tid >> 3) << 1, cv = (tid & 7) << 3;
      const unsigned short* s0 = qkv + (size_t)(tokb + kt*64 + r0)*3072 + 2048 + h*64 + cv;
      u16x8 a = *(const u16x8*)s0;
      u16x8 b2 = *(const u16x8*)(s0 + 3072);
#pragma unroll
      for (int j=0;j<8;j++){
        int d = cv + j;
        unsigned int pk = (unsigned int)a[j] | ((unsigned int)b2[j]<<16);
        *(unsigned int*)(Vt + swz64(d, r0)) = pk;
      }
    }
    __syncthreads();

    f32x4 s4[4] = {};
#pragma unroll
    for (int kc=0; kc<2; ++kc){
      i32x4 aq = *(const i32x4*)(Qs + swz64(wv*16 + l15, kc*32 + lh*8));
#pragma unroll
      for (int nt2=0; nt2<4; ++nt2){
        i32x4 bk = *(const i32x4*)(Ks + swz64(nt2*16 + l15, kc*32 + lh*8));
        asm("v_mfma_f32_16x16x32_bf16 %0, %1, %2, %0" : "+v"(s4[nt2]) : "v"(aq), "v"(bk));
      }
    }
#pragma unroll
    for (int nt2=0; nt2<4; ++nt2) s4[nt2] = accfence(s4[nt2]);

    const bool diag = (kt == qt);
    float sf[4];
#pragma unroll
    for (int r=0;r<4;r++){
      int rl = lh*4 + r;
      float mx = -1e30f;
#pragma unroll
      for (int nt2=0; nt2<4; ++nt2){
        float v = s4[nt2][r];
        if (diag && (nt2*16 + l15) > (wv*16 + rl)) v = -1e30f;
        s4[nt2][r] = v;
        mx = fmaxf(mx, v);
      }
      mx = fmaxf(mx, __shfl_xor(mx,1));
      mx = fmaxf(mx, __shfl_xor(mx,2));
      mx = fmaxf(mx, __shfl_xor(mx,4));
      mx = fmaxf(mx, __shfl_xor(mx,8));
      float mn = fmaxf(m_run[r], mx);
      sf[r] = __expf(m_run[r] - mn);
      m_run[r] = mn;
      float ps = 0.f;
#pragma unroll
      for (int nt2=0; nt2<4; ++nt2){
        float p = __expf(s4[nt2][r] - mn);
        ps += p;
        Ps[wv][swz64(rl, nt2*16 + l15)] = f2bfr(p);
      }
      ps += __shfl_xor(ps,1); ps += __shfl_xor(ps,2);
      ps += __shfl_xor(ps,4); ps += __shfl_xor(ps,8);
      l_run[r] = l_run[r]*sf[r] + ps;
    }
#pragma unroll
    for (int dt=0; dt<4; ++dt){
#pragma unroll
      for (int r=0;r<4;r++) accO[dt][r] *= sf[r];
      accO[dt] = accfence(accO[dt]);
    }
#pragma unroll
    for (int kc=0; kc<2; ++kc){
      i32x4 pa = *(const i32x4*)(Ps[wv] + swz64(l15, kc*32 + lh*8));
#pragma unroll
      for (int dt=0; dt<4; ++dt){
        i32x4 vb3 = *(const i32x4*)(Vt + swz64(dt*16 + l15, kc*32 + lh*8));
        asm("v_mfma_f32_16x16x32_bf16 %0, %1, %2, %0" : "+v"(accO[dt]) : "v"(pa), "v"(vb3));
      }
    }
  }
#pragma unroll
  for (int dt=0; dt<4; ++dt) accO[dt] = accfence(accO[dt]);
  unsigned short* Op = Opart + ((size_t)z << 20);
#pragma unroll
  for (int r=0;r<4;r++){
    int row = tokb + qt*64 + wv*16 + lh*4 + r;
    unsigned short* op = Op + (size_t)row*1024 + h*64 + l15;
#pragma unroll
    for (int dt=0; dt<4; ++dt)
      op[dt*16] = f2bfr(accO[dt][r]);
    if (l15 == 0){
      float2 v2 = make_float2(m_run[r], l_run[r]);
      *(float2*)(ml + ((size_t)(z*16 + h)*1024 + row)*2) = v2;
    }
  }
}

// ---------------- merge two attn partials (bf16) + row quant -> i8 ----------------
__global__ __launch_bounds__(256) void attn_merge_quant_k(const unsigned short* __restrict__ Opart,
                                                          const float* __restrict__ ml,
                                                          signed char* __restrict__ xq,
                                                          float* __restrict__ rs){
  __shared__ float red[4];
  int m = blockIdx.x, t = threadIdx.x;
  int head = t >> 4;                       // 4 cols per thread, 4-aligned -> single head
  float2 ml0 = *(const float2*)(ml + ((size_t)head*1024 + m)*2);
  float2 ml1 = *(const float2*)(ml + ((size_t)(16 + head)*1024 + m)*2);
  float mm = fmaxf(ml0.x, ml1.x);
  float w0 = __expf(ml0.x - mm), w1 = __expf(ml1.x - mm);
  float invl = 1.f / (ml0.y*w0 + ml1.y*w1);
  size_t off = (size_t)m*1024 + t*4;
  ushort4 u0 = *(const ushort4*)(Opart + off);
  ushort4 u1 = *(const ushort4*)(Opart + 1048576 + off);
  float v[4];
  v[0] = (bf2f(u0.x)*w0 + bf2f(u1.x)*w1)*invl;
  v[1] = (bf2f(u0.y)*w0 + bf2f(u1.y)*w1)*invl;
  v[2] = (bf2f(u0.z)*w0 + bf2f(u1.z)*w1)*invl;
  v[3] = (bf2f(u0.w)*w0 + bf2f(u1.w)*w1)*invl;
  float am = fmaxf(fmaxf(fabsf(v[0]),fabsf(v[1])),fmaxf(fabsf(v[2]),fabsf(v[3])));
  am = bredmax(am, red);
  float a = fmaxf(am, 1e-8f), inv = 127.f/a;
  char4 q;
  q.x = f2i8(fminf(fmaxf(rintf(v[0]*inv),-128.f),127.f));
  q.y = f2i8(fminf(fmaxf(rintf(v[1]*inv),-128.f),127.f));
  q.z = f2i8(fminf(fmaxf(rintf(v[2]*inv),-128.f),127.f));
  q.w = f2i8(fminf(fmaxf(rintf(v[3]*inv),-128.f),127.f));
  *(char4*)(xq + (size_t)m*1024 + t*4) = q;
  if (t==0) rs[m] = a/127.f;
}

// ================= host =================
extern "C" void kernel_launch(void* const* d_in, const int* in_sizes, int n_in,
                              void* d_out, int out_size, void* d_ws, size_t ws_size,
                              hipStream_t stream)
{
  (void)in_sizes; (void)n_in;
  const float* x     = (const float*)d_in[0];
  const float* e     = (const float*)d_in[1];
  const float* temb  = (const float*)d_in[2];
  const float* bn1   = (const float*)d_in[3];
  const float* bwq   = (const float*)d_in[4];
  const float* bwk   = (const float*)d_in[5];
  const float* bwv   = (const float*)d_in[6];
  const float* bwo   = (const float*)d_in[7];
  const float* bn2   = (const float*)d_in[8];
  const float* bwg   = (const float*)d_in[9];
  const float* bwu   = (const float*)d_in[10];
  const float* bwd   = (const float*)d_in[11];
  const float* Araw  = (const float*)d_in[12];
  const float* Bw    = (const float*)d_in[13];
  const float* ldw   = (const float*)d_in[14];
  const float* luw   = (const float*)d_in[15];
  const float* ig    = (const float*)d_in[16];
  const float* actw  = (const float*)d_in[17];
  const float* alph  = (const float*)d_in[18];
  const float* lpw   = (const float*)d_in[19];
  const float* lp2w  = (const float*)d_in[20];
  const float* lp2b  = (const float*)d_in[21];
  const float* lnw   = (const float*)d_in[22];

  char* ws = (char*)d_ws;
  float* out = (float*)d_out;
  const size_t WS_NEEDED = 94600704ull;
  if (ws_size < WS_NEEDED){
    fill_k<<<(out_size+255)/256,256,0,stream>>>(out, out_size, 1.0e9f);
    return;
  }

  signed char* qw_qkv = (signed char*)(ws + 0);          // 6 MB
  signed char* qw_wo  = (signed char*)(ws + 6291456);    // 2 MB
  signed char* qw_gu  = (signed char*)(ws + 8388608);    // 16 MB (g/u row-interleaved)
  signed char* qw_wd  = (signed char*)(ws + 25165824);   // 8 MB
  signed char* qw_bw  = (signed char*)(ws + 33554432);   // 1 MB
  signed char* qw_ld  = (signed char*)(ws + 34603008);
  signed char* qw_lu  = (signed char*)(ws + 34635776);
  signed char* qw_act = (signed char*)(ws + 34668544);
  float* scales = (float*)(ws + 34669568);
  float* delta  = (float*)(ws + 34688512);
  float* hbuf   = (float*)(ws + 34692608);
  float* Bebuf  = (float*)(ws + 38886912);
  float* bufX   = (float*)(ws + 43081216);
  float* bufY   = (float*)(ws + 47275520);
  float* gub    = (float*)(ws + 51469824);               // scratch: partials / attn Opart / silu out
  unsigned short* qkv_bf = (unsigned short*)(ws + 76635648);  // 6 MB bf16 qkv
  float* mlbuf  = (float*)(ws + 85024256);               // 256 KB attn m/l partials
  signed char* xq1k = (signed char*)(ws + 89218560);
  float* rs1k   = (float*)(ws + 90267136);
  signed char* xqm  = (signed char*)(ws + 90271232);
  float* rsm    = (float*)(ws + 94465536);
  float* ropetab= (float*)(ws + 94469632);               // 128 KB
  float* part   = gub;                                   // absmean partials (setup only)

  // ---- setup: scales + ternary weights ----
  WSetup wsu;
  wsu.src[0]=Bw;
  wsu.src[1]=bwq; wsu.src[2]=bwq+1048576;
  wsu.src[3]=bwk; wsu.src[4]=bwk+1048576;
  wsu.src[5]=bwv; wsu.src[6]=bwv+1048576;
  wsu.src[7]=bwo; wsu.src[8]=bwo+1048576;
  wsu.src[9]=bwg; wsu.src[10]=bwg+4194304;
  wsu.src[11]=bwu; wsu.src[12]=bwu+4194304;
  wsu.src[13]=bwd; wsu.src[14]=bwd+4194304;
  wsu.src[15]=ldw; wsu.src[16]=luw; wsu.src[17]=actw;
  wsu.dst[0]=qw_bw;
  wsu.dst[1]=qw_qkv;             wsu.dst[2]=qw_qkv+3145728;
  wsu.dst[3]=qw_qkv+1048576;     wsu.dst[4]=qw_qkv+3145728+1048576;
  wsu.dst[5]=qw_qkv+2097152;     wsu.dst[6]=qw_qkv+3145728+2097152;
  wsu.dst[7]=qw_wo;              wsu.dst[8]=qw_wo+1048576;
  wsu.dst[9]=qw_gu;              wsu.dst[10]=qw_gu+8388608;
  wsu.dst[11]=qw_gu;             wsu.dst[12]=qw_gu+8388608;
  wsu.dst[13]=qw_wd;             wsu.dst[14]=qw_wd+4194304;
  wsu.dst[15]=qw_ld; wsu.dst[16]=qw_lu; wsu.dst[17]=qw_act;
  for (int i=0;i<18;i++) wsu.mode[i]=0;
  wsu.mode[9]=1;  wsu.mode[10]=1;   // wg -> even rows
  wsu.mode[11]=2; wsu.mode[12]=2;   // wu -> odd rows

  absmean_all_k<<<2117,256,0,stream>>>(wsu, part);
  finalize_scales_k<<<1,256,0,stream>>>(part, scales);
  quantw_all_k<<<2117,256,0,stream>>>(wsu, scales);

  // ---- misc setup (copy_init + delta + ropetab merged) ----
  setup_misc_k<<<1216,256,0,stream>>>(x, hbuf, out, temb, lpw, lp2w, lp2b, delta, ropetab);

  // Be = bitlinear(e, B_w)  (splitK x4, f32 partials — setup only)
  rowquant1k_k<false><<<1024,256,0,stream>>>(e, xq1k, rs1k);
  { dim3 g(8,8,4); gemm_i8<true,false,false><<<g,256,0,stream>>>(xq1k, qw_bw, nullptr, nullptr, nullptr, gub, 1024, 1024, 256); }
  reduce4_k<<<1024,256,0,stream>>>(gub, rs1k, scales+0, nullptr, Bebuf);

  // ---- main recurrent loop (n_loops = 8) ----
  for (int it=0; it<8; ++it){
    if (it==0)
      loopnorm_quant_k<<<1024,256,0,stream>>>(hbuf, delta, lnw, bn1, bufX, xq1k, rs1k);
    for (int l=0;l<2;l++){
      // qkv: 128x128 GEMM + fused scale/rope epilogue -> bf16 qkvb
      { dim3 g(24,8); gemm_qkv128<<<g,256,0,stream>>>(xq1k, qw_qkv + (size_t)l*3145728, rs1k, scales+18+l*3, ropetab, qkv_bf); }
      // attention split over 2 k-halves (512 blocks) + merge/quant; bf16 partials
      attn_split_k<<<512,256,0,stream>>>(qkv_bf, (unsigned short*)gub, mlbuf);
      attn_merge_quant_k<<<1024,256,0,stream>>>((const unsigned short*)gub, mlbuf, xq1k, rs1k);
      // wo (splitK x4, bf16 partials) + fused reduce+residual+rmsnorm(bn2)+quant
      { dim3 g(8,8,4); gemm_i8<true,false,true><<<g,256,0,stream>>>(xq1k, qw_wo + (size_t)l*1048576, nullptr, nullptr, nullptr, gub, 1024, 1024, 256); }
      redq_norm_k<<<1024,256,0,stream>>>((const unsigned short*)gub, rs1k, scales+7+l, bufX, bn2 + (size_t)l*1024, bufY, xq1k, rs1k);
      // gu with fused silu epilogue -> bf16 [1024][4096]
      { dim3 g(64,8); gemm_i8<false,true,false><<<g,256,0,stream>>>(xq1k, qw_gu + (size_t)l*8388608, rs1k, scales+24+l*2, nullptr, gub, 8192, 1024, 1024); }
      rowquant4k_k<<<1024,256,0,stream>>>((const unsigned short*)gub, xqm, rsm);
      // wd (splitK x4, bf16 partials)
      { dim3 g(8,8,4); gemm_i8<true,false,true><<<g,256,0,stream>>>(xqm, qw_wd + (size_t)l*4194304, nullptr, nullptr, nullptr, gub, 1024, 4096, 1024); }
      if (l==0){
        redq_norm_k<<<1024,256,0,stream>>>((const unsigned short*)gub, rsm, scales+13, bufY, bn1 + 1024, bufX, xq1k, rs1k);
      } else {
        redfin_k<<<1024,256,0,stream>>>((const unsigned short*)gub, rsm, scales+14, bufY, hbuf, Bebuf, Araw, alph, it,
                                        qw_ld, scales+15, qw_lu, scales+16, qw_act, scales+17,
                                        ig, out, out + 1048576,
                                        delta + (it+1 < 8 ? (it+1)*128 : 0), lnw, bn1, bufX, xq1k, rs1k,
                                        (it < 7) ? 1 : 0);
      }
    }
  }
}

// Round 17
// 1766.942 us; speedup vs baseline: 1.0727x; 1.0086x over previous
//
#include <hip/hip_runtime.h>
#include <stdint.h>

#define DEV static __device__ __forceinline__

typedef float f32x4 __attribute__((ext_vector_type(4)));
typedef int   i32x4 __attribute__((ext_vector_type(4)));
typedef unsigned short u16x8 __attribute__((ext_vector_type(8)));

DEV float bf2f(unsigned short u){ return __uint_as_float(((unsigned int)u)<<16); }
DEV unsigned short f2bfr(float f){ // round-to-nearest-even bf16
  unsigned int u = __float_as_uint(f);
  return (unsigned short)((u + 0x7FFF + ((u>>16)&1)) >> 16);
}
DEV signed char f2i8(float f){ return (signed char)(int)f; } // f already rint+clamped

// ---------------- block reductions (256-thread blocks, 4 waves) ----------------
DEV float wredsum(float v){
#pragma unroll
  for (int o=32;o;o>>=1) v += __shfl_xor(v,o);
  return v;
}
DEV float wredmax(float v){
#pragma unroll
  for (int o=32;o;o>>=1) v = fmaxf(v,__shfl_xor(v,o));
  return v;
}
DEV float bredsum(float v, float* red){
  v = wredsum(v);
  if ((threadIdx.x&63)==0) red[threadIdx.x>>6] = v;
  __syncthreads();
  float r = red[0]+red[1]+red[2]+red[3];
  __syncthreads();
  return r;
}
DEV float bredmax(float v, float* red){
  v = wredmax(v);
  if ((threadIdx.x&63)==0) red[threadIdx.x>>6] = v;
  __syncthreads();
  float r = fmaxf(fmaxf(red[0],red[1]),fmaxf(red[2],red[3]));
  __syncthreads();
  return r;
}

// ---------------- misc ----------------
__global__ void fill_k(float* p, int n, float v){
  int i = blockIdx.x*256 + threadIdx.x;
  if (i < n) p[i] = v;
}

// merged setup: copy_init (1024 blocks) + delta (128) + ropetab (64)
__global__ __launch_bounds__(256) void setup_misc_k(const float* __restrict__ x,
                                                    float* __restrict__ h, float* __restrict__ ho,
                                                    const float* __restrict__ temb,
                                                    const float* __restrict__ lpw,
                                                    const float* __restrict__ lp2w,
                                                    const float* __restrict__ lp2b,
                                                    float* __restrict__ delta,
                                                    float* __restrict__ tab){
  __shared__ float red[4];
  int bid = blockIdx.x, t = threadIdx.x;
  if (bid < 1024){
    int i = bid*256 + t;
    float4 v = *(const float4*)(x + (size_t)i*4);
    *(float4*)(h  + (size_t)i*4) = v;
    *(float4*)(ho + (size_t)i*4) = v;
    if (i==0) ho[1048576] = 0.f;
  } else if (bid < 1152){
    int blk = bid - 1024;
    int b = blk >> 6, j = blk & 63;
    float te = temb[b*256 + t];
    float p1 = bredsum(te * lpw[j*256 + t], red);
    float p2 = bredsum(te * lp2w[j*256 + t], red);
    if (t < 8){
      int i = t;
      float frac = (float)i / 7.f;
      int jj = j & 31;
      float fr = expf(-logf(10000.f) * (float)jj * (1.f/32.f));
      float ang = frac * fr;
      float sig = (j < 32) ? sinf(ang) : cosf(ang);
      delta[i*128 + b*64 + j] = sig*p1 + p2 + lp2b[j];
    }
  } else {
    int i = (bid-1152)*256 + t;   // 16384
    int tpos = i >> 5, d = i & 31;
    float inv = powf(10000.f, -(float)d * (1.f/32.f));
    float sv, cv; sincosf((float)tpos * inv, &sv, &cv);
    tab[i*2]   = cv;
    tab[i*2+1] = sv;
  }
}

// ---------------- fused setup: 18 weight matrices ----------------
struct WSetup {
  const float* src[18];
  signed char* dst[18];
  int mode[18];     // 0 normal; 1 row-interleave even; 2 row-interleave odd
};
DEV long n4of(int mat){ return mat<9 ? 262144 : (mat<15 ? 1048576 : (mat<17 ? 8192 : 256)); }

// block -> (mat, seg of 4096 float4 = 64 KB). grid 2117.
DEV void setup_map(int bid, int& mat, int& seg){
  if (bid < 576){ mat = bid >> 6; seg = bid & 63; }
  else if (bid < 2112){ mat = 9 + ((bid-576) >> 8); seg = (bid-576) & 255; }
  else if (bid < 2116){ mat = 15 + ((bid-2112) >> 1); seg = (bid-2112) & 1; }
  else { mat = 17; seg = 0; }
}

__global__ __launch_bounds__(256) void absmean_all_k(WSetup wsu, float* __restrict__ part){
  __shared__ float red[4];
  int mat, seg;
  setup_map(blockIdx.x, mat, seg);
  long n4 = n4of(mat);
  long base = (long)seg*4096;
  long chunk = (n4 - base < 4096) ? (n4 - base) : 4096;
  const float4* p = (const float4*)wsu.src[mat] + base;
  float s0=0.f, s1=0.f, s2=0.f, s3=0.f;
  if (chunk == 4096){
    const long quar = 1024;
    const float4* p1 = p + quar;
    const float4* p2 = p + 2*quar;
    const float4* p3 = p + 3*quar;
#pragma unroll
    for (int jj=0;jj<4;jj++){
      long j = threadIdx.x + jj*256;
      float4 a = p[j], b = p1[j], c = p2[j], d = p3[j];
      s0 += fabsf(a.x)+fabsf(a.y)+fabsf(a.z)+fabsf(a.w);
      s1 += fabsf(b.x)+fabsf(b.y)+fabsf(b.z)+fabsf(b.w);
      s2 += fabsf(c.x)+fabsf(c.y)+fabsf(c.z)+fabsf(c.w);
      s3 += fabsf(d.x)+fabsf(d.y)+fabsf(d.z)+fabsf(d.w);
    }
  } else {
    for (long j = threadIdx.x; j < chunk; j += 256){
      float4 a = p[j];
      s0 += fabsf(a.x)+fabsf(a.y)+fabsf(a.z)+fabsf(a.w);
    }
  }
  float s = bredsum(s0+s1+s2+s3, red);
  if (threadIdx.x==0) part[(long)mat*1024 + seg] = s;
}

__global__ __launch_bounds__(256) void finalize_scales_k(const float* __restrict__ part,
                                                         float* __restrict__ scales){
  __shared__ float red[4];
  const long numel[18] = {1048576, 1048576,1048576, 1048576,1048576, 1048576,1048576,
                          1048576,1048576, 4194304,4194304, 4194304,4194304, 4194304,4194304,
                          32768, 32768, 1024};
  int t = threadIdx.x;
  for (int m=0;m<18;m++){
    int segs = (m < 9) ? 64 : (m < 15 ? 256 : (m < 17 ? 2 : 1));
    float v = 0.f;
    for (int j=t; j<segs; j+=256) v += part[(long)m*1024 + j];
    v = bredsum(v, red);
    if (t==0) scales[m] = v/(float)numel[m] + 1e-8f;
  }
  if (t==0){
    for (int l=0;l<2;l++){
      scales[18+l*3+0] = scales[1+l];   // wq
      scales[18+l*3+1] = scales[3+l];   // wk
      scales[18+l*3+2] = scales[5+l];   // wv
      scales[24+l*2+0] = scales[9+l];   // wg
      scales[24+l*2+1] = scales[11+l];  // wu
    }
  }
}

__global__ __launch_bounds__(256) void quantw_all_k(WSetup wsu, const float* __restrict__ scales){
  int mat, seg;
  setup_map(blockIdx.x, mat, seg);
  long n4 = n4of(mat);
  float s = scales[mat];
  int md = wsu.mode[mat];
  const float4* src = (const float4*)wsu.src[mat];
  char4* dst = (char4*)wsu.dst[mat];
  long base = (long)seg*4096;
  long end = (base + 4096 < n4) ? (base + 4096) : n4;
#pragma unroll 4
  for (long i = base + threadIdx.x; i < end; i += 256){
    float4 v = src[i];
    char4 q;
    q.x = f2i8(fminf(fmaxf(rintf(v.x/s), -1.f), 1.f));
    q.y = f2i8(fminf(fmaxf(rintf(v.y/s), -1.f), 1.f));
    q.z = f2i8(fminf(fmaxf(rintf(v.z/s), -1.f), 1.f));
    q.w = f2i8(fminf(fmaxf(rintf(v.w/s), -1.f), 1.f));
    if (md == 0) dst[i] = q;
    else {
      long r = i >> 8, cc = i & 255;    // K=1024 -> 256 char4/row
      dst[(((r<<1) | (md-1))<<8) | cc] = q;
    }
  }
}

// ---------------- row quant (1024 wide) -> i8; input f32 or bf16 ----------------
template<bool BF>
__global__ __launch_bounds__(256) void rowquant1k_k(const void* __restrict__ xin,
                                                    signed char* __restrict__ xq,
                                                    float* __restrict__ rs){
  __shared__ float red[4];
  int m = blockIdx.x, t = threadIdx.x;
  float v[4];
  if (BF){
    ushort4 u = *(const ushort4*)((const unsigned short*)xin + (size_t)m*1024 + t*4);
    v[0]=bf2f(u.x); v[1]=bf2f(u.y); v[2]=bf2f(u.z); v[3]=bf2f(u.w);
  } else {
    float4 f = *(const float4*)((const float*)xin + (size_t)m*1024 + t*4);
    v[0]=f.x; v[1]=f.y; v[2]=f.z; v[3]=f.w;
  }
  float am = fmaxf(fmaxf(fabsf(v[0]),fabsf(v[1])),fmaxf(fabsf(v[2]),fabsf(v[3])));
  am = bredmax(am, red);
  float a = fmaxf(am, 1e-8f), inv = 127.f/a;
  char4 q;
  q.x = f2i8(fminf(fmaxf(rintf(v[0]*inv),-128.f),127.f));
  q.y = f2i8(fminf(fmaxf(rintf(v[1]*inv),-128.f),127.f));
  q.z = f2i8(fminf(fmaxf(rintf(v[2]*inv),-128.f),127.f));
  q.w = f2i8(fminf(fmaxf(rintf(v[3]*inv),-128.f),127.f));
  *(char4*)(xq + (size_t)m*1024 + t*4) = q;
  if (t==0) rs[m] = a/127.f;
}

// ---------------- row quant (4096 wide, bf16 input) -> i8 ----------------
__global__ __launch_bounds__(256) void rowquant4k_k(const unsigned short* __restrict__ x,
                                                    signed char* __restrict__ xq,
                                                    float* __restrict__ rs){
  __shared__ float red[4];
  int m = blockIdx.x, t = threadIdx.x;
  const unsigned short* p = x + (size_t)m*4096 + t*16;
  u16x8 u0 = *(const u16x8*)p;
  u16x8 u1 = *(const u16x8*)(p + 8);
  float v[16];
#pragma unroll
  for (int j=0;j<8;j++){ v[j] = bf2f(u0[j]); v[j+8] = bf2f(u1[j]); }
  float am = 0.f;
#pragma unroll
  for (int j=0;j<16;j++) am = fmaxf(am, fabsf(v[j]));
  am = bredmax(am, red);
  float a = fmaxf(am, 1e-8f), inv = 127.f/a;
#pragma unroll
  for (int j=0;j<16;j+=4){
    char4 q;
    q.x = f2i8(fminf(fmaxf(rintf(v[j+0]*inv),-128.f),127.f));
    q.y = f2i8(fminf(fmaxf(rintf(v[j+1]*inv),-128.f),127.f));
    q.z = f2i8(fminf(fmaxf(rintf(v[j+2]*inv),-128.f),127.f));
    q.w = f2i8(fminf(fmaxf(rintf(v[j+3]*inv),-128.f),127.f));
    *(char4*)(xq + (size_t)m*4096 + t*16 + j) = q;
  }
  if (t==0) rs[m] = a/127.f;
}

// ---------------- fused: h_in = rmsnorm(h+delta, lnw) -> bf16; a_in quant with n1 ----------------
__global__ __launch_bounds__(256) void loopnorm_quant_k(const float* __restrict__ h,
                                                        const float* __restrict__ delta,
                                                        const float* __restrict__ lnw,
                                                        const float* __restrict__ n1,
                                                        unsigned short* __restrict__ hin,
                                                        signed char* __restrict__ xq,
                                                        float* __restrict__ rs){
  __shared__ float red[4];
  int m = blockIdx.x, t = threadIdx.x;
  int b = m >> 9;
  float v[4];
  float4 f = *(const float4*)(h + (size_t)m*1024 + t*4);
  v[0]=f.x; v[1]=f.y; v[2]=f.z; v[3]=f.w;
  if (t < 16){
#pragma unroll
    for (int j=0;j<4;j++) v[j] += delta[b*64 + t*4 + j];
  }
  float ss = v[0]*v[0]+v[1]*v[1]+v[2]*v[2]+v[3]*v[3];
  ss = bredsum(ss, red);
  float r1 = rsqrtf(ss*(1.f/1024.f) + 1e-6f);
  float w4[4];
#pragma unroll
  for (int j=0;j<4;j++) w4[j] = v[j]*r1*lnw[t*4+j];
  ushort4 ob;
  ob.x = f2bfr(w4[0]); ob.y = f2bfr(w4[1]); ob.z = f2bfr(w4[2]); ob.w = f2bfr(w4[3]);
  *(ushort4*)(hin + (size_t)m*1024 + t*4) = ob;
  float s2 = w4[0]*w4[0]+w4[1]*w4[1]+w4[2]*w4[2]+w4[3]*w4[3];
  s2 = bredsum(s2, red);
  float r2 = rsqrtf(s2*(1.f/1024.f) + 1e-6f);
  float y[4];
#pragma unroll
  for (int j=0;j<4;j++) y[j] = w4[j]*r2*n1[t*4+j];
  float am = fmaxf(fmaxf(fabsf(y[0]),fabsf(y[1])),fmaxf(fabsf(y[2]),fabsf(y[3])));
  am = bredmax(am, red);
  float a = fmaxf(am, 1e-8f), inv = 127.f/a;
  char4 q;
  q.x = f2i8(fminf(fmaxf(rintf(y[0]*inv),-128.f),127.f));
  q.y = f2i8(fminf(fmaxf(rintf(y[1]*inv),-128.f),127.f));
  q.z = f2i8(fminf(fmaxf(rintf(y[2]*inv),-128.f),127.f));
  q.w = f2i8(fminf(fmaxf(rintf(y[3]*inv),-128.f),127.f));
  *(char4*)(xq + (size_t)m*1024 + t*4) = q;
  if (t==0) rs[m] = a/127.f;
}

// ---------------- i8 MFMA GEMM (triple-buffered, 2-deep prefetch, swizzled) ----------------
DEV f32x4 accfence(f32x4 c){ asm volatile("s_nop 7\n\ts_nop 7" : "+v"(c)); return c; }
DEV i32x4 accfencei(i32x4 c){ asm volatile("s_nop 7\n\ts_nop 7" : "+v"(c)); return c; }

template<bool SPLITK, bool GUSILU, bool PB16>
__global__ __launch_bounds__(256)
void gemm_i8(const signed char* __restrict__ A, const signed char* __restrict__ W,
             const float* __restrict__ rowsc, const float* __restrict__ wscv,
             const float* __restrict__ res, float* __restrict__ C, int N, int Kf, int Kc)
{
  __shared__ __align__(16) signed char As[3][8192];
  __shared__ __align__(16) signed char Bs[3][8192];
  const int tid = threadIdx.x;
  const int lane = tid & 63, wvid = tid >> 6;
  const int wr = wvid >> 1, wc = wvid & 1;
  const int bm = blockIdx.y, bn = blockIdx.x;

  const int r0 = (wvid<<4) + (lane>>2);
  const int sw = (((lane&3) ^ ((r0>>1)&3)) << 4);        // byte offset of 16B chunk
  const long kstart = SPLITK ? (long)blockIdx.z * Kc : 0;
  const signed char* gA = A + (size_t)(bm*128 + r0)*Kf + kstart + sw;
  const signed char* gB = W + (size_t)(bn*128 + r0)*Kf + kstart + sw;
  const size_t row64 = (size_t)64*Kf;

#define STAGE(buf, koff) do { \
    __builtin_amdgcn_global_load_lds(gA + (koff),         &As[buf][(wvid<<10)],      16, 0, 0); \
    __builtin_amdgcn_global_load_lds(gA + (koff) + row64, &As[buf][(wvid<<10)+4096], 16, 0, 0); \
    __builtin_amdgcn_global_load_lds(gB + (koff),         &Bs[buf][(wvid<<10)],      16, 0, 0); \
    __builtin_amdgcn_global_load_lds(gB + (koff) + row64, &Bs[buf][(wvid<<10)+4096], 16, 0, 0); \
  } while(0)

  i32x4 acc[4][4] = {};
  const int rA = (wr<<6) + (lane&15);
  const int rB = (wc<<6) + (lane&15);
  const int psA = (((lane>>4) ^ (((lane&15)>>1)&3)) << 4);  // byte offset

  const int NT = Kc >> 6;   // >= 4 for all our shapes
  STAGE(0, 0);
  STAGE(1, 64);
  int cur = 0, nxt = 1, nx2 = 2;
  for (int kt = 0; kt < NT; ++kt){
    const int k2 = kt + 2;
    const int kn = (k2 < NT) ? (k2<<6) : 0;     // wrap: dead-buffer reload, keeps vmcnt count exact
    STAGE(nx2, kn);
    asm volatile("s_waitcnt vmcnt(8)" ::: "memory");   // tile kt's 4 DMAs done; 8 stay in flight
    __builtin_amdgcn_s_barrier();
    asm volatile("" ::: "memory");
    i32x4 a[4], b[4];
    const signed char* Ab = As[cur];
    const signed char* Bb = Bs[cur];
#pragma unroll
    for (int mi=0;mi<4;mi++) a[mi] = *(const i32x4*)(Ab + (rA + mi*16)*64 + psA);
#pragma unroll
    for (int ni=0;ni<4;ni++) b[ni] = *(const i32x4*)(Bb + (rB + ni*16)*64 + psA);
#pragma unroll
    for (int mi=0;mi<4;mi++)
#pragma unroll
      for (int ni=0;ni<4;ni++)
        asm("v_mfma_i32_16x16x64_i8 %0, %1, %2, %0" : "+v"(acc[mi][ni]) : "v"(a[mi]), "v"(b[ni]));
    asm volatile("s_waitcnt lgkmcnt(0)" ::: "memory");
    __builtin_amdgcn_s_barrier();
    int tmp = cur; cur = nxt; nxt = nx2; nx2 = tmp;
  }
#undef STAGE

#pragma unroll
  for (int mi=0;mi<4;mi++)
#pragma unroll
    for (int ni=0;ni<4;ni++)
      acc[mi][ni] = accfencei(acc[mi][ni]);

  const int rif = (lane>>4)<<2;
  const int cif = lane&15;
  const int gcol0 = bn*128 + (wc<<6);

  if constexpr (SPLITK){
    if constexpr (PB16){
      unsigned short* P = (unsigned short*)C + (size_t)blockIdx.z * ((size_t)N << 10);
#pragma unroll
      for (int mi=0;mi<4;mi++)
#pragma unroll
        for (int r=0;r<4;r++){
          const int grow = bm*128 + (wr<<6) + mi*16 + rif + r;
#pragma unroll
          for (int ni=0;ni<4;ni++)
            P[(size_t)grow*N + gcol0 + ni*16 + cif] = f2bfr((float)acc[mi][ni][r]);
        }
    } else {
      float* P = C + (size_t)blockIdx.z * ((size_t)N << 10);
#pragma unroll
      for (int mi=0;mi<4;mi++)
#pragma unroll
        for (int r=0;r<4;r++){
          const int grow = bm*128 + (wr<<6) + mi*16 + rif + r;
#pragma unroll
          for (int ni=0;ni<4;ni++)
            P[(size_t)grow*N + gcol0 + ni*16 + cif] = (float)acc[mi][ni][r];
        }
    }
    return;
  }

  if constexpr (GUSILU){
    const float sg = wscv[0], su = wscv[1];
    unsigned short* Cb = (unsigned short*)C;   // bf16 [M][4096]
#pragma unroll
    for (int mi=0;mi<4;mi++){
#pragma unroll
      for (int r=0;r<4;r++){
        const int grow = bm*128 + (wr<<6) + mi*16 + rif + r;
        const float rsc = rowsc[grow];
#pragma unroll
        for (int ni=0;ni<4;ni++){
          const int gcol = gcol0 + ni*16 + cif;
          float val = (float)acc[mi][ni][r] * rsc * ((gcol & 1) ? su : sg);
          float other = __shfl_xor(val, 1);
          if (!(lane & 1)){
            float g = val, u = other;
            float outv = g/(1.f+expf(-g))*u;
            Cb[(size_t)grow*4096 + (gcol>>1)] = f2bfr(outv);
          }
        }
      }
    }
    return;
  }

#pragma unroll
  for (int mi=0;mi<4;mi++){
#pragma unroll
    for (int r=0;r<4;r++){
      const int grow = bm*128 + (wr<<6) + mi*16 + rif + r;
      const float rsc = rowsc[grow];
#pragma unroll
      for (int ni=0;ni<4;ni++){
        const int gcol = gcol0 + ni*16 + cif;
        float vvv = (float)acc[mi][ni][r] * rsc * wscv[0];
        const size_t off = (size_t)grow*N + gcol;
        if (res) vvv += res[off];
        C[off] = vvv;
      }
    }
  }
}

// ---------------- qkv GEMM: same triple-buffered loop + rope epilogue -> bf16 ----------------
// grid (24, 8). N=3072, K=1024. Each 64-col half-tile (wc) is one head-section.
__global__ __launch_bounds__(256)
void gemm_qkv128(const signed char* __restrict__ A, const signed char* __restrict__ W,
                 const float* __restrict__ rowsc, const float* __restrict__ wscv,
                 const float* __restrict__ tab, unsigned short* __restrict__ C)
{
  __shared__ __align__(16) signed char As[3][8192];
  __shared__ __align__(16) signed char Bs[3][8192];
  const int tid = threadIdx.x;
  const int lane = tid & 63, wvid = tid >> 6;
  const int wr = wvid >> 1, wc = wvid & 1;
  const int bm = blockIdx.y, bn = blockIdx.x;
  const int Kf = 1024;

  const int r0 = (wvid<<4) + (lane>>2);
  const int sw = (((lane&3) ^ ((r0>>1)&3)) << 4);
  const signed char* gA = A + (size_t)(bm*128 + r0)*Kf + sw;
  const signed char* gB = W + (size_t)(bn*128 + r0)*Kf + sw;
  const size_t row64 = (size_t)64*Kf;

#define STAGE(buf, koff) do { \
    __builtin_amdgcn_global_load_lds(gA + (koff),         &As[buf][(wvid<<10)],      16, 0, 0); \
    __builtin_amdgcn_global_load_lds(gA + (koff) + row64, &As[buf][(wvid<<10)+4096], 16, 0, 0); \
    __builtin_amdgcn_global_load_lds(gB + (koff),         &Bs[buf][(wvid<<10)],      16, 0, 0); \
    __builtin_amdgcn_global_load_lds(gB + (koff) + row64, &Bs[buf][(wvid<<10)+4096], 16, 0, 0); \
  } while(0)

  i32x4 acc[4][4] = {};
  const int rA = (wr<<6) + (lane&15);
  const int rB = (wc<<6) + (lane&15);
  const int psA = (((lane>>4) ^ (((lane&15)>>1)&3)) << 4);

  const int NT = 16;
  STAGE(0, 0);
  STAGE(1, 64);
  int cur = 0, nxt = 1, nx2 = 2;
  for (int kt = 0; kt < NT; ++kt){
    const int k2 = kt + 2;
    const int kn = (k2 < NT) ? (k2<<6) : 0;
    STAGE(nx2, kn);
    asm volatile("s_waitcnt vmcnt(8)" ::: "memory");
    __builtin_amdgcn_s_barrier();
    asm volatile("" ::: "memory");
    i32x4 a[4], b[4];
    const signed char* Ab = As[cur];
    const signed char* Bb = Bs[cur];
#pragma unroll
    for (int mi=0;mi<4;mi++) a[mi] = *(const i32x4*)(Ab + (rA + mi*16)*64 + psA);
#pragma unroll
    for (int ni=0;ni<4;ni++) b[ni] = *(const i32x4*)(Bb + (rB + ni*16)*64 + psA);
#pragma unroll
    for (int mi=0;mi<4;mi++)
#pragma unroll
      for (int ni=0;ni<4;ni++)
        asm("v_mfma_i32_16x16x64_i8 %0, %1, %2, %0" : "+v"(acc[mi][ni]) : "v"(a[mi]), "v"(b[ni]));
    asm volatile("s_waitcnt lgkmcnt(0)" ::: "memory");
    __builtin_amdgcn_s_barrier();
    int tmp = cur; cur = nxt; nxt = nx2; nx2 = tmp;
  }
#undef STAGE

#pragma unroll
  for (int mi=0;mi<4;mi++)
#pragma unroll
    for (int ni=0;ni<4;ni++)
      acc[mi][ni] = accfencei(acc[mi][ni]);

  const int rif = (lane>>4)<<2;
  const int cif = lane&15;
  const int gcol0 = bn*128 + (wc<<6);     // head-aligned 64-col span
  const int sec = gcol0 >> 10;            // 0=q, 1=k, 2=v
  const float wsc = wscv[sec] * ((sec==0) ? 0.125f : 1.f);

  if (sec < 2){
    // rope: col d pairs with d+32 -> acc[mi][np] with acc[mi][np+2], np in {0,1}
#pragma unroll
    for (int mi=0;mi<4;mi++){
#pragma unroll
      for (int r=0;r<4;r++){
        const int grow = bm*128 + (wr<<6) + mi*16 + rif + r;
        const float s = rowsc[grow] * wsc;
        const int tpos = grow & 511;
#pragma unroll
        for (int np=0;np<2;np++){
          const int d = np*16 + cif;
          float2 cs = *(const float2*)(tab + (size_t)((tpos<<5) + d)*2);
          float x1 = (float)acc[mi][np][r]   * s;
          float x2 = (float)acc[mi][np+2][r] * s;
          C[(size_t)grow*3072 + gcol0 + d]      = f2bfr(x1*cs.x - x2*cs.y);
          C[(size_t)grow*3072 + gcol0 + 32 + d] = f2bfr(x1*cs.y + x2*cs.x);
        }
      }
    }
  } else {
#pragma unroll
    for (int mi=0;mi<4;mi++){
#pragma unroll
      for (int r=0;r<4;r++){
        const int grow = bm*128 + (wr<<6) + mi*16 + rif + r;
        const float s = rowsc[grow] * wsc;
#pragma unroll
        for (int ni=0;ni<4;ni++)
          C[(size_t)grow*3072 + gcol0 + ni*16 + cif] = f2bfr((float)acc[mi][ni][r] * s);
      }
    }
  }
}

// ---------------- split-K(4) reduce (f32 partials): C = (res?) + (sum P)*rowsc*wsc ----------------
__global__ __launch_bounds__(256) void reduce4_k(const float* __restrict__ P,
                                                 const float* __restrict__ rowsc,
                                                 const float* __restrict__ wsc,
                                                 const float* __restrict__ res,
                                                 float* __restrict__ C){
  int m = blockIdx.x, t = threadIdx.x;
  float s0 = rowsc[m] * wsc[0];
  size_t off = (size_t)m*1024 + t*4;
  float4 a = *(const float4*)(P + off);
  float4 b = *(const float4*)(P + 1048576 + off);
  float4 c = *(const float4*)(P + 2097152 + off);
  float4 d = *(const float4*)(P + 3145728 + off);
  float4 o;
  o.x = (a.x+b.x+c.x+d.x)*s0;
  o.y = (a.y+b.y+c.y+d.y)*s0;
  o.z = (a.z+b.z+c.z+d.z)*s0;
  o.w = (a.w+b.w+c.w+d.w)*s0;
  if (res){
    float4 r = *(const float4*)(res + off);
    o.x += r.x; o.y += r.y; o.z += r.z; o.w += r.w;
  }
  *(float4*)(C + off) = o;
}

// ---------------- fused: split-K(4) bf16-partial reduce + bf16 residual + rmsnorm + quant ----------------
__global__ __launch_bounds__(256) void redq_norm_k(const unsigned short* __restrict__ P,
                                                   const float* rowsc,
                                                   const float* __restrict__ wsc,
                                                   const unsigned short* __restrict__ res,
                                                   const float* __restrict__ gamma,
                                                   unsigned short* __restrict__ Cout,
                                                   signed char* __restrict__ xq,
                                                   float* rs){
  __shared__ float red[4];
  int m = blockIdx.x, t = threadIdx.x;
  float s0 = rowsc[m] * wsc[0];
  size_t off = (size_t)m*1024 + t*4;
  ushort4 a = *(const ushort4*)(P + off);
  ushort4 b = *(const ushort4*)(P + 1048576 + off);
  ushort4 c = *(const ushort4*)(P + 2097152 + off);
  ushort4 d = *(const ushort4*)(P + 3145728 + off);
  ushort4 r4 = *(const ushort4*)(res + off);
  float v[4];
  v[0] = bf2f(r4.x) + (bf2f(a.x)+bf2f(b.x)+bf2f(c.x)+bf2f(d.x))*s0;
  v[1] = bf2f(r4.y) + (bf2f(a.y)+bf2f(b.y)+bf2f(c.y)+bf2f(d.y))*s0;
  v[2] = bf2f(r4.z) + (bf2f(a.z)+bf2f(b.z)+bf2f(c.z)+bf2f(d.z))*s0;
  v[3] = bf2f(r4.w) + (bf2f(a.w)+bf2f(b.w)+bf2f(c.w)+bf2f(d.w))*s0;
  ushort4 ob;
  ob.x = f2bfr(v[0]); ob.y = f2bfr(v[1]); ob.z = f2bfr(v[2]); ob.w = f2bfr(v[3]);
  *(ushort4*)(Cout + off) = ob;
  float ss = v[0]*v[0]+v[1]*v[1]+v[2]*v[2]+v[3]*v[3];
  ss = bredsum(ss, red);
  float r1 = rsqrtf(ss*(1.f/1024.f) + 1e-6f);
  float y[4];
#pragma unroll
  for (int j=0;j<4;j++) y[j] = v[j]*r1*gamma[t*4+j];
  float am = fmaxf(fmaxf(fabsf(y[0]),fabsf(y[1])),fmaxf(fabsf(y[2]),fabsf(y[3])));
  am = bredmax(am, red);
  float aq = fmaxf(am, 1e-8f), inv = 127.f/aq;
  char4 q;
  q.x = f2i8(fminf(fmaxf(rintf(y[0]*inv),-128.f),127.f));
  q.y = f2i8(fminf(fmaxf(rintf(y[1]*inv),-128.f),127.f));
  q.z = f2i8(fminf(fmaxf(rintf(y[2]*inv),-128.f),127.f));
  q.w = f2i8(fminf(fmaxf(rintf(y[3]*inv),-128.f),127.f));
  *(char4*)(xq + (size_t)m*1024 + t*4) = q;
  if (t==0) rs[m] = aq/127.f;
}

// ---------------- fused tail (bf16 partials + bf16 residual): reduce + recurrence + quant + loraDown
//                  + topk + loraUp + act-sigmoid + h_out + ponder (+ next-iter loopnorm -> bf16) ----------------
__global__ __launch_bounds__(256) void redfin_k(const unsigned short* __restrict__ P,
                                                const float* __restrict__ rowsc,
                                                const float* __restrict__ wsc,
                                                const unsigned short* __restrict__ res,
                                                float* __restrict__ h,
                                                const float* __restrict__ Be,
                                                const float* __restrict__ Araw,
                                                const float* __restrict__ alpha, int it,
                                                const signed char* __restrict__ ldq,
                                                const float* __restrict__ sld,
                                                const signed char* __restrict__ luq,
                                                const float* __restrict__ slu,
                                                const signed char* __restrict__ actq,
                                                const float* __restrict__ sact,
                                                const float* __restrict__ ig,
                                                float* __restrict__ hout,
                                                float* __restrict__ ponder,
                                                const float* __restrict__ dnext,
                                                const float* __restrict__ lnw,
                                                const float* __restrict__ n1,
                                                unsigned short* __restrict__ hin,
                                                signed char* __restrict__ xqn,
                                                float* __restrict__ rsn,
                                                int doNext){
  __shared__ float red[4];
  __shared__ float xrow[1024];
  __shared__ float part[256];
  __shared__ float xs[32];
  __shared__ float sh_thr, sh_gs;
  int m = blockIdx.x, t = threadIdx.x;
  float al = alpha[it];
  float s0 = rowsc[m] * wsc[0];
  size_t off = (size_t)m*1024 + t*4;
  ushort4 a = *(const ushort4*)(P + off);
  ushort4 b = *(const ushort4*)(P + 1048576 + off);
  ushort4 c = *(const ushort4*)(P + 2097152 + off);
  ushort4 d = *(const ushort4*)(P + 3145728 + off);
  ushort4 r4 = *(const ushort4*)(res + off);
  float4 hh = *(const float4*)(h + off);
  float4 be = *(const float4*)(Be + off);
  float4 ar = *(const float4*)(Araw + t*4);
  float v[4];
  v[0] = 0.99f*tanhf(ar.x)*hh.x + be.x + al*(bf2f(r4.x) + (bf2f(a.x)+bf2f(b.x)+bf2f(c.x)+bf2f(d.x))*s0);
  v[1] = 0.99f*tanhf(ar.y)*hh.y + be.y + al*(bf2f(r4.y) + (bf2f(a.y)+bf2f(b.y)+bf2f(c.y)+bf2f(d.y))*s0);
  v[2] = 0.99f*tanhf(ar.z)*hh.z + be.z + al*(bf2f(r4.z) + (bf2f(a.z)+bf2f(b.z)+bf2f(c.z)+bf2f(d.z))*s0);
  v[3] = 0.99f*tanhf(ar.w)*hh.w + be.w + al*(bf2f(r4.w) + (bf2f(a.w)+bf2f(b.w)+bf2f(c.w)+bf2f(d.w))*s0);
  float am = fmaxf(fmaxf(fabsf(v[0]),fabsf(v[1])),fmaxf(fabsf(v[2]),fabsf(v[3])));
  am = bredmax(am, red);
  float aq = fmaxf(am, 1e-8f), inv = 127.f/aq;
#pragma unroll
  for (int j=0;j<4;j++) xrow[t*4+j] = fminf(fmaxf(rintf(v[j]*inv),-128.f),127.f);
  float rsv = aq/127.f;
  __syncthreads();
  {
    int r = t & 31, seg = t >> 5;
    const signed char* wrow = ldq + (size_t)r*1024 + seg*128;
    const float* xr = xrow + seg*128;
    float acc = 0.f;
    for (int k=0;k<128;k+=4){
      char4 w4 = *(const char4*)(wrow + k);
      acc += xr[k]*(float)w4.x + xr[k+1]*(float)w4.y + xr[k+2]*(float)w4.z + xr[k+3]*(float)w4.w;
    }
    part[t] = acc;
  }
  __syncthreads();
  if (t < 32){
    float s = 0.f;
    for (int sg=0; sg<8; sg++) s += part[sg*32 + t];
    xs[t] = s * rsv * (*sld);
  }
  __syncthreads();
  float val = 0.f, av = 0.f, amax = 0.f;
  if (t < 32){
    val = xs[t]; av = fabsf(val);
    int rank = 0;
    for (int j=0;j<32;j++){
      float aj = fabsf(xs[j]);
      amax = fmaxf(amax, aj);
      if (aj > av || (aj == av && j < t)) rank++;
    }
    if (rank == 17) sh_thr = av;
  }
  __syncthreads();
  if (t < 32){
    float a2 = fmaxf(amax, 1e-8f);
    float q = 0.f;
    if (av >= sh_thr) q = fminf(fmaxf(rintf(val*(127.f/a2)), -128.f), 127.f);
    xs[t] = q;
    if (t == 0) sh_gs = ig[it] * (*slu) * (a2/127.f);
  }
  __syncthreads();
  float gs = sh_gs;
  float hn[4];
  int n0 = t*4;
#pragma unroll
  for (int ni=0;ni<4;ni++){
    const signed char* lr = luq + (size_t)(n0+ni)*32;
    float dd = 0.f;
    for (int k=0;k<32;k+=4){
      char4 w4 = *(const char4*)(lr + k);
      dd += xs[k]*(float)w4.x + xs[k+1]*(float)w4.y + xs[k+2]*(float)w4.z + xs[k+3]*(float)w4.w;
    }
    hn[ni] = v[ni] + gs*dd;
  }
  float am2 = fmaxf(fmaxf(fabsf(hn[0]),fabsf(hn[1])),fmaxf(fabsf(hn[2]),fabsf(hn[3])));
  am2 = bredmax(am2, red);
  float a2 = fmaxf(am2, 1e-8f), inv2 = 127.f/a2;
  float zp = 0.f;
#pragma unroll
  for (int ni=0;ni<4;ni++){
    float q = fminf(fmaxf(rintf(hn[ni]*inv2),-128.f),127.f);
    zp += q * (float)actq[n0+ni];
  }
  zp = bredsum(zp, red);
  float z = zp * (a2/127.f) * (*sact);
  float wv = 1.f/(1.f+expf(-z));
#pragma unroll
  for (int ni=0;ni<4;ni++){
    size_t o2 = (size_t)m*1024 + n0+ni;
    float ho = hout[o2];
    hout[o2] = ho + wv*(hn[ni]-ho);
    h[o2] = hn[ni];
  }
  if (t==0) atomicAdd(ponder, wv * (1.f/8192.f));

  // ---- fused next-iteration loopnorm + quant ----
  if (doNext){
    int b2 = m >> 9;
    float v2[4] = {hn[0], hn[1], hn[2], hn[3]};
    if (t < 16){
#pragma unroll
      for (int j=0;j<4;j++) v2[j] += dnext[b2*64 + t*4 + j];
    }
    float ss2 = v2[0]*v2[0]+v2[1]*v2[1]+v2[2]*v2[2]+v2[3]*v2[3];
    ss2 = bredsum(ss2, red);
    float r1 = rsqrtf(ss2*(1.f/1024.f) + 1e-6f);
    float w4[4];
#pragma unroll
    for (int j=0;j<4;j++) w4[j] = v2[j]*r1*lnw[t*4+j];
    ushort4 ob;
    ob.x = f2bfr(w4[0]); ob.y = f2bfr(w4[1]); ob.z = f2bfr(w4[2]); ob.w = f2bfr(w4[3]);
    *(ushort4*)(hin + off) = ob;
    float s2 = w4[0]*w4[0]+w4[1]*w4[1]+w4[2]*w4[2]+w4[3]*w4[3];
    s2 = bredsum(s2, red);
    float r2 = rsqrtf(s2*(1.f/1024.f) + 1e-6f);
    float y[4];
#pragma unroll
    for (int j=0;j<4;j++) y[j] = w4[j]*r2*n1[t*4+j];
    float am3 = fmaxf(fmaxf(fabsf(y[0]),fabsf(y[1])),fmaxf(fabsf(y[2]),fabsf(y[3])));
    am3 = bredmax(am3, red);
    float aq3 = fmaxf(am3, 1e-8f), inv3 = 127.f/aq3;
    char4 q;
    q.x = f2i8(fminf(fmaxf(rintf(y[0]*inv3),-128.f),127.f));
    q.y = f2i8(fminf(fmaxf(rintf(y[1]*inv3),-128.f),127.f));
    q.z = f2i8(fminf(fmaxf(rintf(y[2]*inv3),-128.f),127.f));
    q.w = f2i8(fminf(fmaxf(rintf(y[3]*inv3),-128.f),127.f));
    *(char4*)(xqn + off) = q;
    if (t==0) rsn[m] = aq3/127.f;
  }
}

// ---------------- MFMA flash attention, split-k over 2 blocks; bf16 partial out ----------------
DEV int swz64(int r, int c){ return r*64 + (c ^ ((r&7)<<3)); }

__global__ __launch_bounds__(256) void attn_split_k(const unsigned short* __restrict__ qkv,
                                                    unsigned short* __restrict__ Opart,
                                                    float* __restrict__ ml){
  __shared__ __align__(16) unsigned short Qs[4096];
  __shared__ __align__(16) unsigned short Ks[4096];
  __shared__ __align__(16) unsigned short Vt[4096];   // [d][k], swizzled on d
  __shared__ __align__(16) unsigned short Ps[4][1024];
  const int tid = threadIdx.x;
  const int lane = tid & 63, wv = tid >> 6;
  const int bidl = blockIdx.x & 255;
  const int z = blockIdx.x >> 8;          // 0..1
  const int qt = bidl & 7, bh = bidl >> 3;
  const int b = bh >> 4, h = bh & 15;
  const int tokb = b*512;
  const int l15 = lane & 15, lh = lane >> 4;

  { // stage Q (already scaled by 1/8)
    int r = tid >> 2, c0 = (tid & 3) << 4;
    const unsigned short* s = qkv + (size_t)(tokb + qt*64 + r)*3072 + h*64 + c0;
    u16x8 f0 = *(const u16x8*)s, f1 = *(const u16x8*)(s+8);
    *(u16x8*)(Qs + swz64(r, c0))   = f0;
    *(u16x8*)(Qs + swz64(r, c0+8)) = f1;
  }

  float m_run[4] = {-1e30f,-1e30f,-1e30f,-1e30f};
  float l_run[4] = {0.f,0.f,0.f,0.f};
  f32x4 accO[4] = {};

  const int nt = qt + 1;
  const int half = (nt + 1) >> 1;
  const int kA = z ? half : 0;
  const int kB = z ? nt : half;

  for (int kt = kA; kt < kB; ++kt){
    __syncthreads();
    { // stage K
      int r = tid >> 2, c0 = (tid & 3) << 4;
      const unsigned short* s = qkv + (size_t)(tokb + kt*64 + r)*3072 + 1024 + h*64 + c0;
      u16x8 f0 = *(const u16x8*)s, f1 = *(const u16x8*)(s+8);
      *(u16x8*)(Ks + swz64(r, c0))   = f0;
      *(u16x8*)(Ks + swz64(r, c0+8)) = f1;
    }
    { // stage V transposed
      int r0 = (tid >> 3) << 1, cv = (tid & 7) << 3;
      const unsigned short* s0 = qkv + (size_t)(tokb + kt*64 + r0)*3072 + 2048 + h*64 + cv;
      u16x8 a = *(const u16x8*)s0;
      u16x8 b2 = *(const u16x8*)(s0 + 3072);
#pragma unroll
      for (int j=0;j<8;j++){
        int d = cv + j;
        unsigned int pk = (unsigned int)a[j] | ((unsigned int)b2[j]<<16);
        *(unsigned int*)(Vt + swz64(d, r0)) = pk;
      }
    }
    __syncthreads();

    f32x4 s4[4] = {};
#pragma unroll
    for (int kc=0; kc<2; ++kc){
      i32x4 aq = *(const i32x4*)(Qs + swz64(wv*16 + l15, kc*32 + lh*8));
#pragma unroll
      for (int nt2=0; nt2<4; ++nt2){
        i32x4 bk = *(const i32x4*)(Ks + swz64(nt2*16 + l15, kc*32 + lh*8));
        asm("v_mfma_f32_16x16x32_bf16 %0, %1, %2, %0" : "+v"(s4[nt2]) : "v"(aq), "v"(bk));
      }
    }
#pragma unroll
    for (int nt2=0; nt2<4; ++nt2) s4[nt2] = accfence(s4[nt2]);

    const bool diag = (kt == qt);
    float sf[4];
#pragma unroll
    for (int r=0;r<4;r++){
      int rl = lh*4 + r;
      float mx = -1e30f;
#pragma unroll
      for (int nt2=0; nt2<4; ++nt2){
        float v = s4[nt2][r];
        if (diag && (nt2*16 + l15) > (wv*16 + rl)) v = -1e30f;
        s4[nt2][r] = v;
        mx = fmaxf(mx, v);
      }
      mx = fmaxf(mx, __shfl_xor(mx,1));
      mx = fmaxf(mx, __shfl_xor(mx,2));
      mx = fmaxf(mx, __shfl_xor(mx,4));
      mx = fmaxf(mx, __shfl_xor(mx,8));
      float mn = fmaxf(m_run[r], mx);
      sf[r] = __expf(m_run[r] - mn);
      m_run[r] = mn;
      float ps = 0.f;
#pragma unroll
      for (int nt2=0; nt2<4; ++nt2){
        float p = __expf(s4[nt2][r] - mn);
        ps += p;
        Ps[wv][swz64(rl, nt2*16 + l15)] = f2bfr(p);
      }
      ps += __shfl_xor(ps,1); ps += __shfl_xor(ps,2);
      ps += __shfl_xor(ps,4); ps += __shfl_xor(ps,8);
      l_run[r] = l_run[r]*sf[r] + ps;
    }
#pragma unroll
    for (int dt=0; dt<4; ++dt){
#pragma unroll
      for (int r=0;r<4;r++) accO[dt][r] *= sf[r];
      accO[dt] = accfence(accO[dt]);
    }
#pragma unroll
    for (int kc=0; kc<2; ++kc){
      i32x4 pa = *(const i32x4*)(Ps[wv] + swz64(l15, kc*32 + lh*8));
#pragma unroll
      for (int dt=0; dt<4; ++dt){
        i32x4 vb3 = *(const i32x4*)(Vt + swz64(dt*16 + l15, kc*32 + lh*8));
        asm("v_mfma_f32_16x16x32_bf16 %0, %1, %2, %0" : "+v"(accO[dt]) : "v"(pa), "v"(vb3));
      }
    }
  }
#pragma unroll
  for (int dt=0; dt<4; ++dt) accO[dt] = accfence(accO[dt]);
  unsigned short* Op = Opart + ((size_t)z << 20);
#pragma unroll
  for (int r=0;r<4;r++){
    int row = tokb + qt*64 + wv*16 + lh*4 + r;
    unsigned short* op = Op + (size_t)row*1024 + h*64 + l15;
#pragma unroll
    for (int dt=0; dt<4; ++dt)
      op[dt*16] = f2bfr(accO[dt][r]);
    if (l15 == 0){
      float2 v2 = make_float2(m_run[r], l_run[r]);
      *(float2*)(ml + ((size_t)(z*16 + h)*1024 + row)*2) = v2;
    }
  }
}

// ---------------- merge two attn partials (bf16) + row quant -> i8 ----------------
__global__ __launch_bounds__(256) void attn_merge_quant_k(const unsigned short* __restrict__ Opart,
                                                          const float* __restrict__ ml,
                                                          signed char* __restrict__ xq,
                                                          float* __restrict__ rs){
  __shared__ float red[4];
  int m = blockIdx.x, t = threadIdx.x;
  int head = t >> 4;                       // 4 cols per thread, 4-aligned -> single head
  float2 ml0 = *(const float2*)(ml + ((size_t)head*1024 + m)*2);
  float2 ml1 = *(const float2*)(ml + ((size_t)(16 + head)*1024 + m)*2);
  float mm = fmaxf(ml0.x, ml1.x);
  float w0 = __expf(ml0.x - mm), w1 = __expf(ml1.x - mm);
  float invl = 1.f / (ml0.y*w0 + ml1.y*w1);
  size_t off = (size_t)m*1024 + t*4;
  ushort4 u0 = *(const ushort4*)(Opart + off);
  ushort4 u1 = *(const ushort4*)(Opart + 1048576 + off);
  float v[4];
  v[0] = (bf2f(u0.x)*w0 + bf2f(u1.x)*w1)*invl;
  v[1] = (bf2f(u0.y)*w0 + bf2f(u1.y)*w1)*invl;
  v[2] = (bf2f(u0.z)*w0 + bf2f(u1.z)*w1)*invl;
  v[3] = (bf2f(u0.w)*w0 + bf2f(u1.w)*w1)*invl;
  float am = fmaxf(fmaxf(fabsf(v[0]),fabsf(v[1])),fmaxf(fabsf(v[2]),fabsf(v[3])));
  am = bredmax(am, red);
  float a = fmaxf(am, 1e-8f), inv = 127.f/a;
  char4 q;
  q.x = f2i8(fminf(fmaxf(rintf(v[0]*inv),-128.f),127.f));
  q.y = f2i8(fminf(fmaxf(rintf(v[1]*inv),-128.f),127.f));
  q.z = f2i8(fminf(fmaxf(rintf(v[2]*inv),-128.f),127.f));
  q.w = f2i8(fminf(fmaxf(rintf(v[3]*inv),-128.f),127.f));
  *(char4*)(xq + (size_t)m*1024 + t*4) = q;
  if (t==0) rs[m] = a/127.f;
}

// ================= host =================
extern "C" void kernel_launch(void* const* d_in, const int* in_sizes, int n_in,
                              void* d_out, int out_size, void* d_ws, size_t ws_size,
                              hipStream_t stream)
{
  (void)in_sizes; (void)n_in;
  const float* x     = (const float*)d_in[0];
  const float* e     = (const float*)d_in[1];
  const float* temb  = (const float*)d_in[2];
  const float* bn1   = (const float*)d_in[3];
  const float* bwq   = (const float*)d_in[4];
  const float* bwk   = (const float*)d_in[5];
  const float* bwv   = (const float*)d_in[6];
  const float* bwo   = (const float*)d_in[7];
  const float* bn2   = (const float*)d_in[8];
  const float* bwg   = (const float*)d_in[9];
  const float* bwu   = (const float*)d_in[10];
  const float* bwd   = (const float*)d_in[11];
  const float* Araw  = (const float*)d_in[12];
  const float* Bw    = (const float*)d_in[13];
  const float* ldw   = (const float*)d_in[14];
  const float* luw   = (const float*)d_in[15];
  const float* ig    = (const float*)d_in[16];
  const float* actw  = (const float*)d_in[17];
  const float* alph  = (const float*)d_in[18];
  const float* lpw   = (const float*)d_in[19];
  const float* lp2w  = (const float*)d_in[20];
  const float* lp2b  = (const float*)d_in[21];
  const float* lnw   = (const float*)d_in[22];

  char* ws = (char*)d_ws;
  float* out = (float*)d_out;
  const size_t WS_NEEDED = 94600704ull;
  if (ws_size < WS_NEEDED){
    fill_k<<<(out_size+255)/256,256,0,stream>>>(out, out_size, 1.0e9f);
    return;
  }

  signed char* qw_qkv = (signed char*)(ws + 0);          // 6 MB
  signed char* qw_wo  = (signed char*)(ws + 6291456);    // 2 MB
  signed char* qw_gu  = (signed char*)(ws + 8388608);    // 16 MB (g/u row-interleaved)
  signed char* qw_wd  = (signed char*)(ws + 25165824);   // 8 MB
  signed char* qw_bw  = (signed char*)(ws + 33554432);   // 1 MB
  signed char* qw_ld  = (signed char*)(ws + 34603008);
  signed char* qw_lu  = (signed char*)(ws + 34635776);
  signed char* qw_act = (signed char*)(ws + 34668544);
  float* scales = (float*)(ws + 34669568);
  float* delta  = (float*)(ws + 34688512);
  float* hbuf   = (float*)(ws + 34692608);
  float* Bebuf  = (float*)(ws + 38886912);
  unsigned short* bufX = (unsigned short*)(ws + 43081216);   // 2 MB bf16 residual
  unsigned short* bufY = (unsigned short*)(ws + 47275520);   // 2 MB bf16 residual
  float* gub    = (float*)(ws + 51469824);               // scratch: partials / attn Opart / silu out
  unsigned short* qkv_bf = (unsigned short*)(ws + 76635648);  // 6 MB bf16 qkv
  float* mlbuf  = (float*)(ws + 85024256);               // 256 KB attn m/l partials
  signed char* xq1k = (signed char*)(ws + 89218560);
  float* rs1k   = (float*)(ws + 90267136);
  signed char* xqm  = (signed char*)(ws + 90271232);
  float* rsm    = (float*)(ws + 94465536);
  float* ropetab= (float*)(ws + 94469632);               // 128 KB
  float* part   = gub;                                   // absmean partials (setup only)

  // ---- setup: scales + ternary weights ----
  WSetup wsu;
  wsu.src[0]=Bw;
  wsu.src[1]=bwq; wsu.src[2]=bwq+1048576;
  wsu.src[3]=bwk; wsu.src[4]=bwk+1048576;
  wsu.src[5]=bwv; wsu.src[6]=bwv+1048576;
  wsu.src[7]=bwo; wsu.src[8]=bwo+1048576;
  wsu.src[9]=bwg; wsu.src[10]=bwg+4194304;
  wsu.src[11]=bwu; wsu.src[12]=bwu+4194304;
  wsu.src[13]=bwd; wsu.src[14]=bwd+4194304;
  wsu.src[15]=ldw; wsu.src[16]=luw; wsu.src[17]=actw;
  wsu.dst[0]=qw_bw;
  wsu.dst[1]=qw_qkv;             wsu.dst[2]=qw_qkv+3145728;
  wsu.dst[3]=qw_qkv+1048576;     wsu.dst[4]=qw_qkv+3145728+1048576;
  wsu.dst[5]=qw_qkv+2097152;     wsu.dst[6]=qw_qkv+3145728+2097152;
  wsu.dst[7]=qw_wo;              wsu.dst[8]=qw_wo+1048576;
  wsu.dst[9]=qw_gu;              wsu.dst[10]=qw_gu+8388608;
  wsu.dst[11]=qw_gu;             wsu.dst[12]=qw_gu+8388608;
  wsu.dst[13]=qw_wd;             wsu.dst[14]=qw_wd+4194304;
  wsu.dst[15]=qw_ld; wsu.dst[16]=qw_lu; wsu.dst[17]=qw_act;
  for (int i=0;i<18;i++) wsu.mode[i]=0;
  wsu.mode[9]=1;  wsu.mode[10]=1;   // wg -> even rows
  wsu.mode[11]=2; wsu.mode[12]=2;   // wu -> odd rows

  absmean_all_k<<<2117,256,0,stream>>>(wsu, part);
  finalize_scales_k<<<1,256,0,stream>>>(part, scales);
  quantw_all_k<<<2117,256,0,stream>>>(wsu, scales);

  // ---- misc setup (copy_init + delta + ropetab merged) ----
  setup_misc_k<<<1216,256,0,stream>>>(x, hbuf, out, temb, lpw, lp2w, lp2b, delta, ropetab);

  // Be = bitlinear(e, B_w)  (splitK x4, f32 partials — setup only)
  rowquant1k_k<false><<<1024,256,0,stream>>>(e, xq1k, rs1k);
  { dim3 g(8,8,4); gemm_i8<true,false,false><<<g,256,0,stream>>>(xq1k, qw_bw, nullptr, nullptr, nullptr, gub, 1024, 1024, 256); }
  reduce4_k<<<1024,256,0,stream>>>(gub, rs1k, scales+0, nullptr, Bebuf);

  // ---- main recurrent loop (n_loops = 8) ----
  for (int it=0; it<8; ++it){
    if (it==0)
      loopnorm_quant_k<<<1024,256,0,stream>>>(hbuf, delta, lnw, bn1, bufX, xq1k, rs1k);
    for (int l=0;l<2;l++){
      // qkv: 128x128 GEMM + fused scale/rope epilogue -> bf16 qkvb
      { dim3 g(24,8); gemm_qkv128<<<g,256,0,stream>>>(xq1k, qw_qkv + (size_t)l*3145728, rs1k, scales+18+l*3, ropetab, qkv_bf); }
      // attention split over 2 k-halves (512 blocks) + merge/quant; bf16 partials
      attn_split_k<<<512,256,0,stream>>>(qkv_bf, (unsigned short*)gub, mlbuf);
      attn_merge_quant_k<<<1024,256,0,stream>>>((const unsigned short*)gub, mlbuf, xq1k, rs1k);
      // wo (splitK x4, bf16 partials) + fused reduce+residual+rmsnorm(bn2)+quant
      { dim3 g(8,8,4); gemm_i8<true,false,true><<<g,256,0,stream>>>(xq1k, qw_wo + (size_t)l*1048576, nullptr, nullptr, nullptr, gub, 1024, 1024, 256); }
      redq_norm_k<<<1024,256,0,stream>>>((const unsigned short*)gub, rs1k, scales+7+l, bufX, bn2 + (size_t)l*1024, bufY, xq1k, rs1k);
      // gu with fused silu epilogue -> bf16 [1024][4096]
      { dim3 g(64,8); gemm_i8<false,true,false><<<g,256,0,stream>>>(xq1k, qw_gu + (size_t)l*8388608, rs1k, scales+24+l*2, nullptr, gub, 8192, 1024, 1024); }
      rowquant4k_k<<<1024,256,0,stream>>>((const unsigned short*)gub, xqm, rsm);
      // wd (splitK x4, bf16 partials)
      { dim3 g(8,8,4); gemm_i8<true,false,true><<<g,256,0,stream>>>(xqm, qw_wd + (size_t)l*4194304, nullptr, nullptr, nullptr, gub, 1024, 4096, 1024); }
      if (l==0){
        redq_norm_k<<<1024,256,0,stream>>>((const unsigned short*)gub, rsm, scales+13, bufY, bn1 + 1024, bufX, xq1k, rs1k);
      } else {
        redfin_k<<<1024,256,0,stream>>>((const unsigned short*)gub, rsm, scales+14, bufY, hbuf, Bebuf, Araw, alph, it,
                                        qw_ld, scales+15, qw_lu, scales+16, qw_act, scales+17,
                                        ig, out, out + 1048576,
                                        delta + (it+1 < 8 ? (it+1)*128 : 0), lnw, bn1, bufX, xq1k, rs1k,
                                        (it < 7) ? 1 : 0);
      }
    }
  }
}